// Round 3
// baseline (261.965 us; speedup 1.0000x reference)
//
#include <hip/hip_runtime.h>

// out = X A + 1 r^T,  A = scale Wq^T (K^T V).  With G = X^T X, s = X^T 1:
//   K^T V = Wk G Wv^T + (Wk s) bv^T + bk (Wv s)^T + S bk bv^T
// Augment Wq+ = [Wq^T; bq^T; 0pad] (896x768) so r = col 768 of At.
//   prep_w: Wqt+/Wkt/Wvb (bf16) + zero csum/tcnt
//   prep_x: Xbf [4][4096][768], Xt [4][768][4096], csum atomics
//   gram2:  42 P+ tiles (first-launched, unswizzled) + 672 tri split-K Gram
//           partial tiles (K=512) with LAST-ARRIVER REDUCE -> G (+mirror)
//           fused in-dispatch (per-tile atomic counter + device fences)
//           + u/d2/c2p aux
//   c1mix:  168 C1+ tiles (P+ ⊠ G) + 896 c1p aux (SCALE*Wqt+ . u)
//   At  = Wvb ⊠ C1+ (+rank2)[4][768][896]
//   out = Xbf ⊠ At (K=768) + At[col][768] epilogue   fp32
// GEMM: 128x128 tile, BK=64, serial 32KB-LDS loop (m97 structure),
// global_load_lds(16B) pre-swizzled source, XOR (r&7)<<4 reads,
// XCD-chunked bijective blockIdx swizzle.
// (R1 post-mortem: explicit dbuf+counted-vmcnt core regressed +12us —
//  compiler-scheduled serial core wins at occupancy; do not re-add.
//  R2 post-mortem: P+ tiles mid-pack in gram2's swizzled space cost ~5us;
//  they must launch FIRST, unswizzled.)

typedef __attribute__((ext_vector_type(8))) __bf16 bf16x8;
typedef __attribute__((ext_vector_type(4))) float f32x4;

#define SCALE 0.03608439182435161f

union FragU {
    uint4 q;
    bf16x8 f;
    unsigned short s[8];
};

__device__ __forceinline__ unsigned short f2bf(float x) {
    unsigned int u = __builtin_bit_cast(unsigned int, x);
    u = (u + 0x7fffu + ((u >> 16) & 1u)) >> 16;
    return (unsigned short)u;
}
__device__ __forceinline__ float bf2f(unsigned short u) {
    unsigned int v = ((unsigned int)u) << 16;
    return __builtin_bit_cast(float, v);
}

__device__ __forceinline__ unsigned xcd_swizzle(unsigned lin, unsigned nwg) {
    const unsigned q = nwg >> 3, rr8 = nwg & 7;
    const unsigned xcd = lin & 7, o = lin >> 3;
    return (xcd < rr8 ? xcd * (q + 1) : rr8 * (q + 1) + (xcd - rr8) * q) + o;
}

__device__ __forceinline__ void stage_gl(const unsigned short* __restrict__ srcRowBase,
                                         int ldElems, char* lds, int wave, int lane) {
#pragma unroll
    for (int p = 0; p < 4; ++p) {
        int slotbase = (wave * 4 + p) * 1024;
        int slot = slotbase + lane * 16;
        int r = slot >> 7;
        int cb = (slot & 127) ^ ((r & 7) << 4);
        const char* g = (const char*)(srcRowBase + (size_t)r * ldElems) + cb;
        __builtin_amdgcn_global_load_lds(
            (const __attribute__((address_space(1))) unsigned int*)g,
            (__attribute__((address_space(3))) unsigned int*)(lds + slotbase),
            16, 0, 0);
    }
}

__device__ __forceinline__ bf16x8 load_frag(const char* lds, int row, int kbyte) {
    int a = row * 128 + kbyte;
    a ^= (row & 7) << 4;
    FragU u;
    u.q = *(const uint4*)(lds + a);
    return u.f;
}

__device__ __forceinline__ void gemm_core(const unsigned short* __restrict__ Ab,
                                          const unsigned short* __restrict__ Bb,
                                          int K, int lda, int ldb,
                                          char* ldsA, char* ldsB,
                                          int wave, int lane, int wm, int wn,
                                          int l15, int khi, f32x4 (&acc)[4][4]) {
    for (int k0 = 0; k0 < K; k0 += 64) {
        stage_gl(Ab + k0, lda, ldsA, wave, lane);
        stage_gl(Bb + k0, ldb, ldsB, wave, lane);
        __syncthreads();
#pragma unroll
        for (int kk = 0; kk < 2; ++kk) {
            const int kbyte = kk * 64 + khi;
            bf16x8 af[4], bfr[4];
#pragma unroll
            for (int i = 0; i < 4; ++i)
                af[i] = load_frag(ldsA, wm * 64 + i * 16 + l15, kbyte);
#pragma unroll
            for (int j = 0; j < 4; ++j)
                bfr[j] = load_frag(ldsB, wn * 64 + j * 16 + l15, kbyte);
#pragma unroll
            for (int i = 0; i < 4; ++i)
#pragma unroll
                for (int j = 0; j < 4; ++j)
                    acc[i][j] = __builtin_amdgcn_mfma_f32_16x16x32_bf16(
                        af[i], bfr[j], acc[i][j], 0, 0, 0);
        }
        __syncthreads();
    }
}

enum { BIAS_NONE = 0, BIAS_RANK2 = 2, BIAS_RCOL = 3 };

template <int BIASM, bool OUT_BF16>
__global__ __launch_bounds__(256, 2) void gemm_bf16(
    const unsigned short* __restrict__ A, const unsigned short* __restrict__ B,
    void* __restrict__ C,
    const float* __restrict__ p0, const float* __restrict__ p1,
    const float* __restrict__ p2, const float* __restrict__ p3,
    const unsigned short* __restrict__ rsrc,
    int K, int lda, int ldb, int ldc, long bsA, long bsB, long bsC,
    float scale, int vld1) {
    __shared__ __align__(16) char ldsA[16384];
    __shared__ __align__(16) char ldsB[16384];

    const unsigned gx = gridDim.x, gy = gridDim.y;
    const unsigned lin = blockIdx.x + gx * (blockIdx.y + gy * blockIdx.z);
    const unsigned wg = xcd_swizzle(lin, gx * gy * gridDim.z);
    const int bx = wg % gx;
    const int by = (wg / gx) % gy;
    const int z = wg / (gx * gy);

    const int m0 = by * 128;
    const int n0 = bx * 128;
    const unsigned short* Ab = A + (size_t)z * bsA + (size_t)m0 * lda;
    const unsigned short* Bb = B + (size_t)z * bsB + (size_t)n0 * ldb;

    const int lane = threadIdx.x & 63;
    const int wave = threadIdx.x >> 6;
    const int wm = wave >> 1;
    const int wn = wave & 1;
    const int l15 = lane & 15;
    const int khi = (lane >> 4) << 4;

    f32x4 acc[4][4];
#pragma unroll
    for (int i = 0; i < 4; ++i)
#pragma unroll
        for (int j = 0; j < 4; ++j)
            acc[i][j] = (f32x4){0.f, 0.f, 0.f, 0.f};

    gemm_core(Ab, Bb, K, lda, ldb, ldsA, ldsB, wave, lane, wm, wn, l15, khi, acc);

    const int rbase = (lane >> 4) << 2;
#pragma unroll
    for (int i = 0; i < 4; ++i) {
#pragma unroll
        for (int r = 0; r < 4; ++r) {
            int row = m0 + wm * 64 + i * 16 + rbase + r;
            float rA = 0.f, rB = 0.f;
            if (BIASM == BIAS_RANK2) {
                rA = p0[row];
                rB = p2[z * 768 + row];
            }
#pragma unroll
            for (int j = 0; j < 4; ++j) {
                int col = n0 + wn * 64 + j * 16 + l15;
                float v = acc[i][j][r] * scale;
                if (BIASM == BIAS_RANK2) v += rA * p1[z * vld1 + col] + rB * p3[col];
                if (BIASM == BIAS_RCOL)
                    v += bf2f(rsrc[(size_t)z * 688128 + (size_t)col * 896 + 768]);
                size_t off = (size_t)z * bsC + (size_t)row * ldc + col;
                if (OUT_BF16)
                    ((unsigned short*)C)[off] = f2bf(v);
                else
                    ((float*)C)[off] = v;
            }
        }
    }
}

// z=0: Wqt+ rows 0..767 = Wq^T; z=1: Wkt = Wk^T; z=2: Wvb = bf16(Wv);
// z=3: Wqt+ row 768 = bq, rows 769..895 = 0; z=4: zero csum+tcnt.
__global__ __launch_bounds__(256) void prep_w(const float* __restrict__ Wq,
                                              const float* __restrict__ Wk,
                                              const float* __restrict__ Wv,
                                              const float* __restrict__ bq,
                                              unsigned short* __restrict__ Wqt,
                                              unsigned short* __restrict__ Wkt,
                                              unsigned short* __restrict__ Wvb,
                                              float* __restrict__ csum) {
    const int mode = blockIdx.z;
    const int t = threadIdx.x;
    if (mode == 4) {
        if (blockIdx.x == 0 && blockIdx.y == 0) {
            float4 z4 = {0.f, 0.f, 0.f, 0.f};
            for (int i = t * 4; i < 3168; i += 1024) *(float4*)(csum + i) = z4;
        }
        return;
    }
    if (mode == 3) {
        if (blockIdx.y) return;
        int rr = 768 + (t >> 1);
        int c0 = blockIdx.x * 64 + (t & 1) * 32;
        unsigned short v[32] __attribute__((aligned(16)));
        if (rr == 768) {
#pragma unroll
            for (int j = 0; j < 32; ++j) v[j] = f2bf(bq[c0 + j]);
        } else {
#pragma unroll
            for (int j = 0; j < 32; ++j) v[j] = 0;
        }
        unsigned short* dst = Wqt + (size_t)rr * 768 + c0;
#pragma unroll
        for (int j = 0; j < 4; ++j) *(uint4*)(dst + j * 8) = *(uint4*)&v[j * 8];
        return;
    }
    __shared__ unsigned short tile[64 * 72];
    const float* src = mode == 0 ? Wq : (mode == 1 ? Wk : Wv);
    const int r0 = blockIdx.x * 64;
    const int c0 = blockIdx.y * 64;
    int r = t >> 2, cq = (t & 3) * 16;
    unsigned short v[16] __attribute__((aligned(16)));
    const float* s = src + (size_t)(r0 + r) * 768 + c0 + cq;
#pragma unroll
    for (int j = 0; j < 16; j += 4) {
        float4 f = *(const float4*)(s + j);
        v[j] = f2bf(f.x); v[j + 1] = f2bf(f.y);
        v[j + 2] = f2bf(f.z); v[j + 3] = f2bf(f.w);
    }
    if (mode == 2) {
        unsigned short* dst = Wvb + (size_t)(r0 + r) * 768 + c0 + cq;
        *(uint4*)dst = *(uint4*)&v[0];
        *(uint4*)(dst + 8) = *(uint4*)&v[8];
        return;
    }
    *(uint4*)&tile[r * 72 + cq] = *(uint4*)&v[0];
    *(uint4*)&tile[r * 72 + cq + 8] = *(uint4*)&v[8];
    __syncthreads();
    int dr = t >> 2, sq = (t & 3) * 16;
    unsigned short w[16] __attribute__((aligned(16)));
#pragma unroll
    for (int j = 0; j < 16; ++j) w[j] = tile[(sq + j) * 72 + dr];
    unsigned short* dst = (mode == 0 ? Wqt : Wkt) + (size_t)(c0 + dr) * 768 + r0 + sq;
    *(uint4*)dst = *(uint4*)&w[0];
    *(uint4*)(dst + 8) = *(uint4*)&w[8];
}

// Xbf [4][4096][768], Xt [4][768][4096], csum atomics.
__global__ __launch_bounds__(256) void prep_x(const float* __restrict__ X,
                                              unsigned short* __restrict__ Xbf,
                                              unsigned short* __restrict__ Xt,
                                              float* __restrict__ csum) {
    const int b = blockIdx.z;
    const int s0 = blockIdx.x * 64;
    const int t = threadIdx.x;
    __shared__ unsigned short tile[64 * 72];
    const int d0 = blockIdx.y * 64;
    const float* Xb = X + (size_t)b * 4096 * 768;
    unsigned short* XbfB = Xbf + (size_t)b * 4096 * 768;
    unsigned short* XtB = Xt + (size_t)b * 768 * 4096;
    {
        int r = t >> 2, cq = (t & 3) * 16;
        const float* src = Xb + (size_t)(s0 + r) * 768 + d0 + cq;
        unsigned short v[16] __attribute__((aligned(16)));
#pragma unroll
        for (int j = 0; j < 16; j += 4) {
            float4 f = *(const float4*)(src + j);
            v[j] = f2bf(f.x); v[j + 1] = f2bf(f.y);
            v[j + 2] = f2bf(f.z); v[j + 3] = f2bf(f.w);
        }
        unsigned short* dst = XbfB + (size_t)(s0 + r) * 768 + d0 + cq;
        *(uint4*)dst = *(uint4*)&v[0];
        *(uint4*)(dst + 8) = *(uint4*)&v[8];
        *(uint4*)&tile[r * 72 + cq] = *(uint4*)&v[0];
        *(uint4*)&tile[r * 72 + cq + 8] = *(uint4*)&v[8];
    }
    __syncthreads();
    {
        int dr = t >> 2, sq = (t & 3) * 16;
        unsigned short v[16] __attribute__((aligned(16)));
        float part = 0.f;
#pragma unroll
        for (int j = 0; j < 16; ++j) {
            unsigned short u = tile[(sq + j) * 72 + dr];
            v[j] = u;
            part += bf2f(u);
        }
        unsigned short* dst = XtB + (size_t)(d0 + dr) * 4096 + s0 + sq;
        *(uint4*)dst = *(uint4*)&v[0];
        *(uint4*)(dst + 8) = *(uint4*)&v[8];
        part += __shfl_down(part, 1);
        part += __shfl_down(part, 2);
        if ((t & 3) == 0) atomicAdd(&csum[b * 768 + d0 + dr], part);
    }
}

// Grid 1706 flat:
//   blockIdx.x < 42: P+ tile (unswizzled, launched first): Pp = Wqt+ ⊠ Wkt
//   else wg = swz(blockIdx.x-42, 1664):
//     wg <  672: tri Gram split-K partial (tile=wg%21, zz=wg/21; b=zz>>3,
//                split=zz&7, K=512) -> Gp; LAST arriver (atomic counter)
//                reduces 8 partials -> G tile + mirror
//     wg < 1440: aux u/d2: id=wg-672, b=id/192, row=(id%192)*4+wave
//     wg >=1440: c2p: row=(wg-1440)*4+wave (<896)
__global__ __launch_bounds__(256, 2) void gram2(
    const unsigned short* __restrict__ Xt, unsigned short* __restrict__ Gp,
    unsigned short* __restrict__ G, unsigned int* __restrict__ tcnt,
    const float* __restrict__ Wk, const float* __restrict__ Wv,
    const unsigned short* __restrict__ Wqt, const unsigned short* __restrict__ Wkt,
    unsigned short* __restrict__ Pp,
    const float* __restrict__ bk, const float* __restrict__ bv,
    const float* __restrict__ csum,
    float* __restrict__ u, float* __restrict__ d2, float* __restrict__ c2p) {
    const long PB = 3145728;
    const int t = threadIdx.x;
    const int lane = t & 63;
    const int wave = t >> 6;
    __shared__ __align__(16) char smem[34816];  // ldsA|ldsB (32K) / tl (34816)
    __shared__ unsigned sOld;
    char* ldsA = smem;
    char* ldsB = smem + 16384;

    const int wm = wave >> 1;
    const int wn = wave & 1;
    const int l15 = lane & 15;
    const int khi = (lane >> 4) << 4;
    const int rbase = (lane >> 4) << 2;

    if (blockIdx.x < 42) {  // P+ = Wqt+ ⊠ Wkt (launched first, spread raw)
        const int id = blockIdx.x;
        const int m0 = (id / 6) * 128;
        const int n0 = (id % 6) * 128;
        f32x4 acc[4][4];
#pragma unroll
        for (int i = 0; i < 4; ++i)
#pragma unroll
            for (int j = 0; j < 4; ++j)
                acc[i][j] = (f32x4){0.f, 0.f, 0.f, 0.f};
        gemm_core(Wqt + (size_t)m0 * 768, Wkt + (size_t)n0 * 768,
                  768, 768, 768, ldsA, ldsB, wave, lane, wm, wn, l15, khi, acc);
#pragma unroll
        for (int i = 0; i < 4; ++i)
#pragma unroll
            for (int r = 0; r < 4; ++r) {
                int row = m0 + wm * 64 + i * 16 + rbase + r;
#pragma unroll
                for (int j = 0; j < 4; ++j) {
                    int col = n0 + wn * 64 + j * 16 + l15;
                    Pp[(size_t)row * 768 + col] = f2bf(acc[i][j][r]);
                }
            }
        return;
    }

    const unsigned wg = xcd_swizzle(blockIdx.x - 42, 1664);

    if (wg >= 1440) {  // c2p
        const int row = (wg - 1440) * 4 + wave;
        float a = 0.f;
        for (int e = lane * 4; e < 768; e += 256) {
            const unsigned short* qr = Wqt + (size_t)row * 768 + e;
            float4 b4 = *(const float4*)(bk + e);
            a += bf2f(qr[0]) * b4.x + bf2f(qr[1]) * b4.y +
                 bf2f(qr[2]) * b4.z + bf2f(qr[3]) * b4.w;
        }
#pragma unroll
        for (int off = 32; off; off >>= 1) a += __shfl_down(a, off);
        if (lane == 0) c2p[row] = a;
        return;
    }
    if (wg >= 672) {  // u + d2
        const int id = wg - 672;
        const int b = id / 192;
        const int row = (id % 192) * 4 + wave;
        const float* s = csum + b * 768;
        float aU = 0.f, aD = 0.f;
        for (int e = lane * 4; e < 768; e += 256) {
            float4 wk4 = *(const float4*)(Wk + (size_t)row * 768 + e);
            float4 wv4 = *(const float4*)(Wv + (size_t)row * 768 + e);
            float4 s4 = *(const float4*)(s + e);
            aU += wk4.x * s4.x + wk4.y * s4.y + wk4.z * s4.z + wk4.w * s4.w;
            aD += wv4.x * s4.x + wv4.y * s4.y + wv4.z * s4.z + wv4.w * s4.w;
        }
#pragma unroll
        for (int off = 32; off; off >>= 1) {
            aU += __shfl_down(aU, off);
            aD += __shfl_down(aD, off);
        }
        if (lane == 0) {
            u[b * 768 + row] = aU;
            d2[b * 768 + row] = SCALE * (aD + 4096.f * bv[row]);
        }
        return;
    }

    // Gram split-K partial tile
    f32x4 acc[4][4];
#pragma unroll
    for (int i = 0; i < 4; ++i)
#pragma unroll
        for (int j = 0; j < 4; ++j)
            acc[i][j] = (f32x4){0.f, 0.f, 0.f, 0.f};

    const int tile = wg % 21;
    const int zz = wg / 21;
    const int b = zz >> 3;
    const int koff = (zz & 7) * 512;
    int tt = tile, tby = 0;
    while (tt >= 6 - tby) { tt -= 6 - tby; ++tby; }
    const int tbx = tby + tt;
    const int m0 = tby * 128;
    const int n0 = tbx * 128;
    const unsigned short* Ab = Xt + (size_t)b * PB + (size_t)m0 * 4096 + koff;
    const unsigned short* Bb = Xt + (size_t)b * PB + (size_t)n0 * 4096 + koff;
    gemm_core(Ab, Bb, 512, 4096, 4096, ldsA, ldsB, wave, lane, wm, wn, l15, khi, acc);
    unsigned short* dst = Gp + ((size_t)zz * 21 + tile) * 16384;
#pragma unroll
    for (int i = 0; i < 4; ++i)
#pragma unroll
        for (int r = 0; r < 4; ++r) {
            int rloc = wm * 64 + i * 16 + rbase + r;
#pragma unroll
            for (int j = 0; j < 4; ++j) {
                int cloc = wn * 64 + j * 16 + l15;
                dst[(size_t)rloc * 128 + cloc] = f2bf(acc[i][j][r]);
            }
        }

    // last-arriver reduce: 8 partials -> G tile (+mirror)
    __syncthreads();
    if (t == 0) {
        __threadfence();
        sOld = atomicAdd(&tcnt[b * 21 + tile], 1u);
    }
    __syncthreads();
    if (sOld == 7) {
        __threadfence();
        const int rr = t >> 1;
        const int c0w = (t & 1) * 64;
        float racc[64];
#pragma unroll
        for (int j = 0; j < 64; ++j) racc[j] = 0.f;
        for (int sp = 0; sp < 8; ++sp) {
            const unsigned short* base =
                Gp + ((size_t)(b * 8 + sp) * 21 + tile) * 16384 +
                (size_t)rr * 128 + c0w;
#pragma unroll
            for (int j = 0; j < 8; ++j) {
                uint4 qv = *(const uint4*)(base + j * 8);
                const unsigned short* pv = (const unsigned short*)&qv;
#pragma unroll
                for (int k = 0; k < 8; ++k) racc[j * 8 + k] += bf2f(pv[k]);
            }
        }
        unsigned short v[64] __attribute__((aligned(16)));
#pragma unroll
        for (int j = 0; j < 64; ++j) v[j] = f2bf(racc[j]);
        unsigned short* dstG = G + (size_t)b * 589824 +
                               (size_t)(tby * 128 + rr) * 768 + tbx * 128 + c0w;
#pragma unroll
        for (int j = 0; j < 8; ++j) *(uint4*)(dstG + j * 8) = *(uint4*)&v[j * 8];
        if (tby != tbx) {
            unsigned short* tl = (unsigned short*)smem;
#pragma unroll
            for (int j = 0; j < 8; ++j)
                *(uint4*)&tl[rr * 136 + c0w + j * 8] = *(uint4*)&v[j * 8];
            __syncthreads();
            unsigned short w[64] __attribute__((aligned(16)));
#pragma unroll
            for (int qq = 0; qq < 64; ++qq) w[qq] = tl[(c0w + qq) * 136 + rr];
            unsigned short* dm = G + (size_t)b * 589824 +
                                 (size_t)(tbx * 128 + rr) * 768 + tby * 128 + c0w;
#pragma unroll
            for (int j = 0; j < 8; ++j) *(uint4*)(dm + j * 8) = *(uint4*)&w[j * 8];
        }
    }
}

// Grid 1064 flat:
//   wg < 168:  C1+ tile: C1p = Pp ⊠ G   (id: z=wg/42, m0=((wg%42)/6)*128,
//              n0=((wg%42)%6)*128)
//   wg >= 168: c1p aux: idx=wg-168, b=idx/224, row=(idx%224)*4+wave:
//              c1p[b][row] = SCALE * Wqt+[row] . u_b
__global__ __launch_bounds__(256, 2) void c1mix(
    const unsigned short* __restrict__ Pp, const unsigned short* __restrict__ G,
    unsigned short* __restrict__ C1p, const unsigned short* __restrict__ Wqt,
    const float* __restrict__ u, float* __restrict__ c1p) {
    const int t = threadIdx.x;
    const int lane = t & 63;
    const int wave = t >> 6;
    const unsigned wg = blockIdx.x;
    if (wg >= 168) {  // c1p
        const int idx = wg - 168;
        const int b = idx / 224;
        const int row = (idx % 224) * 4 + wave;
        const float* ub = u + b * 768;
        float a = 0.f;
        for (int e = lane * 4; e < 768; e += 256) {
            const unsigned short* qr = Wqt + (size_t)row * 768 + e;
            float4 u4 = *(const float4*)(ub + e);
            a += bf2f(qr[0]) * u4.x + bf2f(qr[1]) * u4.y +
                 bf2f(qr[2]) * u4.z + bf2f(qr[3]) * u4.w;
        }
#pragma unroll
        for (int off = 32; off; off >>= 1) a += __shfl_down(a, off);
        if (lane == 0) c1p[b * 896 + row] = SCALE * a;
        return;
    }
    __shared__ __align__(16) char ldsA[16384];
    __shared__ __align__(16) char ldsB[16384];
    const int z = wg / 42;
    const int r42 = wg % 42;
    const int m0 = (r42 / 6) * 128;
    const int n0 = (r42 % 6) * 128;
    const int wm = wave >> 1;
    const int wn = wave & 1;
    const int l15 = lane & 15;
    const int khi = (lane >> 4) << 4;
    f32x4 acc[4][4];
#pragma unroll
    for (int i = 0; i < 4; ++i)
#pragma unroll
        for (int j = 0; j < 4; ++j)
            acc[i][j] = (f32x4){0.f, 0.f, 0.f, 0.f};
    gemm_core(Pp + (size_t)m0 * 768, G + (size_t)z * 589824 + (size_t)n0 * 768,
              768, 768, 768, ldsA, ldsB, wave, lane, wm, wn, l15, khi, acc);
    const int rbase = (lane >> 4) << 2;
#pragma unroll
    for (int i = 0; i < 4; ++i)
#pragma unroll
        for (int r = 0; r < 4; ++r) {
            int row = m0 + wm * 64 + i * 16 + rbase + r;
#pragma unroll
            for (int j = 0; j < 4; ++j) {
                int col = n0 + wn * 64 + j * 16 + l15;
                C1p[(size_t)z * 688128 + (size_t)row * 768 + col] =
                    f2bf(acc[i][j][r]);
            }
        }
}

extern "C" void kernel_launch(void* const* d_in, const int* in_sizes, int n_in,
                              void* d_out, int out_size, void* d_ws, size_t ws_size,
                              hipStream_t stream) {
    const float* x  = (const float*)d_in[0];
    const float* Wq = (const float*)d_in[1];
    const float* bq = (const float*)d_in[2];
    const float* Wk = (const float*)d_in[3];
    const float* bk = (const float*)d_in[4];
    const float* Wv = (const float*)d_in[5];
    const float* bv = (const float*)d_in[6];
    float* out = (float*)d_out;

    const long PB = 3145728;   // 4096*768
    const long DD = 589824;    // 768*768
    const long DA = 688128;    // 896*768

    unsigned short* ws  = (unsigned short*)d_ws;
    unsigned short* Xbf = ws;                       // 12582912
    unsigned short* Xt  = ws + 12582912;            // 12582912
    unsigned short* Pp  = ws + 25165824;            // 688128
    unsigned short* G   = ws + 25853952;            // 2359296
    unsigned short* Wqt = ws + 28213248;            // 688128 ([896][768])
    unsigned short* Wkt = ws + 28901376;            // 589824
    unsigned short* Wvb = ws + 29491200;            // 589824
    unsigned short* Gp  = ws + 30081024;            // 11010048 (21*32 tiles)
    unsigned short* C1p = Gp;                       // overlay after gram2 reduce
    unsigned short* At  = Gp + 2752512;             // 2752512
    float* fbase = (float*)(ws + 41091072);
    float* csum = fbase;                            // 3072
    unsigned int* tcnt = (unsigned int*)(fbase + 3072);  // 84 (pad 96)
    float* u    = fbase + 3168;                     // 3072
    float* c1p  = fbase + 6240;                     // 3584
    float* c2p  = fbase + 9824;                     // 896
    float* d2   = fbase + 10720;                    // 3072

    dim3 blk(256, 1, 1);

    prep_w<<<dim3(12, 12, 5), blk, 0, stream>>>(Wq, Wk, Wv, bq, Wqt, Wkt, Wvb, csum);
    prep_x<<<dim3(64, 12, 4), blk, 0, stream>>>(x, Xbf, Xt, csum);

    // P+ (first) + Gram tri partials w/ fused last-arriver reduce -> G + aux
    gram2<<<dim3(1706, 1, 1), blk, 0, stream>>>(Xt, Gp, G, tcnt, Wk, Wv, Wqt, Wkt,
                                                Pp, bk, bv, csum, u, d2, c2p);

    // C1+ = P+ ⊠ G  +  c1p aux (overlapped)
    c1mix<<<dim3(1064, 1, 1), blk, 0, stream>>>(Pp, G, C1p, Wqt, u, c1p);

    // At = Wvb ⊠ C1+ (+rank2)   [4][768][896]
    gemm_bf16<BIAS_RANK2, true><<<dim3(7, 6, 4), blk, 0, stream>>>(
        Wvb, C1p, At, bv, c1p, d2, c2p, nullptr,
        768, 768, 768, 896, 0, DA, DA, SCALE, 896);

    // out = Xbf ⊠ At (K=768) + r epilogue (At col 768)   fp32
    gemm_bf16<BIAS_RCOL, false><<<dim3(6, 32, 4), blk, 0, stream>>>(
        Xbf, At, out, nullptr, nullptr, nullptr, nullptr, At,
        768, 768, 896, 768, PB, DA, PB, 1.0f, 0);
}

// Round 4
// 153.511 us; speedup vs baseline: 1.7065x; 1.7065x over previous
//
#include <hip/hip_runtime.h>

// out = X A + 1 r^T,  A = scale Wq^T (K^T V).  With G = X^T X, s = X^T 1:
//   K^T V = Wk G Wv^T + (Wk s) bv^T + bk (Wv s)^T + S bk bv^T
// Augment Wq+ = [Wq^T; bq^T; 0pad] (896x768) so r = col 768 of At.
//   prep_w: Wqt+/Wkt/Wvb (bf16) + zero csum
//   prep_x: Xbf [4][4096][768], Xt [4][768][4096], csum atomics
//   gram2:  336 tri split-K Gram partial tiles (K=1024, split=4) + u/d2/c2p
//   redvec2: reduce Gp (4 splits) -> G (mirror); c1p; 42 P+ tiles
//   C1+ = P+ ⊠ G            [4][896][768]
//   At  = Wvb ⊠ C1+ (+rank2)[4][768][896]
//   out = Xbf ⊠ At (K=768) + At[col][768] epilogue   fp32
// GEMM: 128x128 tile, BK=64, serial 32KB-LDS loop (m97 structure),
// global_load_lds(16B) pre-swizzled source, XOR (r&7)<<4 reads,
// XCD-chunked bijective blockIdx swizzle.
// (R1: dbuf+counted-vmcnt core regressed +12us — do not re-add.
//  R2: P+ mid-pack in gram2 cost ~5us — P+ stays in redvec2.
//  R3: fused last-arriver reduce in gram2 = 6x regression — never fuse a
//  divergent heavy-register reduce tail into the MFMA kernel.)

typedef __attribute__((ext_vector_type(8))) __bf16 bf16x8;
typedef __attribute__((ext_vector_type(4))) float f32x4;

#define SCALE 0.03608439182435161f

union FragU {
    uint4 q;
    bf16x8 f;
    unsigned short s[8];
};

__device__ __forceinline__ unsigned short f2bf(float x) {
    unsigned int u = __builtin_bit_cast(unsigned int, x);
    u = (u + 0x7fffu + ((u >> 16) & 1u)) >> 16;
    return (unsigned short)u;
}
__device__ __forceinline__ float bf2f(unsigned short u) {
    unsigned int v = ((unsigned int)u) << 16;
    return __builtin_bit_cast(float, v);
}

__device__ __forceinline__ unsigned xcd_swizzle(unsigned lin, unsigned nwg) {
    const unsigned q = nwg >> 3, rr8 = nwg & 7;
    const unsigned xcd = lin & 7, o = lin >> 3;
    return (xcd < rr8 ? xcd * (q + 1) : rr8 * (q + 1) + (xcd - rr8) * q) + o;
}

__device__ __forceinline__ void stage_gl(const unsigned short* __restrict__ srcRowBase,
                                         int ldElems, char* lds, int wave, int lane) {
#pragma unroll
    for (int p = 0; p < 4; ++p) {
        int slotbase = (wave * 4 + p) * 1024;
        int slot = slotbase + lane * 16;
        int r = slot >> 7;
        int cb = (slot & 127) ^ ((r & 7) << 4);
        const char* g = (const char*)(srcRowBase + (size_t)r * ldElems) + cb;
        __builtin_amdgcn_global_load_lds(
            (const __attribute__((address_space(1))) unsigned int*)g,
            (__attribute__((address_space(3))) unsigned int*)(lds + slotbase),
            16, 0, 0);
    }
}

__device__ __forceinline__ bf16x8 load_frag(const char* lds, int row, int kbyte) {
    int a = row * 128 + kbyte;
    a ^= (row & 7) << 4;
    FragU u;
    u.q = *(const uint4*)(lds + a);
    return u.f;
}

__device__ __forceinline__ void gemm_core(const unsigned short* __restrict__ Ab,
                                          const unsigned short* __restrict__ Bb,
                                          int K, int lda, int ldb,
                                          char* ldsA, char* ldsB,
                                          int wave, int lane, int wm, int wn,
                                          int l15, int khi, f32x4 (&acc)[4][4]) {
    for (int k0 = 0; k0 < K; k0 += 64) {
        stage_gl(Ab + k0, lda, ldsA, wave, lane);
        stage_gl(Bb + k0, ldb, ldsB, wave, lane);
        __syncthreads();
#pragma unroll
        for (int kk = 0; kk < 2; ++kk) {
            const int kbyte = kk * 64 + khi;
            bf16x8 af[4], bfr[4];
#pragma unroll
            for (int i = 0; i < 4; ++i)
                af[i] = load_frag(ldsA, wm * 64 + i * 16 + l15, kbyte);
#pragma unroll
            for (int j = 0; j < 4; ++j)
                bfr[j] = load_frag(ldsB, wn * 64 + j * 16 + l15, kbyte);
#pragma unroll
            for (int i = 0; i < 4; ++i)
#pragma unroll
                for (int j = 0; j < 4; ++j)
                    acc[i][j] = __builtin_amdgcn_mfma_f32_16x16x32_bf16(
                        af[i], bfr[j], acc[i][j], 0, 0, 0);
        }
        __syncthreads();
    }
}

enum { BIAS_NONE = 0, BIAS_RANK2 = 2, BIAS_RCOL = 3 };

template <int BIASM, bool OUT_BF16>
__global__ __launch_bounds__(256, 2) void gemm_bf16(
    const unsigned short* __restrict__ A, const unsigned short* __restrict__ B,
    void* __restrict__ C,
    const float* __restrict__ p0, const float* __restrict__ p1,
    const float* __restrict__ p2, const float* __restrict__ p3,
    const unsigned short* __restrict__ rsrc,
    int K, int lda, int ldb, int ldc, long bsA, long bsB, long bsC,
    float scale, int vld1) {
    __shared__ __align__(16) char ldsA[16384];
    __shared__ __align__(16) char ldsB[16384];

    const unsigned gx = gridDim.x, gy = gridDim.y;
    const unsigned lin = blockIdx.x + gx * (blockIdx.y + gy * blockIdx.z);
    const unsigned wg = xcd_swizzle(lin, gx * gy * gridDim.z);
    const int bx = wg % gx;
    const int by = (wg / gx) % gy;
    const int z = wg / (gx * gy);

    const int m0 = by * 128;
    const int n0 = bx * 128;
    const unsigned short* Ab = A + (size_t)z * bsA + (size_t)m0 * lda;
    const unsigned short* Bb = B + (size_t)z * bsB + (size_t)n0 * ldb;

    const int lane = threadIdx.x & 63;
    const int wave = threadIdx.x >> 6;
    const int wm = wave >> 1;
    const int wn = wave & 1;
    const int l15 = lane & 15;
    const int khi = (lane >> 4) << 4;

    f32x4 acc[4][4];
#pragma unroll
    for (int i = 0; i < 4; ++i)
#pragma unroll
        for (int j = 0; j < 4; ++j)
            acc[i][j] = (f32x4){0.f, 0.f, 0.f, 0.f};

    gemm_core(Ab, Bb, K, lda, ldb, ldsA, ldsB, wave, lane, wm, wn, l15, khi, acc);

    const int rbase = (lane >> 4) << 2;
#pragma unroll
    for (int i = 0; i < 4; ++i) {
#pragma unroll
        for (int r = 0; r < 4; ++r) {
            int row = m0 + wm * 64 + i * 16 + rbase + r;
            float rA = 0.f, rB = 0.f;
            if (BIASM == BIAS_RANK2) {
                rA = p0[row];
                rB = p2[z * 768 + row];
            }
#pragma unroll
            for (int j = 0; j < 4; ++j) {
                int col = n0 + wn * 64 + j * 16 + l15;
                float v = acc[i][j][r] * scale;
                if (BIASM == BIAS_RANK2) v += rA * p1[z * vld1 + col] + rB * p3[col];
                if (BIASM == BIAS_RCOL)
                    v += bf2f(rsrc[(size_t)z * 688128 + (size_t)col * 896 + 768]);
                size_t off = (size_t)z * bsC + (size_t)row * ldc + col;
                if (OUT_BF16)
                    ((unsigned short*)C)[off] = f2bf(v);
                else
                    ((float*)C)[off] = v;
            }
        }
    }
}

// z=0: Wqt+ rows 0..767 = Wq^T; z=1: Wkt = Wk^T; z=2: Wvb = bf16(Wv);
// z=3: Wqt+ row 768 = bq, rows 769..895 = 0; z=4: zero csum.
__global__ __launch_bounds__(256) void prep_w(const float* __restrict__ Wq,
                                              const float* __restrict__ Wk,
                                              const float* __restrict__ Wv,
                                              const float* __restrict__ bq,
                                              unsigned short* __restrict__ Wqt,
                                              unsigned short* __restrict__ Wkt,
                                              unsigned short* __restrict__ Wvb,
                                              float* __restrict__ csum) {
    const int mode = blockIdx.z;
    const int t = threadIdx.x;
    if (mode == 4) {
        if (blockIdx.x == 0 && blockIdx.y == 0) {
            float4 z4 = {0.f, 0.f, 0.f, 0.f};
            for (int i = t * 4; i < 3072; i += 1024) *(float4*)(csum + i) = z4;
        }
        return;
    }
    if (mode == 3) {
        if (blockIdx.y) return;
        int rr = 768 + (t >> 1);
        int c0 = blockIdx.x * 64 + (t & 1) * 32;
        unsigned short v[32] __attribute__((aligned(16)));
        if (rr == 768) {
#pragma unroll
            for (int j = 0; j < 32; ++j) v[j] = f2bf(bq[c0 + j]);
        } else {
#pragma unroll
            for (int j = 0; j < 32; ++j) v[j] = 0;
        }
        unsigned short* dst = Wqt + (size_t)rr * 768 + c0;
#pragma unroll
        for (int j = 0; j < 4; ++j) *(uint4*)(dst + j * 8) = *(uint4*)&v[j * 8];
        return;
    }
    __shared__ unsigned short tile[64 * 72];
    const float* src = mode == 0 ? Wq : (mode == 1 ? Wk : Wv);
    const int r0 = blockIdx.x * 64;
    const int c0 = blockIdx.y * 64;
    int r = t >> 2, cq = (t & 3) * 16;
    unsigned short v[16] __attribute__((aligned(16)));
    const float* s = src + (size_t)(r0 + r) * 768 + c0 + cq;
#pragma unroll
    for (int j = 0; j < 16; j += 4) {
        float4 f = *(const float4*)(s + j);
        v[j] = f2bf(f.x); v[j + 1] = f2bf(f.y);
        v[j + 2] = f2bf(f.z); v[j + 3] = f2bf(f.w);
    }
    if (mode == 2) {
        unsigned short* dst = Wvb + (size_t)(r0 + r) * 768 + c0 + cq;
        *(uint4*)dst = *(uint4*)&v[0];
        *(uint4*)(dst + 8) = *(uint4*)&v[8];
        return;
    }
    *(uint4*)&tile[r * 72 + cq] = *(uint4*)&v[0];
    *(uint4*)&tile[r * 72 + cq + 8] = *(uint4*)&v[8];
    __syncthreads();
    int dr = t >> 2, sq = (t & 3) * 16;
    unsigned short w[16] __attribute__((aligned(16)));
#pragma unroll
    for (int j = 0; j < 16; ++j) w[j] = tile[(sq + j) * 72 + dr];
    unsigned short* dst = (mode == 0 ? Wqt : Wkt) + (size_t)(c0 + dr) * 768 + r0 + sq;
    *(uint4*)dst = *(uint4*)&w[0];
    *(uint4*)(dst + 8) = *(uint4*)&w[8];
}

// Xbf [4][4096][768], Xt [4][768][4096], csum atomics.
__global__ __launch_bounds__(256) void prep_x(const float* __restrict__ X,
                                              unsigned short* __restrict__ Xbf,
                                              unsigned short* __restrict__ Xt,
                                              float* __restrict__ csum) {
    const int b = blockIdx.z;
    const int s0 = blockIdx.x * 64;
    const int t = threadIdx.x;
    __shared__ unsigned short tile[64 * 72];
    const int d0 = blockIdx.y * 64;
    const float* Xb = X + (size_t)b * 4096 * 768;
    unsigned short* XbfB = Xbf + (size_t)b * 4096 * 768;
    unsigned short* XtB = Xt + (size_t)b * 768 * 4096;
    {
        int r = t >> 2, cq = (t & 3) * 16;
        const float* src = Xb + (size_t)(s0 + r) * 768 + d0 + cq;
        unsigned short v[16] __attribute__((aligned(16)));
#pragma unroll
        for (int j = 0; j < 16; j += 4) {
            float4 f = *(const float4*)(src + j);
            v[j] = f2bf(f.x); v[j + 1] = f2bf(f.y);
            v[j + 2] = f2bf(f.z); v[j + 3] = f2bf(f.w);
        }
        unsigned short* dst = XbfB + (size_t)(s0 + r) * 768 + d0 + cq;
        *(uint4*)dst = *(uint4*)&v[0];
        *(uint4*)(dst + 8) = *(uint4*)&v[8];
        *(uint4*)&tile[r * 72 + cq] = *(uint4*)&v[0];
        *(uint4*)&tile[r * 72 + cq + 8] = *(uint4*)&v[8];
    }
    __syncthreads();
    {
        int dr = t >> 2, sq = (t & 3) * 16;
        unsigned short v[16] __attribute__((aligned(16)));
        float part = 0.f;
#pragma unroll
        for (int j = 0; j < 16; ++j) {
            unsigned short u = tile[(sq + j) * 72 + dr];
            v[j] = u;
            part += bf2f(u);
        }
        unsigned short* dst = XtB + (size_t)(d0 + dr) * 4096 + s0 + sq;
        *(uint4*)dst = *(uint4*)&v[0];
        *(uint4*)(dst + 8) = *(uint4*)&v[8];
        part += __shfl_down(part, 1);
        part += __shfl_down(part, 2);
        if ((t & 3) == 0) atomicAdd(&csum[b * 768 + d0 + dr], part);
    }
}

// Flat grid 1328:
//   wg <  336: triangular Gram partial tile (tile=wg%21, zz=wg/21; b=zz>>2,
//              split=zz&3, K=1024) -> packed Gp
//   wg < 1104: aux u/d2: id=wg-336, b=id/192, row=(id%192)*4+wave:
//              u[b][row]=Wk[row].s_b ; d2[b][row]=SCALE*(Wv[row].s_b+4096 bv)
//   wg >=1104: c2p: row=(wg-1104)*4+wave (<896): c2p[row]=Wqt+[row].bk
__global__ __launch_bounds__(256, 2) void gram2(
    const unsigned short* __restrict__ Xt, unsigned short* __restrict__ Gp,
    const float* __restrict__ Wk, const float* __restrict__ Wv,
    const unsigned short* __restrict__ Wqt,
    const float* __restrict__ bk, const float* __restrict__ bv,
    const float* __restrict__ csum,
    float* __restrict__ u, float* __restrict__ d2, float* __restrict__ c2p) {
    const long PB = 3145728;
    const unsigned wg = xcd_swizzle(blockIdx.x, gridDim.x);
    const int t = threadIdx.x;
    const int lane = t & 63;
    const int wave = t >> 6;

    if (wg >= 1104) {  // c2p
        const int row = (wg - 1104) * 4 + wave;
        float a = 0.f;
        for (int e = lane * 4; e < 768; e += 256) {
            const unsigned short* qr = Wqt + (size_t)row * 768 + e;
            float4 b4 = *(const float4*)(bk + e);
            a += bf2f(qr[0]) * b4.x + bf2f(qr[1]) * b4.y +
                 bf2f(qr[2]) * b4.z + bf2f(qr[3]) * b4.w;
        }
#pragma unroll
        for (int off = 32; off; off >>= 1) a += __shfl_down(a, off);
        if (lane == 0) c2p[row] = a;
        return;
    }
    if (wg >= 336) {  // u + d2
        const int id = wg - 336;
        const int b = id / 192;
        const int row = (id % 192) * 4 + wave;
        const float* s = csum + b * 768;
        float aU = 0.f, aD = 0.f;
        for (int e = lane * 4; e < 768; e += 256) {
            float4 wk4 = *(const float4*)(Wk + (size_t)row * 768 + e);
            float4 wv4 = *(const float4*)(Wv + (size_t)row * 768 + e);
            float4 s4 = *(const float4*)(s + e);
            aU += wk4.x * s4.x + wk4.y * s4.y + wk4.z * s4.z + wk4.w * s4.w;
            aD += wv4.x * s4.x + wv4.y * s4.y + wv4.z * s4.z + wv4.w * s4.w;
        }
#pragma unroll
        for (int off = 32; off; off >>= 1) {
            aU += __shfl_down(aU, off);
            aD += __shfl_down(aD, off);
        }
        if (lane == 0) {
            u[b * 768 + row] = aU;
            d2[b * 768 + row] = SCALE * (aD + 4096.f * bv[row]);
        }
        return;
    }

    __shared__ __align__(16) char ldsA[16384];
    __shared__ __align__(16) char ldsB[16384];
    const int wm = wave >> 1;
    const int wn = wave & 1;
    const int l15 = lane & 15;
    const int khi = (lane >> 4) << 4;
    f32x4 acc[4][4];
#pragma unroll
    for (int i = 0; i < 4; ++i)
#pragma unroll
        for (int j = 0; j < 4; ++j)
            acc[i][j] = (f32x4){0.f, 0.f, 0.f, 0.f};
    const int rbase = (lane >> 4) << 2;

    const int tile = wg % 21;
    const int zz = wg / 21;
    const int b = zz >> 2;
    const int koff = (zz & 3) * 1024;
    int tt = tile, tby = 0;
    while (tt >= 6 - tby) { tt -= 6 - tby; ++tby; }
    const int m0 = tby * 128;
    const int n0 = (tby + tt) * 128;
    const unsigned short* Ab = Xt + (size_t)b * PB + (size_t)m0 * 4096 + koff;
    const unsigned short* Bb = Xt + (size_t)b * PB + (size_t)n0 * 4096 + koff;
    gemm_core(Ab, Bb, 1024, 4096, 4096, ldsA, ldsB, wave, lane, wm, wn, l15, khi, acc);
    unsigned short* dst = Gp + ((size_t)zz * 21 + tile) * 16384;
#pragma unroll
    for (int i = 0; i < 4; ++i)
#pragma unroll
        for (int r = 0; r < 4; ++r) {
            int rloc = wm * 64 + i * 16 + rbase + r;
#pragma unroll
            for (int j = 0; j < 4; ++j) {
                int cloc = wn * 64 + j * 16 + l15;
                dst[(size_t)rloc * 128 + cloc] = f2bf(acc[i][j][r]);
            }
        }
}

// grid (287,4):
//   x<21: reduce Gp (4 splits) -> G tile, mirror off-diag (y=b)
//   21<=x<245: c1p[b][row] = SCALE * Wqt+[row] . u_b   (row=(x-21)*4+wave)
//   x>=245 && y==0: P+ tile id=x-245 (7x6, K=768) -> Pp
__global__ __launch_bounds__(256, 2) void redvec2(
    const unsigned short* __restrict__ Gp, unsigned short* __restrict__ G,
    const unsigned short* __restrict__ Wqt, const unsigned short* __restrict__ Wkt,
    unsigned short* __restrict__ Pp,
    const float* __restrict__ u, float* __restrict__ c1p) {
    const int b = blockIdx.y;
    const int t = threadIdx.x;
    const int lane = t & 63;
    const int wave = t >> 6;
    if (blockIdx.x >= 245) {
        if (b) return;
        __shared__ __align__(16) char ldsA[16384];
        __shared__ __align__(16) char ldsB[16384];
        const int id = blockIdx.x - 245;
        const int m0 = (id / 6) * 128;
        const int n0 = (id % 6) * 128;
        const int wm = wave >> 1;
        const int wn = wave & 1;
        const int l15 = lane & 15;
        const int khi = (lane >> 4) << 4;
        f32x4 acc[4][4];
#pragma unroll
        for (int i = 0; i < 4; ++i)
#pragma unroll
            for (int j = 0; j < 4; ++j)
                acc[i][j] = (f32x4){0.f, 0.f, 0.f, 0.f};
        gemm_core(Wqt + (size_t)m0 * 768, Wkt + (size_t)n0 * 768,
                  768, 768, 768, ldsA, ldsB, wave, lane, wm, wn, l15, khi, acc);
        const int rbase = (lane >> 4) << 2;
#pragma unroll
        for (int i = 0; i < 4; ++i)
#pragma unroll
            for (int r = 0; r < 4; ++r) {
                int row = m0 + wm * 64 + i * 16 + rbase + r;
#pragma unroll
                for (int j = 0; j < 4; ++j) {
                    int col = n0 + wn * 64 + j * 16 + l15;
                    Pp[(size_t)row * 768 + col] = f2bf(acc[i][j][r]);
                }
            }
        return;
    }
    if (blockIdx.x >= 21) {  // c1p
        const int row = (blockIdx.x - 21) * 4 + wave;
        const float* ub = u + b * 768;
        float a = 0.f;
        for (int e = lane * 4; e < 768; e += 256) {
            const unsigned short* qr = Wqt + (size_t)row * 768 + e;
            float4 u4 = *(const float4*)(ub + e);
            a += bf2f(qr[0]) * u4.x + bf2f(qr[1]) * u4.y +
                 bf2f(qr[2]) * u4.z + bf2f(qr[3]) * u4.w;
        }
#pragma unroll
        for (int off = 32; off; off >>= 1) a += __shfl_down(a, off);
        if (lane == 0) c1p[b * 896 + row] = SCALE * a;
        return;
    }
    __shared__ unsigned short tl[128 * 136];
    const int tile = blockIdx.x;
    int tt = tile, tby = 0;
    while (tt >= 6 - tby) { tt -= 6 - tby; ++tby; }
    const int tbx = tby + tt;
    const int r = t >> 1;
    const int c0 = (t & 1) * 64;
    float acc[64];
#pragma unroll
    for (int j = 0; j < 64; ++j) acc[j] = 0.f;
    for (int sp = 0; sp < 4; ++sp) {
        const unsigned short* base =
            Gp + ((size_t)(b * 4 + sp) * 21 + tile) * 16384 + (size_t)r * 128 + c0;
#pragma unroll
        for (int j = 0; j < 8; ++j) {
            uint4 qv = *(const uint4*)(base + j * 8);
            const unsigned short* pv = (const unsigned short*)&qv;
#pragma unroll
            for (int k = 0; k < 8; ++k) acc[j * 8 + k] += bf2f(pv[k]);
        }
    }
    unsigned short v[64] __attribute__((aligned(16)));
#pragma unroll
    for (int j = 0; j < 64; ++j) v[j] = f2bf(acc[j]);
    unsigned short* dst = G + (size_t)b * 589824 +
                          (size_t)(tby * 128 + r) * 768 + tbx * 128 + c0;
#pragma unroll
    for (int j = 0; j < 8; ++j) *(uint4*)(dst + j * 8) = *(uint4*)&v[j * 8];
    if (tby != tbx) {
#pragma unroll
        for (int j = 0; j < 8; ++j)
            *(uint4*)&tl[r * 136 + c0 + j * 8] = *(uint4*)&v[j * 8];
        __syncthreads();
        unsigned short w[64] __attribute__((aligned(16)));
#pragma unroll
        for (int qq = 0; qq < 64; ++qq) w[qq] = tl[(c0 + qq) * 136 + r];
        unsigned short* dm = G + (size_t)b * 589824 +
                             (size_t)(tbx * 128 + r) * 768 + tby * 128 + c0;
#pragma unroll
        for (int j = 0; j < 8; ++j) *(uint4*)(dm + j * 8) = *(uint4*)&w[j * 8];
    }
}

extern "C" void kernel_launch(void* const* d_in, const int* in_sizes, int n_in,
                              void* d_out, int out_size, void* d_ws, size_t ws_size,
                              hipStream_t stream) {
    const float* x  = (const float*)d_in[0];
    const float* Wq = (const float*)d_in[1];
    const float* bq = (const float*)d_in[2];
    const float* Wk = (const float*)d_in[3];
    const float* bk = (const float*)d_in[4];
    const float* Wv = (const float*)d_in[5];
    const float* bv = (const float*)d_in[6];
    float* out = (float*)d_out;

    const long PB = 3145728;   // 4096*768
    const long DD = 589824;    // 768*768
    const long DA = 688128;    // 896*768

    unsigned short* ws  = (unsigned short*)d_ws;
    unsigned short* Xbf = ws;                       // 12582912
    unsigned short* Xt  = ws + 12582912;            // 12582912
    unsigned short* Pp  = ws + 25165824;            // 688128
    unsigned short* G   = ws + 25853952;            // 2359296
    unsigned short* Wqt = ws + 28213248;            // 688128 ([896][768])
    unsigned short* Wkt = ws + 28901376;            // 589824
    unsigned short* Wvb = ws + 29491200;            // 589824
    unsigned short* Gp  = ws + 30081024;            // 5505024 (21*16 tiles)
    unsigned short* C1p = Gp;                       // overlay after redvec2
    unsigned short* At  = Gp + 2752512;             // 2752512
    float* fbase = (float*)(ws + 41091072);
    float* csum = fbase;                            // 3072
    float* u    = fbase + 3072;                     // 3072
    float* c1p  = fbase + 6144;                     // 3584
    float* c2p  = fbase + 9728;                     // 896
    float* d2   = fbase + 10624;                    // 3072

    dim3 blk(256, 1, 1);

    prep_w<<<dim3(12, 12, 5), blk, 0, stream>>>(Wq, Wk, Wv, bq, Wqt, Wkt, Wvb, csum);
    prep_x<<<dim3(64, 12, 4), blk, 0, stream>>>(x, Xbf, Xt, csum);

    // Gram tri split-K partials (split=4, K=1024) + u/d2 + c2p aux
    gram2<<<dim3(1328, 1, 1), blk, 0, stream>>>(Xt, Gp, Wk, Wv, Wqt, bk, bv,
                                                csum, u, d2, c2p);

    // reduce G (4 splits) + c1p + P+
    redvec2<<<dim3(287, 4), blk, 0, stream>>>(Gp, G, Wqt, Wkt, Pp, u, c1p);

    // C1+ = P+ ⊠ G   [4][896][768]
    gemm_bf16<BIAS_NONE, true><<<dim3(6, 7, 4), blk, 0, stream>>>(
        Pp, G, C1p, nullptr, nullptr, nullptr, nullptr, nullptr,
        768, 768, 768, 768, 0, DD, DA, 1.0f, 0);

    // At = Wvb ⊠ C1+ (+rank2)   [4][768][896]
    gemm_bf16<BIAS_RANK2, true><<<dim3(7, 6, 4), blk, 0, stream>>>(
        Wvb, C1p, At, bv, c1p, d2, c2p, nullptr,
        768, 768, 768, 896, 0, DA, DA, SCALE, 896);

    // out = Xbf ⊠ At (K=768) + r epilogue (At col 768)   fp32
    gemm_bf16<BIAS_RCOL, false><<<dim3(6, 32, 4), blk, 0, stream>>>(
        Xbf, At, out, nullptr, nullptr, nullptr, nullptr, At,
        768, 768, 896, 768, PB, DA, PB, 1.0f, 0);
}

// Round 5
// 146.263 us; speedup vs baseline: 1.7911x; 1.0496x over previous
//
#include <hip/hip_runtime.h>

// out = X A + 1 r^T,  A = scale Wq^T (K^T V).  With G = X^T X, s = X^T 1:
//   K^T V = Wk G Wv^T + (Wk s) bv^T + bk (Wv s)^T + S bk bv^T
// Augment Wq+ = [Wq^T; bq^T; 0pad] (896x768) so r = col 768 of At.
//   prep_w: Wqt+/Wkt/Wvb (bf16) + zero csum
//   prep_x: Xbf [4][4096][768], Xt [4][768][4096], csum atomics
//   gram2:  1344 tri split-K Gram partial tiles (K=256, split=16) + u/d2/c2p
//   redvec2: reduce Gp (16 splits) -> G (mirror); c1p; 42 P+ tiles
//   C1+ = P+ ⊠ G            [4][896][768]
//   At  = Wvb ⊠ C1+ (+rank2)[4][768][896]
//   out = Xbf ⊠ At (K=768) + At[col][768] epilogue   fp32
// GEMM: 128x128 tile, BK=64, serial 32KB-LDS loop (m97 structure),
// global_load_lds(16B) pre-swizzled source, XOR (r&7)<<4 reads,
// XCD-chunked bijective blockIdx swizzle.
// (R1: dbuf+counted-vmcnt core regressed +12us — do not re-add.
//  R2: P+ mid-pack in gram2 cost ~5us — P+ stays in redvec2.
//  R3: fused last-arriver reduce in gram2 = 6x regression — never fuse.
//  R4: split=4 (336 blocks, 1.3/CU) = gram2 52us, all counters <8% —
//  gram2 is LATENCY-bound on L2-resident Xt; time scales with heavy
//  blocks/CU. Hence split=16: 1344 blocks ~= 4/CU (LDS/VGPR cap).)

typedef __attribute__((ext_vector_type(8))) __bf16 bf16x8;
typedef __attribute__((ext_vector_type(4))) float f32x4;

#define SCALE 0.03608439182435161f

union FragU {
    uint4 q;
    bf16x8 f;
    unsigned short s[8];
};

__device__ __forceinline__ unsigned short f2bf(float x) {
    unsigned int u = __builtin_bit_cast(unsigned int, x);
    u = (u + 0x7fffu + ((u >> 16) & 1u)) >> 16;
    return (unsigned short)u;
}
__device__ __forceinline__ float bf2f(unsigned short u) {
    unsigned int v = ((unsigned int)u) << 16;
    return __builtin_bit_cast(float, v);
}

__device__ __forceinline__ unsigned xcd_swizzle(unsigned lin, unsigned nwg) {
    const unsigned q = nwg >> 3, rr8 = nwg & 7;
    const unsigned xcd = lin & 7, o = lin >> 3;
    return (xcd < rr8 ? xcd * (q + 1) : rr8 * (q + 1) + (xcd - rr8) * q) + o;
}

__device__ __forceinline__ void stage_gl(const unsigned short* __restrict__ srcRowBase,
                                         int ldElems, char* lds, int wave, int lane) {
#pragma unroll
    for (int p = 0; p < 4; ++p) {
        int slotbase = (wave * 4 + p) * 1024;
        int slot = slotbase + lane * 16;
        int r = slot >> 7;
        int cb = (slot & 127) ^ ((r & 7) << 4);
        const char* g = (const char*)(srcRowBase + (size_t)r * ldElems) + cb;
        __builtin_amdgcn_global_load_lds(
            (const __attribute__((address_space(1))) unsigned int*)g,
            (__attribute__((address_space(3))) unsigned int*)(lds + slotbase),
            16, 0, 0);
    }
}

__device__ __forceinline__ bf16x8 load_frag(const char* lds, int row, int kbyte) {
    int a = row * 128 + kbyte;
    a ^= (row & 7) << 4;
    FragU u;
    u.q = *(const uint4*)(lds + a);
    return u.f;
}

__device__ __forceinline__ void gemm_core(const unsigned short* __restrict__ Ab,
                                          const unsigned short* __restrict__ Bb,
                                          int K, int lda, int ldb,
                                          char* ldsA, char* ldsB,
                                          int wave, int lane, int wm, int wn,
                                          int l15, int khi, f32x4 (&acc)[4][4]) {
    for (int k0 = 0; k0 < K; k0 += 64) {
        stage_gl(Ab + k0, lda, ldsA, wave, lane);
        stage_gl(Bb + k0, ldb, ldsB, wave, lane);
        __syncthreads();
#pragma unroll
        for (int kk = 0; kk < 2; ++kk) {
            const int kbyte = kk * 64 + khi;
            bf16x8 af[4], bfr[4];
#pragma unroll
            for (int i = 0; i < 4; ++i)
                af[i] = load_frag(ldsA, wm * 64 + i * 16 + l15, kbyte);
#pragma unroll
            for (int j = 0; j < 4; ++j)
                bfr[j] = load_frag(ldsB, wn * 64 + j * 16 + l15, kbyte);
#pragma unroll
            for (int i = 0; i < 4; ++i)
#pragma unroll
                for (int j = 0; j < 4; ++j)
                    acc[i][j] = __builtin_amdgcn_mfma_f32_16x16x32_bf16(
                        af[i], bfr[j], acc[i][j], 0, 0, 0);
        }
        __syncthreads();
    }
}

enum { BIAS_NONE = 0, BIAS_RANK2 = 2, BIAS_RCOL = 3 };

template <int BIASM, bool OUT_BF16>
__global__ __launch_bounds__(256, 2) void gemm_bf16(
    const unsigned short* __restrict__ A, const unsigned short* __restrict__ B,
    void* __restrict__ C,
    const float* __restrict__ p0, const float* __restrict__ p1,
    const float* __restrict__ p2, const float* __restrict__ p3,
    const unsigned short* __restrict__ rsrc,
    int K, int lda, int ldb, int ldc, long bsA, long bsB, long bsC,
    float scale, int vld1) {
    __shared__ __align__(16) char ldsA[16384];
    __shared__ __align__(16) char ldsB[16384];

    const unsigned gx = gridDim.x, gy = gridDim.y;
    const unsigned lin = blockIdx.x + gx * (blockIdx.y + gy * blockIdx.z);
    const unsigned wg = xcd_swizzle(lin, gx * gy * gridDim.z);
    const int bx = wg % gx;
    const int by = (wg / gx) % gy;
    const int z = wg / (gx * gy);

    const int m0 = by * 128;
    const int n0 = bx * 128;
    const unsigned short* Ab = A + (size_t)z * bsA + (size_t)m0 * lda;
    const unsigned short* Bb = B + (size_t)z * bsB + (size_t)n0 * ldb;

    const int lane = threadIdx.x & 63;
    const int wave = threadIdx.x >> 6;
    const int wm = wave >> 1;
    const int wn = wave & 1;
    const int l15 = lane & 15;
    const int khi = (lane >> 4) << 4;

    f32x4 acc[4][4];
#pragma unroll
    for (int i = 0; i < 4; ++i)
#pragma unroll
        for (int j = 0; j < 4; ++j)
            acc[i][j] = (f32x4){0.f, 0.f, 0.f, 0.f};

    gemm_core(Ab, Bb, K, lda, ldb, ldsA, ldsB, wave, lane, wm, wn, l15, khi, acc);

    const int rbase = (lane >> 4) << 2;
#pragma unroll
    for (int i = 0; i < 4; ++i) {
#pragma unroll
        for (int r = 0; r < 4; ++r) {
            int row = m0 + wm * 64 + i * 16 + rbase + r;
            float rA = 0.f, rB = 0.f;
            if (BIASM == BIAS_RANK2) {
                rA = p0[row];
                rB = p2[z * 768 + row];
            }
#pragma unroll
            for (int j = 0; j < 4; ++j) {
                int col = n0 + wn * 64 + j * 16 + l15;
                float v = acc[i][j][r] * scale;
                if (BIASM == BIAS_RANK2) v += rA * p1[z * vld1 + col] + rB * p3[col];
                if (BIASM == BIAS_RCOL)
                    v += bf2f(rsrc[(size_t)z * 688128 + (size_t)col * 896 + 768]);
                size_t off = (size_t)z * bsC + (size_t)row * ldc + col;
                if (OUT_BF16)
                    ((unsigned short*)C)[off] = f2bf(v);
                else
                    ((float*)C)[off] = v;
            }
        }
    }
}

// z=0: Wqt+ rows 0..767 = Wq^T; z=1: Wkt = Wk^T; z=2: Wvb = bf16(Wv);
// z=3: Wqt+ row 768 = bq, rows 769..895 = 0; z=4: zero csum.
__global__ __launch_bounds__(256) void prep_w(const float* __restrict__ Wq,
                                              const float* __restrict__ Wk,
                                              const float* __restrict__ Wv,
                                              const float* __restrict__ bq,
                                              unsigned short* __restrict__ Wqt,
                                              unsigned short* __restrict__ Wkt,
                                              unsigned short* __restrict__ Wvb,
                                              float* __restrict__ csum) {
    const int mode = blockIdx.z;
    const int t = threadIdx.x;
    if (mode == 4) {
        if (blockIdx.x == 0 && blockIdx.y == 0) {
            float4 z4 = {0.f, 0.f, 0.f, 0.f};
            for (int i = t * 4; i < 3072; i += 1024) *(float4*)(csum + i) = z4;
        }
        return;
    }
    if (mode == 3) {
        if (blockIdx.y) return;
        int rr = 768 + (t >> 1);
        int c0 = blockIdx.x * 64 + (t & 1) * 32;
        unsigned short v[32] __attribute__((aligned(16)));
        if (rr == 768) {
#pragma unroll
            for (int j = 0; j < 32; ++j) v[j] = f2bf(bq[c0 + j]);
        } else {
#pragma unroll
            for (int j = 0; j < 32; ++j) v[j] = 0;
        }
        unsigned short* dst = Wqt + (size_t)rr * 768 + c0;
#pragma unroll
        for (int j = 0; j < 4; ++j) *(uint4*)(dst + j * 8) = *(uint4*)&v[j * 8];
        return;
    }
    __shared__ unsigned short tile[64 * 72];
    const float* src = mode == 0 ? Wq : (mode == 1 ? Wk : Wv);
    const int r0 = blockIdx.x * 64;
    const int c0 = blockIdx.y * 64;
    int r = t >> 2, cq = (t & 3) * 16;
    unsigned short v[16] __attribute__((aligned(16)));
    const float* s = src + (size_t)(r0 + r) * 768 + c0 + cq;
#pragma unroll
    for (int j = 0; j < 16; j += 4) {
        float4 f = *(const float4*)(s + j);
        v[j] = f2bf(f.x); v[j + 1] = f2bf(f.y);
        v[j + 2] = f2bf(f.z); v[j + 3] = f2bf(f.w);
    }
    if (mode == 2) {
        unsigned short* dst = Wvb + (size_t)(r0 + r) * 768 + c0 + cq;
        *(uint4*)dst = *(uint4*)&v[0];
        *(uint4*)(dst + 8) = *(uint4*)&v[8];
        return;
    }
    *(uint4*)&tile[r * 72 + cq] = *(uint4*)&v[0];
    *(uint4*)&tile[r * 72 + cq + 8] = *(uint4*)&v[8];
    __syncthreads();
    int dr = t >> 2, sq = (t & 3) * 16;
    unsigned short w[16] __attribute__((aligned(16)));
#pragma unroll
    for (int j = 0; j < 16; ++j) w[j] = tile[(sq + j) * 72 + dr];
    unsigned short* dst = (mode == 0 ? Wqt : Wkt) + (size_t)(c0 + dr) * 768 + r0 + sq;
    *(uint4*)dst = *(uint4*)&w[0];
    *(uint4*)(dst + 8) = *(uint4*)&w[8];
}

// Xbf [4][4096][768], Xt [4][768][4096], csum atomics.
__global__ __launch_bounds__(256) void prep_x(const float* __restrict__ X,
                                              unsigned short* __restrict__ Xbf,
                                              unsigned short* __restrict__ Xt,
                                              float* __restrict__ csum) {
    const int b = blockIdx.z;
    const int s0 = blockIdx.x * 64;
    const int t = threadIdx.x;
    __shared__ unsigned short tile[64 * 72];
    const int d0 = blockIdx.y * 64;
    const float* Xb = X + (size_t)b * 4096 * 768;
    unsigned short* XbfB = Xbf + (size_t)b * 4096 * 768;
    unsigned short* XtB = Xt + (size_t)b * 768 * 4096;
    {
        int r = t >> 2, cq = (t & 3) * 16;
        const float* src = Xb + (size_t)(s0 + r) * 768 + d0 + cq;
        unsigned short v[16] __attribute__((aligned(16)));
#pragma unroll
        for (int j = 0; j < 16; j += 4) {
            float4 f = *(const float4*)(src + j);
            v[j] = f2bf(f.x); v[j + 1] = f2bf(f.y);
            v[j + 2] = f2bf(f.z); v[j + 3] = f2bf(f.w);
        }
        unsigned short* dst = XbfB + (size_t)(s0 + r) * 768 + d0 + cq;
        *(uint4*)dst = *(uint4*)&v[0];
        *(uint4*)(dst + 8) = *(uint4*)&v[8];
        *(uint4*)&tile[r * 72 + cq] = *(uint4*)&v[0];
        *(uint4*)&tile[r * 72 + cq + 8] = *(uint4*)&v[8];
    }
    __syncthreads();
    {
        int dr = t >> 2, sq = (t & 3) * 16;
        unsigned short v[16] __attribute__((aligned(16)));
        float part = 0.f;
#pragma unroll
        for (int j = 0; j < 16; ++j) {
            unsigned short u = tile[(sq + j) * 72 + dr];
            v[j] = u;
            part += bf2f(u);
        }
        unsigned short* dst = XtB + (size_t)(d0 + dr) * 4096 + s0 + sq;
        *(uint4*)dst = *(uint4*)&v[0];
        *(uint4*)(dst + 8) = *(uint4*)&v[8];
        part += __shfl_down(part, 1);
        part += __shfl_down(part, 2);
        if ((t & 3) == 0) atomicAdd(&csum[b * 768 + d0 + dr], part);
    }
}

// Flat grid 2336:
//   wg < 1344: triangular Gram partial tile (tile=wg%21, zz=wg/21; b=zz>>4,
//              split=zz&15, K=256) -> packed Gp
//   wg < 2112: aux u/d2: id=wg-1344, b=id/192, row=(id%192)*4+wave:
//              u[b][row]=Wk[row].s_b ; d2[b][row]=SCALE*(Wv[row].s_b+4096 bv)
//   wg >=2112: c2p: row=(wg-2112)*4+wave (<896): c2p[row]=Wqt+[row].bk
__global__ __launch_bounds__(256, 2) void gram2(
    const unsigned short* __restrict__ Xt, unsigned short* __restrict__ Gp,
    const float* __restrict__ Wk, const float* __restrict__ Wv,
    const unsigned short* __restrict__ Wqt,
    const float* __restrict__ bk, const float* __restrict__ bv,
    const float* __restrict__ csum,
    float* __restrict__ u, float* __restrict__ d2, float* __restrict__ c2p) {
    const long PB = 3145728;
    const unsigned wg = xcd_swizzle(blockIdx.x, gridDim.x);
    const int t = threadIdx.x;
    const int lane = t & 63;
    const int wave = t >> 6;

    if (wg >= 2112) {  // c2p
        const int row = (wg - 2112) * 4 + wave;
        float a = 0.f;
        for (int e = lane * 4; e < 768; e += 256) {
            const unsigned short* qr = Wqt + (size_t)row * 768 + e;
            float4 b4 = *(const float4*)(bk + e);
            a += bf2f(qr[0]) * b4.x + bf2f(qr[1]) * b4.y +
                 bf2f(qr[2]) * b4.z + bf2f(qr[3]) * b4.w;
        }
#pragma unroll
        for (int off = 32; off; off >>= 1) a += __shfl_down(a, off);
        if (lane == 0) c2p[row] = a;
        return;
    }
    if (wg >= 1344) {  // u + d2
        const int id = wg - 1344;
        const int b = id / 192;
        const int row = (id % 192) * 4 + wave;
        const float* s = csum + b * 768;
        float aU = 0.f, aD = 0.f;
        for (int e = lane * 4; e < 768; e += 256) {
            float4 wk4 = *(const float4*)(Wk + (size_t)row * 768 + e);
            float4 wv4 = *(const float4*)(Wv + (size_t)row * 768 + e);
            float4 s4 = *(const float4*)(s + e);
            aU += wk4.x * s4.x + wk4.y * s4.y + wk4.z * s4.z + wk4.w * s4.w;
            aD += wv4.x * s4.x + wv4.y * s4.y + wv4.z * s4.z + wv4.w * s4.w;
        }
#pragma unroll
        for (int off = 32; off; off >>= 1) {
            aU += __shfl_down(aU, off);
            aD += __shfl_down(aD, off);
        }
        if (lane == 0) {
            u[b * 768 + row] = aU;
            d2[b * 768 + row] = SCALE * (aD + 4096.f * bv[row]);
        }
        return;
    }

    __shared__ __align__(16) char ldsA[16384];
    __shared__ __align__(16) char ldsB[16384];
    const int wm = wave >> 1;
    const int wn = wave & 1;
    const int l15 = lane & 15;
    const int khi = (lane >> 4) << 4;
    f32x4 acc[4][4];
#pragma unroll
    for (int i = 0; i < 4; ++i)
#pragma unroll
        for (int j = 0; j < 4; ++j)
            acc[i][j] = (f32x4){0.f, 0.f, 0.f, 0.f};
    const int rbase = (lane >> 4) << 2;

    const int tile = wg % 21;
    const int zz = wg / 21;
    const int b = zz >> 4;
    const int koff = (zz & 15) * 256;
    int tt = tile, tby = 0;
    while (tt >= 6 - tby) { tt -= 6 - tby; ++tby; }
    const int m0 = tby * 128;
    const int n0 = (tby + tt) * 128;
    const unsigned short* Ab = Xt + (size_t)b * PB + (size_t)m0 * 4096 + koff;
    const unsigned short* Bb = Xt + (size_t)b * PB + (size_t)n0 * 4096 + koff;
    gemm_core(Ab, Bb, 256, 4096, 4096, ldsA, ldsB, wave, lane, wm, wn, l15, khi, acc);
    unsigned short* dst = Gp + ((size_t)zz * 21 + tile) * 16384;
#pragma unroll
    for (int i = 0; i < 4; ++i)
#pragma unroll
        for (int r = 0; r < 4; ++r) {
            int rloc = wm * 64 + i * 16 + rbase + r;
#pragma unroll
            for (int j = 0; j < 4; ++j) {
                int cloc = wn * 64 + j * 16 + l15;
                dst[(size_t)rloc * 128 + cloc] = f2bf(acc[i][j][r]);
            }
        }
}

// grid (287,4):
//   x<21: reduce Gp (16 splits) -> G tile, mirror off-diag (y=b)
//   21<=x<245: c1p[b][row] = SCALE * Wqt+[row] . u_b   (row=(x-21)*4+wave)
//   x>=245 && y==0: P+ tile id=x-245 (7x6, K=768) -> Pp
__global__ __launch_bounds__(256, 2) void redvec2(
    const unsigned short* __restrict__ Gp, unsigned short* __restrict__ G,
    const unsigned short* __restrict__ Wqt, const unsigned short* __restrict__ Wkt,
    unsigned short* __restrict__ Pp,
    const float* __restrict__ u, float* __restrict__ c1p) {
    const int b = blockIdx.y;
    const int t = threadIdx.x;
    const int lane = t & 63;
    const int wave = t >> 6;
    if (blockIdx.x >= 245) {
        if (b) return;
        __shared__ __align__(16) char ldsA[16384];
        __shared__ __align__(16) char ldsB[16384];
        const int id = blockIdx.x - 245;
        const int m0 = (id / 6) * 128;
        const int n0 = (id % 6) * 128;
        const int wm = wave >> 1;
        const int wn = wave & 1;
        const int l15 = lane & 15;
        const int khi = (lane >> 4) << 4;
        f32x4 acc[4][4];
#pragma unroll
        for (int i = 0; i < 4; ++i)
#pragma unroll
            for (int j = 0; j < 4; ++j)
                acc[i][j] = (f32x4){0.f, 0.f, 0.f, 0.f};
        gemm_core(Wqt + (size_t)m0 * 768, Wkt + (size_t)n0 * 768,
                  768, 768, 768, ldsA, ldsB, wave, lane, wm, wn, l15, khi, acc);
        const int rbase = (lane >> 4) << 2;
#pragma unroll
        for (int i = 0; i < 4; ++i)
#pragma unroll
            for (int r = 0; r < 4; ++r) {
                int row = m0 + wm * 64 + i * 16 + rbase + r;
#pragma unroll
                for (int j = 0; j < 4; ++j) {
                    int col = n0 + wn * 64 + j * 16 + l15;
                    Pp[(size_t)row * 768 + col] = f2bf(acc[i][j][r]);
                }
            }
        return;
    }
    if (blockIdx.x >= 21) {  // c1p
        const int row = (blockIdx.x - 21) * 4 + wave;
        const float* ub = u + b * 768;
        float a = 0.f;
        for (int e = lane * 4; e < 768; e += 256) {
            const unsigned short* qr = Wqt + (size_t)row * 768 + e;
            float4 u4 = *(const float4*)(ub + e);
            a += bf2f(qr[0]) * u4.x + bf2f(qr[1]) * u4.y +
                 bf2f(qr[2]) * u4.z + bf2f(qr[3]) * u4.w;
        }
#pragma unroll
        for (int off = 32; off; off >>= 1) a += __shfl_down(a, off);
        if (lane == 0) c1p[b * 896 + row] = SCALE * a;
        return;
    }
    __shared__ unsigned short tl[128 * 136];
    const int tile = blockIdx.x;
    int tt = tile, tby = 0;
    while (tt >= 6 - tby) { tt -= 6 - tby; ++tby; }
    const int tbx = tby + tt;
    const int r = t >> 1;
    const int c0 = (t & 1) * 64;
    float acc[64];
#pragma unroll
    for (int j = 0; j < 64; ++j) acc[j] = 0.f;
    for (int sp = 0; sp < 16; ++sp) {
        const unsigned short* base =
            Gp + ((size_t)(b * 16 + sp) * 21 + tile) * 16384 + (size_t)r * 128 + c0;
#pragma unroll
        for (int j = 0; j < 8; ++j) {
            uint4 qv = *(const uint4*)(base + j * 8);
            const unsigned short* pv = (const unsigned short*)&qv;
#pragma unroll
            for (int k = 0; k < 8; ++k) acc[j * 8 + k] += bf2f(pv[k]);
        }
    }
    unsigned short v[64] __attribute__((aligned(16)));
#pragma unroll
    for (int j = 0; j < 64; ++j) v[j] = f2bf(acc[j]);
    unsigned short* dst = G + (size_t)b * 589824 +
                          (size_t)(tby * 128 + r) * 768 + tbx * 128 + c0;
#pragma unroll
    for (int j = 0; j < 8; ++j) *(uint4*)(dst + j * 8) = *(uint4*)&v[j * 8];
    if (tby != tbx) {
#pragma unroll
        for (int j = 0; j < 8; ++j)
            *(uint4*)&tl[r * 136 + c0 + j * 8] = *(uint4*)&v[j * 8];
        __syncthreads();
        unsigned short w[64] __attribute__((aligned(16)));
#pragma unroll
        for (int qq = 0; qq < 64; ++qq) w[qq] = tl[(c0 + qq) * 136 + r];
        unsigned short* dm = G + (size_t)b * 589824 +
                             (size_t)(tbx * 128 + r) * 768 + tby * 128 + c0;
#pragma unroll
        for (int j = 0; j < 8; ++j) *(uint4*)(dm + j * 8) = *(uint4*)&w[j * 8];
    }
}

extern "C" void kernel_launch(void* const* d_in, const int* in_sizes, int n_in,
                              void* d_out, int out_size, void* d_ws, size_t ws_size,
                              hipStream_t stream) {
    const float* x  = (const float*)d_in[0];
    const float* Wq = (const float*)d_in[1];
    const float* bq = (const float*)d_in[2];
    const float* Wk = (const float*)d_in[3];
    const float* bk = (const float*)d_in[4];
    const float* Wv = (const float*)d_in[5];
    const float* bv = (const float*)d_in[6];
    float* out = (float*)d_out;

    const long PB = 3145728;   // 4096*768
    const long DD = 589824;    // 768*768
    const long DA = 688128;    // 896*768

    unsigned short* ws  = (unsigned short*)d_ws;
    unsigned short* Xbf = ws;                       // 12582912
    unsigned short* Xt  = ws + 12582912;            // 12582912
    unsigned short* Pp  = ws + 25165824;            // 688128
    unsigned short* G   = ws + 25853952;            // 2359296
    unsigned short* Wqt = ws + 28213248;            // 688128 ([896][768])
    unsigned short* Wkt = ws + 28901376;            // 589824
    unsigned short* Wvb = ws + 29491200;            // 589824
    unsigned short* Gp  = ws + 30081024;            // 22020096 (21*64 tiles)
    unsigned short* C1p = Gp;                       // overlay after redvec2
    unsigned short* At  = Gp + 2752512;             // 2752512
    float* fbase = (float*)(ws + 52101120);
    float* csum = fbase;                            // 3072
    float* u    = fbase + 3072;                     // 3072
    float* c1p  = fbase + 6144;                     // 3584
    float* c2p  = fbase + 9728;                     // 896
    float* d2   = fbase + 10624;                    // 3072

    dim3 blk(256, 1, 1);

    prep_w<<<dim3(12, 12, 5), blk, 0, stream>>>(Wq, Wk, Wv, bq, Wqt, Wkt, Wvb, csum);
    prep_x<<<dim3(64, 12, 4), blk, 0, stream>>>(x, Xbf, Xt, csum);

    // Gram tri split-K partials (split=16, K=256) + u/d2 + c2p aux
    gram2<<<dim3(2336, 1, 1), blk, 0, stream>>>(Xt, Gp, Wk, Wv, Wqt, bk, bv,
                                                csum, u, d2, c2p);

    // reduce G (16 splits) + c1p + P+
    redvec2<<<dim3(287, 4), blk, 0, stream>>>(Gp, G, Wqt, Wkt, Pp, u, c1p);

    // C1+ = P+ ⊠ G   [4][896][768]
    gemm_bf16<BIAS_NONE, true><<<dim3(6, 7, 4), blk, 0, stream>>>(
        Pp, G, C1p, nullptr, nullptr, nullptr, nullptr, nullptr,
        768, 768, 768, 768, 0, DD, DA, 1.0f, 0);

    // At = Wvb ⊠ C1+ (+rank2)   [4][768][896]
    gemm_bf16<BIAS_RANK2, true><<<dim3(7, 6, 4), blk, 0, stream>>>(
        Wvb, C1p, At, bv, c1p, d2, c2p, nullptr,
        768, 768, 768, 896, 0, DA, DA, SCALE, 896);

    // out = Xbf ⊠ At (K=768) + r epilogue (At col 768)   fp32
    gemm_bf16<BIAS_RCOL, false><<<dim3(6, 32, 4), blk, 0, stream>>>(
        Xbf, At, out, nullptr, nullptr, nullptr, nullptr, At,
        768, 768, 896, 768, PB, DA, PB, 1.0f, 0);
}

// Round 6
// 134.899 us; speedup vs baseline: 1.9419x; 1.0842x over previous
//
#include <hip/hip_runtime.h>

// out = X A + 1 r^T,  A = scale Wq^T (K^T V).  With G = X^T X, s = X^T 1:
//   K^T V = Wk G Wv^T + (Wk s) bv^T + bk (Wv s)^T + S bk bv^T
// Augment Wq+ = [Wq^T; bq^T; 0pad] (896x768) so r = col 768 of At.
//   prep_w: Wqt+/Wkt/Wvb (bf16) + zero csum
//   prep_x: Xbf [4][4096][768], Xt [4][768][4096], csum atomics
//   gram2:  672 tri split-K Gram partial tiles (K=512, split=8) + u/d2/c2p
//   redvec2: reduce Gp (8) -> G (mirror); c1p; 42 P+ tiles
//   C1+ = P+ ⊠ G            [4][896][768]   (gemm64: 672 wgs, latency fix)
//   At  = Wvb ⊠ C1+ (+rank2)[4][768][896]   (gemm64: 672 wgs)
//   out = Xbf ⊠ At (K=768) + At[col][768] epilogue   fp32
// GEMM: 128x128 tile, BK=64, serial 32KB-LDS loop (m97 structure),
// global_load_lds(16B) pre-swizzled source, XOR (r&7)<<4 reads,
// XCD-chunked bijective blockIdx swizzle.  gemm64 = 64x64-tile clone for the
// 168-wg mid-chain GEMMs (0.65 blocks/CU -> 2.6, co-resident at 16KB LDS).
// (R1: dbuf+counted-vmcnt regressed; R2: P+ move regressed; R3: fused
//  reduce 6x regression; R4/R5: split 4/16 regressed -> split=8 optimal.)

typedef __attribute__((ext_vector_type(8))) __bf16 bf16x8;
typedef __attribute__((ext_vector_type(4))) float f32x4;

#define SCALE 0.03608439182435161f

union FragU {
    uint4 q;
    bf16x8 f;
    unsigned short s[8];
};

__device__ __forceinline__ unsigned short f2bf(float x) {
    unsigned int u = __builtin_bit_cast(unsigned int, x);
    u = (u + 0x7fffu + ((u >> 16) & 1u)) >> 16;
    return (unsigned short)u;
}
__device__ __forceinline__ float bf2f(unsigned short u) {
    unsigned int v = ((unsigned int)u) << 16;
    return __builtin_bit_cast(float, v);
}

__device__ __forceinline__ unsigned xcd_swizzle(unsigned lin, unsigned nwg) {
    const unsigned q = nwg >> 3, rr8 = nwg & 7;
    const unsigned xcd = lin & 7, o = lin >> 3;
    return (xcd < rr8 ? xcd * (q + 1) : rr8 * (q + 1) + (xcd - rr8) * q) + o;
}

__device__ __forceinline__ void stage_gl(const unsigned short* __restrict__ srcRowBase,
                                         int ldElems, char* lds, int wave, int lane) {
#pragma unroll
    for (int p = 0; p < 4; ++p) {
        int slotbase = (wave * 4 + p) * 1024;
        int slot = slotbase + lane * 16;
        int r = slot >> 7;
        int cb = (slot & 127) ^ ((r & 7) << 4);
        const char* g = (const char*)(srcRowBase + (size_t)r * ldElems) + cb;
        __builtin_amdgcn_global_load_lds(
            (const __attribute__((address_space(1))) unsigned int*)g,
            (__attribute__((address_space(3))) unsigned int*)(lds + slotbase),
            16, 0, 0);
    }
}

// 8KB half-size staging: half in {0,1} covers rows [half*32, half*32+32).
__device__ __forceinline__ void stage_gl64(const unsigned short* __restrict__ srcRowBase,
                                           int ldElems, char* lds, int half, int lane) {
#pragma unroll
    for (int p = 0; p < 4; ++p) {
        int slotbase = (half * 4 + p) * 1024;
        int slot = slotbase + lane * 16;
        int r = slot >> 7;
        int cb = (slot & 127) ^ ((r & 7) << 4);
        const char* g = (const char*)(srcRowBase + (size_t)r * ldElems) + cb;
        __builtin_amdgcn_global_load_lds(
            (const __attribute__((address_space(1))) unsigned int*)g,
            (__attribute__((address_space(3))) unsigned int*)(lds + slotbase),
            16, 0, 0);
    }
}

__device__ __forceinline__ bf16x8 load_frag(const char* lds, int row, int kbyte) {
    int a = row * 128 + kbyte;
    a ^= (row & 7) << 4;
    FragU u;
    u.q = *(const uint4*)(lds + a);
    return u.f;
}

__device__ __forceinline__ void gemm_core(const unsigned short* __restrict__ Ab,
                                          const unsigned short* __restrict__ Bb,
                                          int K, int lda, int ldb,
                                          char* ldsA, char* ldsB,
                                          int wave, int lane, int wm, int wn,
                                          int l15, int khi, f32x4 (&acc)[4][4]) {
    for (int k0 = 0; k0 < K; k0 += 64) {
        stage_gl(Ab + k0, lda, ldsA, wave, lane);
        stage_gl(Bb + k0, ldb, ldsB, wave, lane);
        __syncthreads();
#pragma unroll
        for (int kk = 0; kk < 2; ++kk) {
            const int kbyte = kk * 64 + khi;
            bf16x8 af[4], bfr[4];
#pragma unroll
            for (int i = 0; i < 4; ++i)
                af[i] = load_frag(ldsA, wm * 64 + i * 16 + l15, kbyte);
#pragma unroll
            for (int j = 0; j < 4; ++j)
                bfr[j] = load_frag(ldsB, wn * 64 + j * 16 + l15, kbyte);
#pragma unroll
            for (int i = 0; i < 4; ++i)
#pragma unroll
                for (int j = 0; j < 4; ++j)
                    acc[i][j] = __builtin_amdgcn_mfma_f32_16x16x32_bf16(
                        af[i], bfr[j], acc[i][j], 0, 0, 0);
        }
        __syncthreads();
    }
}

enum { BIAS_NONE = 0, BIAS_RANK2 = 2, BIAS_RCOL = 3 };

template <int BIASM, bool OUT_BF16>
__global__ __launch_bounds__(256, 2) void gemm_bf16(
    const unsigned short* __restrict__ A, const unsigned short* __restrict__ B,
    void* __restrict__ C,
    const float* __restrict__ p0, const float* __restrict__ p1,
    const float* __restrict__ p2, const float* __restrict__ p3,
    const unsigned short* __restrict__ rsrc,
    int K, int lda, int ldb, int ldc, long bsA, long bsB, long bsC,
    float scale, int vld1) {
    __shared__ __align__(16) char ldsA[16384];
    __shared__ __align__(16) char ldsB[16384];

    const unsigned gx = gridDim.x, gy = gridDim.y;
    const unsigned lin = blockIdx.x + gx * (blockIdx.y + gy * blockIdx.z);
    const unsigned wg = xcd_swizzle(lin, gx * gy * gridDim.z);
    const int bx = wg % gx;
    const int by = (wg / gx) % gy;
    const int z = wg / (gx * gy);

    const int m0 = by * 128;
    const int n0 = bx * 128;
    const unsigned short* Ab = A + (size_t)z * bsA + (size_t)m0 * lda;
    const unsigned short* Bb = B + (size_t)z * bsB + (size_t)n0 * ldb;

    const int lane = threadIdx.x & 63;
    const int wave = threadIdx.x >> 6;
    const int wm = wave >> 1;
    const int wn = wave & 1;
    const int l15 = lane & 15;
    const int khi = (lane >> 4) << 4;

    f32x4 acc[4][4];
#pragma unroll
    for (int i = 0; i < 4; ++i)
#pragma unroll
        for (int j = 0; j < 4; ++j)
            acc[i][j] = (f32x4){0.f, 0.f, 0.f, 0.f};

    gemm_core(Ab, Bb, K, lda, ldb, ldsA, ldsB, wave, lane, wm, wn, l15, khi, acc);

    const int rbase = (lane >> 4) << 2;
#pragma unroll
    for (int i = 0; i < 4; ++i) {
#pragma unroll
        for (int r = 0; r < 4; ++r) {
            int row = m0 + wm * 64 + i * 16 + rbase + r;
            float rA = 0.f, rB = 0.f;
            if (BIASM == BIAS_RANK2) {
                rA = p0[row];
                rB = p2[z * 768 + row];
            }
#pragma unroll
            for (int j = 0; j < 4; ++j) {
                int col = n0 + wn * 64 + j * 16 + l15;
                float v = acc[i][j][r] * scale;
                if (BIASM == BIAS_RANK2) v += rA * p1[z * vld1 + col] + rB * p3[col];
                if (BIASM == BIAS_RCOL)
                    v += bf2f(rsrc[(size_t)z * 688128 + (size_t)col * 896 + 768]);
                size_t off = (size_t)z * bsC + (size_t)row * ldc + col;
                if (OUT_BF16)
                    ((unsigned short*)C)[off] = f2bf(v);
                else
                    ((float*)C)[off] = v;
            }
        }
    }
}

// 64x64-tile GEMM for the low-workgroup mid-chain GEMMs. 4 waves as 2x2 of
// 32x32. Waves 0-1 stage A (8KB), waves 2-3 stage B (8KB). Same K-chunk and
// MFMA order as the 128-tile core -> bitwise-identical results.
template <int BIASM>
__global__ __launch_bounds__(256, 2) void gemm64_bf16(
    const unsigned short* __restrict__ A, const unsigned short* __restrict__ B,
    unsigned short* __restrict__ C,
    const float* __restrict__ p0, const float* __restrict__ p1,
    const float* __restrict__ p2, const float* __restrict__ p3,
    int K, int lda, int ldb, int ldc, long bsA, long bsB, long bsC,
    float scale, int vld1) {
    __shared__ __align__(16) char ldsA[8192];
    __shared__ __align__(16) char ldsB[8192];

    const unsigned gx = gridDim.x, gy = gridDim.y;
    const unsigned lin = blockIdx.x + gx * (blockIdx.y + gy * blockIdx.z);
    const unsigned wg = xcd_swizzle(lin, gx * gy * gridDim.z);
    const int bx = wg % gx;
    const int by = (wg / gx) % gy;
    const int z = wg / (gx * gy);

    const int m0 = by * 64;
    const int n0 = bx * 64;
    const unsigned short* Ab = A + (size_t)z * bsA + (size_t)m0 * lda;
    const unsigned short* Bb = B + (size_t)z * bsB + (size_t)n0 * ldb;

    const int lane = threadIdx.x & 63;
    const int wave = threadIdx.x >> 6;
    const int wr = wave >> 1;
    const int wc = wave & 1;
    const int l15 = lane & 15;
    const int khi = (lane >> 4) << 4;

    f32x4 acc[2][2];
#pragma unroll
    for (int i = 0; i < 2; ++i)
#pragma unroll
        for (int j = 0; j < 2; ++j)
            acc[i][j] = (f32x4){0.f, 0.f, 0.f, 0.f};

    for (int k0 = 0; k0 < K; k0 += 64) {
        if (wave < 2)
            stage_gl64(Ab + k0, lda, ldsA, wave, lane);
        else
            stage_gl64(Bb + k0, ldb, ldsB, wave - 2, lane);
        __syncthreads();
#pragma unroll
        for (int kk = 0; kk < 2; ++kk) {
            const int kbyte = kk * 64 + khi;
            bf16x8 af[2], bfr[2];
#pragma unroll
            for (int i = 0; i < 2; ++i)
                af[i] = load_frag(ldsA, wr * 32 + i * 16 + l15, kbyte);
#pragma unroll
            for (int j = 0; j < 2; ++j)
                bfr[j] = load_frag(ldsB, wc * 32 + j * 16 + l15, kbyte);
#pragma unroll
            for (int i = 0; i < 2; ++i)
#pragma unroll
                for (int j = 0; j < 2; ++j)
                    acc[i][j] = __builtin_amdgcn_mfma_f32_16x16x32_bf16(
                        af[i], bfr[j], acc[i][j], 0, 0, 0);
        }
        __syncthreads();
    }

    const int rbase = (lane >> 4) << 2;
#pragma unroll
    for (int i = 0; i < 2; ++i) {
#pragma unroll
        for (int r = 0; r < 4; ++r) {
            int row = m0 + wr * 32 + i * 16 + rbase + r;
            float rA = 0.f, rB = 0.f;
            if (BIASM == BIAS_RANK2) {
                rA = p0[row];
                rB = p2[z * 768 + row];
            }
#pragma unroll
            for (int j = 0; j < 2; ++j) {
                int col = n0 + wc * 32 + j * 16 + l15;
                float v = acc[i][j][r] * scale;
                if (BIASM == BIAS_RANK2) v += rA * p1[z * vld1 + col] + rB * p3[col];
                C[(size_t)z * bsC + (size_t)row * ldc + col] = f2bf(v);
            }
        }
    }
}

// z=0: Wqt+ rows 0..767 = Wq^T; z=1: Wkt = Wk^T; z=2: Wvb = bf16(Wv);
// z=3: Wqt+ row 768 = bq, rows 769..895 = 0; z=4: zero csum.
__global__ __launch_bounds__(256) void prep_w(const float* __restrict__ Wq,
                                              const float* __restrict__ Wk,
                                              const float* __restrict__ Wv,
                                              const float* __restrict__ bq,
                                              unsigned short* __restrict__ Wqt,
                                              unsigned short* __restrict__ Wkt,
                                              unsigned short* __restrict__ Wvb,
                                              float* __restrict__ csum) {
    const int mode = blockIdx.z;
    const int t = threadIdx.x;
    if (mode == 4) {
        if (blockIdx.x == 0 && blockIdx.y == 0) {
            float4 z4 = {0.f, 0.f, 0.f, 0.f};
            for (int i = t * 4; i < 3072; i += 1024) *(float4*)(csum + i) = z4;
        }
        return;
    }
    if (mode == 3) {
        if (blockIdx.y) return;
        int rr = 768 + (t >> 1);
        int c0 = blockIdx.x * 64 + (t & 1) * 32;
        unsigned short v[32] __attribute__((aligned(16)));
        if (rr == 768) {
#pragma unroll
            for (int j = 0; j < 32; ++j) v[j] = f2bf(bq[c0 + j]);
        } else {
#pragma unroll
            for (int j = 0; j < 32; ++j) v[j] = 0;
        }
        unsigned short* dst = Wqt + (size_t)rr * 768 + c0;
#pragma unroll
        for (int j = 0; j < 4; ++j) *(uint4*)(dst + j * 8) = *(uint4*)&v[j * 8];
        return;
    }
    __shared__ unsigned short tile[64 * 72];
    const float* src = mode == 0 ? Wq : (mode == 1 ? Wk : Wv);
    const int r0 = blockIdx.x * 64;
    const int c0 = blockIdx.y * 64;
    int r = t >> 2, cq = (t & 3) * 16;
    unsigned short v[16] __attribute__((aligned(16)));
    const float* s = src + (size_t)(r0 + r) * 768 + c0 + cq;
#pragma unroll
    for (int j = 0; j < 16; j += 4) {
        float4 f = *(const float4*)(s + j);
        v[j] = f2bf(f.x); v[j + 1] = f2bf(f.y);
        v[j + 2] = f2bf(f.z); v[j + 3] = f2bf(f.w);
    }
    if (mode == 2) {
        unsigned short* dst = Wvb + (size_t)(r0 + r) * 768 + c0 + cq;
        *(uint4*)dst = *(uint4*)&v[0];
        *(uint4*)(dst + 8) = *(uint4*)&v[8];
        return;
    }
    *(uint4*)&tile[r * 72 + cq] = *(uint4*)&v[0];
    *(uint4*)&tile[r * 72 + cq + 8] = *(uint4*)&v[8];
    __syncthreads();
    int dr = t >> 2, sq = (t & 3) * 16;
    unsigned short w[16] __attribute__((aligned(16)));
#pragma unroll
    for (int j = 0; j < 16; ++j) w[j] = tile[(sq + j) * 72 + dr];
    unsigned short* dst = (mode == 0 ? Wqt : Wkt) + (size_t)(c0 + dr) * 768 + r0 + sq;
    *(uint4*)dst = *(uint4*)&w[0];
    *(uint4*)(dst + 8) = *(uint4*)&w[8];
}

// Xbf [4][4096][768], Xt [4][768][4096], csum atomics.
__global__ __launch_bounds__(256) void prep_x(const float* __restrict__ X,
                                              unsigned short* __restrict__ Xbf,
                                              unsigned short* __restrict__ Xt,
                                              float* __restrict__ csum) {
    const int b = blockIdx.z;
    const int s0 = blockIdx.x * 64;
    const int t = threadIdx.x;
    __shared__ unsigned short tile[64 * 72];
    const int d0 = blockIdx.y * 64;
    const float* Xb = X + (size_t)b * 4096 * 768;
    unsigned short* XbfB = Xbf + (size_t)b * 4096 * 768;
    unsigned short* XtB = Xt + (size_t)b * 768 * 4096;
    {
        int r = t >> 2, cq = (t & 3) * 16;
        const float* src = Xb + (size_t)(s0 + r) * 768 + d0 + cq;
        unsigned short v[16] __attribute__((aligned(16)));
#pragma unroll
        for (int j = 0; j < 16; j += 4) {
            float4 f = *(const float4*)(src + j);
            v[j] = f2bf(f.x); v[j + 1] = f2bf(f.y);
            v[j + 2] = f2bf(f.z); v[j + 3] = f2bf(f.w);
        }
        unsigned short* dst = XbfB + (size_t)(s0 + r) * 768 + d0 + cq;
        *(uint4*)dst = *(uint4*)&v[0];
        *(uint4*)(dst + 8) = *(uint4*)&v[8];
        *(uint4*)&tile[r * 72 + cq] = *(uint4*)&v[0];
        *(uint4*)&tile[r * 72 + cq + 8] = *(uint4*)&v[8];
    }
    __syncthreads();
    {
        int dr = t >> 2, sq = (t & 3) * 16;
        unsigned short v[16] __attribute__((aligned(16)));
        float part = 0.f;
#pragma unroll
        for (int j = 0; j < 16; ++j) {
            unsigned short u = tile[(sq + j) * 72 + dr];
            v[j] = u;
            part += bf2f(u);
        }
        unsigned short* dst = XtB + (size_t)(d0 + dr) * 4096 + s0 + sq;
        *(uint4*)dst = *(uint4*)&v[0];
        *(uint4*)(dst + 8) = *(uint4*)&v[8];
        part += __shfl_down(part, 1);
        part += __shfl_down(part, 2);
        if ((t & 3) == 0) atomicAdd(&csum[b * 768 + d0 + dr], part);
    }
}

// Flat grid 1664:
//   wg <  672: triangular Gram partial tile (tile=wg%21, zz=wg/21; b=zz>>3,
//              split=zz&7, K=512) -> packed Gp
//   wg < 1440: aux u/d2: id=wg-672, b=id/192, row=(id%192)*4+wave:
//              u[b][row]=Wk[row].s_b ; d2[b][row]=SCALE*(Wv[row].s_b+4096 bv)
//   wg >=1440: c2p: row=(wg-1440)*4+wave (<896): c2p[row]=Wqt+[row].bk
__global__ __launch_bounds__(256, 2) void gram2(
    const unsigned short* __restrict__ Xt, unsigned short* __restrict__ Gp,
    const float* __restrict__ Wk, const float* __restrict__ Wv,
    const unsigned short* __restrict__ Wqt,
    const float* __restrict__ bk, const float* __restrict__ bv,
    const float* __restrict__ csum,
    float* __restrict__ u, float* __restrict__ d2, float* __restrict__ c2p) {
    const long PB = 3145728;
    const unsigned wg = xcd_swizzle(blockIdx.x, gridDim.x);
    const int t = threadIdx.x;
    const int lane = t & 63;
    const int wave = t >> 6;

    if (wg >= 1440) {  // c2p
        const int row = (wg - 1440) * 4 + wave;
        float a = 0.f;
        for (int e = lane * 4; e < 768; e += 256) {
            const unsigned short* qr = Wqt + (size_t)row * 768 + e;
            float4 b4 = *(const float4*)(bk + e);
            a += bf2f(qr[0]) * b4.x + bf2f(qr[1]) * b4.y +
                 bf2f(qr[2]) * b4.z + bf2f(qr[3]) * b4.w;
        }
#pragma unroll
        for (int off = 32; off; off >>= 1) a += __shfl_down(a, off);
        if (lane == 0) c2p[row] = a;
        return;
    }
    if (wg >= 672) {  // u + d2
        const int id = wg - 672;
        const int b = id / 192;
        const int row = (id % 192) * 4 + wave;
        const float* s = csum + b * 768;
        float aU = 0.f, aD = 0.f;
        for (int e = lane * 4; e < 768; e += 256) {
            float4 wk4 = *(const float4*)(Wk + (size_t)row * 768 + e);
            float4 wv4 = *(const float4*)(Wv + (size_t)row * 768 + e);
            float4 s4 = *(const float4*)(s + e);
            aU += wk4.x * s4.x + wk4.y * s4.y + wk4.z * s4.z + wk4.w * s4.w;
            aD += wv4.x * s4.x + wv4.y * s4.y + wv4.z * s4.z + wv4.w * s4.w;
        }
#pragma unroll
        for (int off = 32; off; off >>= 1) {
            aU += __shfl_down(aU, off);
            aD += __shfl_down(aD, off);
        }
        if (lane == 0) {
            u[b * 768 + row] = aU;
            d2[b * 768 + row] = SCALE * (aD + 4096.f * bv[row]);
        }
        return;
    }

    __shared__ __align__(16) char ldsA[16384];
    __shared__ __align__(16) char ldsB[16384];
    const int wm = wave >> 1;
    const int wn = wave & 1;
    const int l15 = lane & 15;
    const int khi = (lane >> 4) << 4;
    f32x4 acc[4][4];
#pragma unroll
    for (int i = 0; i < 4; ++i)
#pragma unroll
        for (int j = 0; j < 4; ++j)
            acc[i][j] = (f32x4){0.f, 0.f, 0.f, 0.f};
    const int rbase = (lane >> 4) << 2;

    const int tile = wg % 21;
    const int zz = wg / 21;
    const int b = zz >> 3;
    const int koff = (zz & 7) * 512;
    int tt = tile, tby = 0;
    while (tt >= 6 - tby) { tt -= 6 - tby; ++tby; }
    const int m0 = tby * 128;
    const int n0 = (tby + tt) * 128;
    const unsigned short* Ab = Xt + (size_t)b * PB + (size_t)m0 * 4096 + koff;
    const unsigned short* Bb = Xt + (size_t)b * PB + (size_t)n0 * 4096 + koff;
    gemm_core(Ab, Bb, 512, 4096, 4096, ldsA, ldsB, wave, lane, wm, wn, l15, khi, acc);
    unsigned short* dst = Gp + ((size_t)zz * 21 + tile) * 16384;
#pragma unroll
    for (int i = 0; i < 4; ++i)
#pragma unroll
        for (int r = 0; r < 4; ++r) {
            int rloc = wm * 64 + i * 16 + rbase + r;
#pragma unroll
            for (int j = 0; j < 4; ++j) {
                int cloc = wn * 64 + j * 16 + l15;
                dst[(size_t)rloc * 128 + cloc] = f2bf(acc[i][j][r]);
            }
        }
}

// grid (287,4):
//   x<21: reduce Gp (8 splits) -> G tile, mirror off-diag (y=b)
//   21<=x<245: c1p[b][row] = SCALE * Wqt+[row] . u_b   (row=(x-21)*4+wave)
//   x>=245 && y==0: P+ tile id=x-245 (7x6, K=768) -> Pp
__global__ __launch_bounds__(256, 2) void redvec2(
    const unsigned short* __restrict__ Gp, unsigned short* __restrict__ G,
    const unsigned short* __restrict__ Wqt, const unsigned short* __restrict__ Wkt,
    unsigned short* __restrict__ Pp,
    const float* __restrict__ u, float* __restrict__ c1p) {
    const int b = blockIdx.y;
    const int t = threadIdx.x;
    const int lane = t & 63;
    const int wave = t >> 6;
    if (blockIdx.x >= 245) {
        if (b) return;
        __shared__ __align__(16) char ldsA[16384];
        __shared__ __align__(16) char ldsB[16384];
        const int id = blockIdx.x - 245;
        const int m0 = (id / 6) * 128;
        const int n0 = (id % 6) * 128;
        const int wm = wave >> 1;
        const int wn = wave & 1;
        const int l15 = lane & 15;
        const int khi = (lane >> 4) << 4;
        f32x4 acc[4][4];
#pragma unroll
        for (int i = 0; i < 4; ++i)
#pragma unroll
            for (int j = 0; j < 4; ++j)
                acc[i][j] = (f32x4){0.f, 0.f, 0.f, 0.f};
        gemm_core(Wqt + (size_t)m0 * 768, Wkt + (size_t)n0 * 768,
                  768, 768, 768, ldsA, ldsB, wave, lane, wm, wn, l15, khi, acc);
        const int rbase = (lane >> 4) << 2;
#pragma unroll
        for (int i = 0; i < 4; ++i)
#pragma unroll
            for (int r = 0; r < 4; ++r) {
                int row = m0 + wm * 64 + i * 16 + rbase + r;
#pragma unroll
                for (int j = 0; j < 4; ++j) {
                    int col = n0 + wn * 64 + j * 16 + l15;
                    Pp[(size_t)row * 768 + col] = f2bf(acc[i][j][r]);
                }
            }
        return;
    }
    if (blockIdx.x >= 21) {  // c1p
        const int row = (blockIdx.x - 21) * 4 + wave;
        const float* ub = u + b * 768;
        float a = 0.f;
        for (int e = lane * 4; e < 768; e += 256) {
            const unsigned short* qr = Wqt + (size_t)row * 768 + e;
            float4 u4 = *(const float4*)(ub + e);
            a += bf2f(qr[0]) * u4.x + bf2f(qr[1]) * u4.y +
                 bf2f(qr[2]) * u4.z + bf2f(qr[3]) * u4.w;
        }
#pragma unroll
        for (int off = 32; off; off >>= 1) a += __shfl_down(a, off);
        if (lane == 0) c1p[b * 896 + row] = SCALE * a;
        return;
    }
    __shared__ unsigned short tl[128 * 136];
    const int tile = blockIdx.x;
    int tt = tile, tby = 0;
    while (tt >= 6 - tby) { tt -= 6 - tby; ++tby; }
    const int tbx = tby + tt;
    const int r = t >> 1;
    const int c0 = (t & 1) * 64;
    float acc[64];
#pragma unroll
    for (int j = 0; j < 64; ++j) acc[j] = 0.f;
    for (int sp = 0; sp < 8; ++sp) {
        const unsigned short* base =
            Gp + ((size_t)(b * 8 + sp) * 21 + tile) * 16384 + (size_t)r * 128 + c0;
#pragma unroll
        for (int j = 0; j < 8; ++j) {
            uint4 qv = *(const uint4*)(base + j * 8);
            const unsigned short* pv = (const unsigned short*)&qv;
#pragma unroll
            for (int k = 0; k < 8; ++k) acc[j * 8 + k] += bf2f(pv[k]);
        }
    }
    unsigned short v[64] __attribute__((aligned(16)));
#pragma unroll
    for (int j = 0; j < 64; ++j) v[j] = f2bf(acc[j]);
    unsigned short* dst = G + (size_t)b * 589824 +
                          (size_t)(tby * 128 + r) * 768 + tbx * 128 + c0;
#pragma unroll
    for (int j = 0; j < 8; ++j) *(uint4*)(dst + j * 8) = *(uint4*)&v[j * 8];
    if (tby != tbx) {
#pragma unroll
        for (int j = 0; j < 8; ++j)
            *(uint4*)&tl[r * 136 + c0 + j * 8] = *(uint4*)&v[j * 8];
        __syncthreads();
        unsigned short w[64] __attribute__((aligned(16)));
#pragma unroll
        for (int qq = 0; qq < 64; ++qq) w[qq] = tl[(c0 + qq) * 136 + r];
        unsigned short* dm = G + (size_t)b * 589824 +
                             (size_t)(tbx * 128 + r) * 768 + tby * 128 + c0;
#pragma unroll
        for (int j = 0; j < 8; ++j) *(uint4*)(dm + j * 8) = *(uint4*)&w[j * 8];
    }
}

extern "C" void kernel_launch(void* const* d_in, const int* in_sizes, int n_in,
                              void* d_out, int out_size, void* d_ws, size_t ws_size,
                              hipStream_t stream) {
    const float* x  = (const float*)d_in[0];
    const float* Wq = (const float*)d_in[1];
    const float* bq = (const float*)d_in[2];
    const float* Wk = (const float*)d_in[3];
    const float* bk = (const float*)d_in[4];
    const float* Wv = (const float*)d_in[5];
    const float* bv = (const float*)d_in[6];
    float* out = (float*)d_out;

    const long PB = 3145728;   // 4096*768
    const long DD = 589824;    // 768*768
    const long DA = 688128;    // 896*768

    unsigned short* ws  = (unsigned short*)d_ws;
    unsigned short* Xbf = ws;                       // 12582912
    unsigned short* Xt  = ws + 12582912;            // 12582912
    unsigned short* Pp  = ws + 25165824;            // 688128
    unsigned short* G   = ws + 25853952;            // 2359296
    unsigned short* Wqt = ws + 28213248;            // 688128 ([896][768])
    unsigned short* Wkt = ws + 28901376;            // 589824
    unsigned short* Wvb = ws + 29491200;            // 589824
    unsigned short* Gp  = ws + 30081024;            // 11010048 (21*32 tiles)
    unsigned short* C1p = Gp;                       // overlay after redvec2
    unsigned short* At  = Gp + 2752512;             // 2752512
    float* fbase = (float*)(ws + 41091072);
    float* csum = fbase;                            // 3072
    float* u    = fbase + 3072;                     // 3072
    float* c1p  = fbase + 6144;                     // 3584
    float* c2p  = fbase + 9728;                     // 896
    float* d2   = fbase + 10624;                    // 3072

    dim3 blk(256, 1, 1);

    prep_w<<<dim3(12, 12, 5), blk, 0, stream>>>(Wq, Wk, Wv, bq, Wqt, Wkt, Wvb, csum);
    prep_x<<<dim3(64, 12, 4), blk, 0, stream>>>(x, Xbf, Xt, csum);

    // Gram tri split-K partials (split=8, K=512) + u/d2 + c2p aux
    gram2<<<dim3(1664, 1, 1), blk, 0, stream>>>(Xt, Gp, Wk, Wv, Wqt, bk, bv,
                                                csum, u, d2, c2p);

    // reduce G + c1p + P+
    redvec2<<<dim3(287, 4), blk, 0, stream>>>(Gp, G, Wqt, Wkt, Pp, u, c1p);

    // C1+ = P+ ⊠ G   [4][896][768]   (64x64 tiles: 672 wgs)
    gemm64_bf16<BIAS_NONE><<<dim3(12, 14, 4), blk, 0, stream>>>(
        Pp, G, C1p, nullptr, nullptr, nullptr, nullptr,
        768, 768, 768, 768, 0, DD, DA, 1.0f, 0);

    // At = Wvb ⊠ C1+ (+rank2)   [4][768][896]   (64x64 tiles: 672 wgs)
    gemm64_bf16<BIAS_RANK2><<<dim3(14, 12, 4), blk, 0, stream>>>(
        Wvb, C1p, At, bv, c1p, d2, c2p,
        768, 768, 768, 896, 0, DA, DA, SCALE, 896);

    // out = Xbf ⊠ At (K=768) + r epilogue (At col 768)   fp32
    gemm_bf16<BIAS_RCOL, false><<<dim3(6, 32, 4), blk, 0, stream>>>(
        Xbf, At, out, nullptr, nullptr, nullptr, nullptr, At,
        768, 768, 896, 768, PB, DA, PB, 1.0f, 0);
}

// Round 8
// 119.423 us; speedup vs baseline: 2.1936x; 1.1296x over previous
//
#include <hip/hip_runtime.h>

// out = X A + 1 r^T,  A = scale Wq^T (K^T V).  With G = X^T X, s = X^T 1:
//   K^T V = Wk G Wv^T + (Wk s) bv^T + bk (Wv s)^T + S bk bv^T
// Augment Wq+ = [Wq^T; bq^T; 0pad] (896x768) so r = col 768 of At.
//   prep_w: Wqt+/Wkt/Wvb (bf16) + zero csum
//   prep_x: Xbf [4][4096][768], Xt [4][768][4096], csum atomics
//   gram2:  2496 tri 64x64 split-K Gram partial tiles (K=512, split=8)
//           + u/d2/c2p aux  (64-tile: 8 blocks/CU co-resident vs 2.6 at 128)
//   redvec2: reduce Gp (8 splits, 78 64x64 tiles) -> G (mirror); c1p; 42 P+
//   C1+ = P+ ⊠ G            [4][896][768]   (gemm64: 672 wgs)
//   At  = Wvb ⊠ C1+ (+rank2)[4][768][896]   (gemm64: 672 wgs)
//   out = Xbf ⊠ At (K=768) + At[col][768] epilogue   fp32
// GEMM: serial LDS loop (m97 structure), global_load_lds(16B) pre-swizzled
// source, XOR (r&7)<<4 reads, XCD-chunked bijective blockIdx swizzle.
// (R1: dbuf+counted-vmcnt regressed; R2: P+ move regressed; R3: fused
//  reduce 6x regression; R4/R5: split 4/16 regressed -> split=8 optimal.
//  R6: 64-tile for 168-wg GEMMs = -7us.  R7: FAILED on grid arithmetic —
//  gram2 grid must be 2496+768+224=3488 so c2p covers all 896 rows.)

typedef __attribute__((ext_vector_type(8))) __bf16 bf16x8;
typedef __attribute__((ext_vector_type(4))) float f32x4;

#define SCALE 0.03608439182435161f

union FragU {
    uint4 q;
    bf16x8 f;
    unsigned short s[8];
};

__device__ __forceinline__ unsigned short f2bf(float x) {
    unsigned int u = __builtin_bit_cast(unsigned int, x);
    u = (u + 0x7fffu + ((u >> 16) & 1u)) >> 16;
    return (unsigned short)u;
}
__device__ __forceinline__ float bf2f(unsigned short u) {
    unsigned int v = ((unsigned int)u) << 16;
    return __builtin_bit_cast(float, v);
}

__device__ __forceinline__ unsigned xcd_swizzle(unsigned lin, unsigned nwg) {
    const unsigned q = nwg >> 3, rr8 = nwg & 7;
    const unsigned xcd = lin & 7, o = lin >> 3;
    return (xcd < rr8 ? xcd * (q + 1) : rr8 * (q + 1) + (xcd - rr8) * q) + o;
}

__device__ __forceinline__ void stage_gl(const unsigned short* __restrict__ srcRowBase,
                                         int ldElems, char* lds, int wave, int lane) {
#pragma unroll
    for (int p = 0; p < 4; ++p) {
        int slotbase = (wave * 4 + p) * 1024;
        int slot = slotbase + lane * 16;
        int r = slot >> 7;
        int cb = (slot & 127) ^ ((r & 7) << 4);
        const char* g = (const char*)(srcRowBase + (size_t)r * ldElems) + cb;
        __builtin_amdgcn_global_load_lds(
            (const __attribute__((address_space(1))) unsigned int*)g,
            (__attribute__((address_space(3))) unsigned int*)(lds + slotbase),
            16, 0, 0);
    }
}

// 8KB half-size staging: half in {0,1} covers rows [half*32, half*32+32).
__device__ __forceinline__ void stage_gl64(const unsigned short* __restrict__ srcRowBase,
                                           int ldElems, char* lds, int half, int lane) {
#pragma unroll
    for (int p = 0; p < 4; ++p) {
        int slotbase = (half * 4 + p) * 1024;
        int slot = slotbase + lane * 16;
        int r = slot >> 7;
        int cb = (slot & 127) ^ ((r & 7) << 4);
        const char* g = (const char*)(srcRowBase + (size_t)r * ldElems) + cb;
        __builtin_amdgcn_global_load_lds(
            (const __attribute__((address_space(1))) unsigned int*)g,
            (__attribute__((address_space(3))) unsigned int*)(lds + slotbase),
            16, 0, 0);
    }
}

__device__ __forceinline__ bf16x8 load_frag(const char* lds, int row, int kbyte) {
    int a = row * 128 + kbyte;
    a ^= (row & 7) << 4;
    FragU u;
    u.q = *(const uint4*)(lds + a);
    return u.f;
}

__device__ __forceinline__ void gemm_core(const unsigned short* __restrict__ Ab,
                                          const unsigned short* __restrict__ Bb,
                                          int K, int lda, int ldb,
                                          char* ldsA, char* ldsB,
                                          int wave, int lane, int wm, int wn,
                                          int l15, int khi, f32x4 (&acc)[4][4]) {
    for (int k0 = 0; k0 < K; k0 += 64) {
        stage_gl(Ab + k0, lda, ldsA, wave, lane);
        stage_gl(Bb + k0, ldb, ldsB, wave, lane);
        __syncthreads();
#pragma unroll
        for (int kk = 0; kk < 2; ++kk) {
            const int kbyte = kk * 64 + khi;
            bf16x8 af[4], bfr[4];
#pragma unroll
            for (int i = 0; i < 4; ++i)
                af[i] = load_frag(ldsA, wm * 64 + i * 16 + l15, kbyte);
#pragma unroll
            for (int j = 0; j < 4; ++j)
                bfr[j] = load_frag(ldsB, wn * 64 + j * 16 + l15, kbyte);
#pragma unroll
            for (int i = 0; i < 4; ++i)
#pragma unroll
                for (int j = 0; j < 4; ++j)
                    acc[i][j] = __builtin_amdgcn_mfma_f32_16x16x32_bf16(
                        af[i], bfr[j], acc[i][j], 0, 0, 0);
        }
        __syncthreads();
    }
}

// 64x64 serial core: 4 waves as 2x2 of 32x32; waves 0-1 stage A, 2-3 stage B.
__device__ __forceinline__ void gemm_core64(const unsigned short* __restrict__ Ab,
                                            const unsigned short* __restrict__ Bb,
                                            int K, int lda, int ldb,
                                            char* ldsA, char* ldsB,
                                            int wave, int lane, int wr, int wc,
                                            int l15, int khi, f32x4 (&acc)[2][2]) {
    for (int k0 = 0; k0 < K; k0 += 64) {
        if (wave < 2)
            stage_gl64(Ab + k0, lda, ldsA, wave, lane);
        else
            stage_gl64(Bb + k0, ldb, ldsB, wave - 2, lane);
        __syncthreads();
#pragma unroll
        for (int kk = 0; kk < 2; ++kk) {
            const int kbyte = kk * 64 + khi;
            bf16x8 af[2], bfr[2];
#pragma unroll
            for (int i = 0; i < 2; ++i)
                af[i] = load_frag(ldsA, wr * 32 + i * 16 + l15, kbyte);
#pragma unroll
            for (int j = 0; j < 2; ++j)
                bfr[j] = load_frag(ldsB, wc * 32 + j * 16 + l15, kbyte);
#pragma unroll
            for (int i = 0; i < 2; ++i)
#pragma unroll
                for (int j = 0; j < 2; ++j)
                    acc[i][j] = __builtin_amdgcn_mfma_f32_16x16x32_bf16(
                        af[i], bfr[j], acc[i][j], 0, 0, 0);
        }
        __syncthreads();
    }
}

enum { BIAS_NONE = 0, BIAS_RANK2 = 2, BIAS_RCOL = 3 };

template <int BIASM, bool OUT_BF16>
__global__ __launch_bounds__(256, 2) void gemm_bf16(
    const unsigned short* __restrict__ A, const unsigned short* __restrict__ B,
    void* __restrict__ C,
    const float* __restrict__ p0, const float* __restrict__ p1,
    const float* __restrict__ p2, const float* __restrict__ p3,
    const unsigned short* __restrict__ rsrc,
    int K, int lda, int ldb, int ldc, long bsA, long bsB, long bsC,
    float scale, int vld1) {
    __shared__ __align__(16) char ldsA[16384];
    __shared__ __align__(16) char ldsB[16384];

    const unsigned gx = gridDim.x, gy = gridDim.y;
    const unsigned lin = blockIdx.x + gx * (blockIdx.y + gy * blockIdx.z);
    const unsigned wg = xcd_swizzle(lin, gx * gy * gridDim.z);
    const int bx = wg % gx;
    const int by = (wg / gx) % gy;
    const int z = wg / (gx * gy);

    const int m0 = by * 128;
    const int n0 = bx * 128;
    const unsigned short* Ab = A + (size_t)z * bsA + (size_t)m0 * lda;
    const unsigned short* Bb = B + (size_t)z * bsB + (size_t)n0 * ldb;

    const int lane = threadIdx.x & 63;
    const int wave = threadIdx.x >> 6;
    const int wm = wave >> 1;
    const int wn = wave & 1;
    const int l15 = lane & 15;
    const int khi = (lane >> 4) << 4;

    f32x4 acc[4][4];
#pragma unroll
    for (int i = 0; i < 4; ++i)
#pragma unroll
        for (int j = 0; j < 4; ++j)
            acc[i][j] = (f32x4){0.f, 0.f, 0.f, 0.f};

    gemm_core(Ab, Bb, K, lda, ldb, ldsA, ldsB, wave, lane, wm, wn, l15, khi, acc);

    const int rbase = (lane >> 4) << 2;
#pragma unroll
    for (int i = 0; i < 4; ++i) {
#pragma unroll
        for (int r = 0; r < 4; ++r) {
            int row = m0 + wm * 64 + i * 16 + rbase + r;
            float rA = 0.f, rB = 0.f;
            if (BIASM == BIAS_RANK2) {
                rA = p0[row];
                rB = p2[z * 768 + row];
            }
#pragma unroll
            for (int j = 0; j < 4; ++j) {
                int col = n0 + wn * 64 + j * 16 + l15;
                float v = acc[i][j][r] * scale;
                if (BIASM == BIAS_RANK2) v += rA * p1[z * vld1 + col] + rB * p3[col];
                if (BIASM == BIAS_RCOL)
                    v += bf2f(rsrc[(size_t)z * 688128 + (size_t)col * 896 + 768]);
                size_t off = (size_t)z * bsC + (size_t)row * ldc + col;
                if (OUT_BF16)
                    ((unsigned short*)C)[off] = f2bf(v);
                else
                    ((float*)C)[off] = v;
            }
        }
    }
}

// 64x64-tile GEMM for the low-workgroup mid-chain GEMMs.
template <int BIASM>
__global__ __launch_bounds__(256, 2) void gemm64_bf16(
    const unsigned short* __restrict__ A, const unsigned short* __restrict__ B,
    unsigned short* __restrict__ C,
    const float* __restrict__ p0, const float* __restrict__ p1,
    const float* __restrict__ p2, const float* __restrict__ p3,
    int K, int lda, int ldb, int ldc, long bsA, long bsB, long bsC,
    float scale, int vld1) {
    __shared__ __align__(16) char ldsA[8192];
    __shared__ __align__(16) char ldsB[8192];

    const unsigned gx = gridDim.x, gy = gridDim.y;
    const unsigned lin = blockIdx.x + gx * (blockIdx.y + gy * blockIdx.z);
    const unsigned wg = xcd_swizzle(lin, gx * gy * gridDim.z);
    const int bx = wg % gx;
    const int by = (wg / gx) % gy;
    const int z = wg / (gx * gy);

    const int m0 = by * 64;
    const int n0 = bx * 64;
    const unsigned short* Ab = A + (size_t)z * bsA + (size_t)m0 * lda;
    const unsigned short* Bb = B + (size_t)z * bsB + (size_t)n0 * ldb;

    const int lane = threadIdx.x & 63;
    const int wave = threadIdx.x >> 6;
    const int wr = wave >> 1;
    const int wc = wave & 1;
    const int l15 = lane & 15;
    const int khi = (lane >> 4) << 4;

    f32x4 acc[2][2];
#pragma unroll
    for (int i = 0; i < 2; ++i)
#pragma unroll
        for (int j = 0; j < 2; ++j)
            acc[i][j] = (f32x4){0.f, 0.f, 0.f, 0.f};

    gemm_core64(Ab, Bb, K, lda, ldb, ldsA, ldsB, wave, lane, wr, wc, l15, khi, acc);

    const int rbase = (lane >> 4) << 2;
#pragma unroll
    for (int i = 0; i < 2; ++i) {
#pragma unroll
        for (int r = 0; r < 4; ++r) {
            int row = m0 + wr * 32 + i * 16 + rbase + r;
            float rA = 0.f, rB = 0.f;
            if (BIASM == BIAS_RANK2) {
                rA = p0[row];
                rB = p2[z * 768 + row];
            }
#pragma unroll
            for (int j = 0; j < 2; ++j) {
                int col = n0 + wc * 32 + j * 16 + l15;
                float v = acc[i][j][r] * scale;
                if (BIASM == BIAS_RANK2) v += rA * p1[z * vld1 + col] + rB * p3[col];
                C[(size_t)z * bsC + (size_t)row * ldc + col] = f2bf(v);
            }
        }
    }
}

// z=0: Wqt+ rows 0..767 = Wq^T; z=1: Wkt = Wk^T; z=2: Wvb = bf16(Wv);
// z=3: Wqt+ row 768 = bq, rows 769..895 = 0; z=4: zero csum.
__global__ __launch_bounds__(256) void prep_w(const float* __restrict__ Wq,
                                              const float* __restrict__ Wk,
                                              const float* __restrict__ Wv,
                                              const float* __restrict__ bq,
                                              unsigned short* __restrict__ Wqt,
                                              unsigned short* __restrict__ Wkt,
                                              unsigned short* __restrict__ Wvb,
                                              float* __restrict__ csum) {
    const int mode = blockIdx.z;
    const int t = threadIdx.x;
    if (mode == 4) {
        if (blockIdx.x == 0 && blockIdx.y == 0) {
            float4 z4 = {0.f, 0.f, 0.f, 0.f};
            for (int i = t * 4; i < 3072; i += 1024) *(float4*)(csum + i) = z4;
        }
        return;
    }
    if (mode == 3) {
        if (blockIdx.y) return;
        int rr = 768 + (t >> 1);
        int c0 = blockIdx.x * 64 + (t & 1) * 32;
        unsigned short v[32] __attribute__((aligned(16)));
        if (rr == 768) {
#pragma unroll
            for (int j = 0; j < 32; ++j) v[j] = f2bf(bq[c0 + j]);
        } else {
#pragma unroll
            for (int j = 0; j < 32; ++j) v[j] = 0;
        }
        unsigned short* dst = Wqt + (size_t)rr * 768 + c0;
#pragma unroll
        for (int j = 0; j < 4; ++j) *(uint4*)(dst + j * 8) = *(uint4*)&v[j * 8];
        return;
    }
    __shared__ unsigned short tile[64 * 72];
    const float* src = mode == 0 ? Wq : (mode == 1 ? Wk : Wv);
    const int r0 = blockIdx.x * 64;
    const int c0 = blockIdx.y * 64;
    int r = t >> 2, cq = (t & 3) * 16;
    unsigned short v[16] __attribute__((aligned(16)));
    const float* s = src + (size_t)(r0 + r) * 768 + c0 + cq;
#pragma unroll
    for (int j = 0; j < 16; j += 4) {
        float4 f = *(const float4*)(s + j);
        v[j] = f2bf(f.x); v[j + 1] = f2bf(f.y);
        v[j + 2] = f2bf(f.z); v[j + 3] = f2bf(f.w);
    }
    if (mode == 2) {
        unsigned short* dst = Wvb + (size_t)(r0 + r) * 768 + c0 + cq;
        *(uint4*)dst = *(uint4*)&v[0];
        *(uint4*)(dst + 8) = *(uint4*)&v[8];
        return;
    }
    *(uint4*)&tile[r * 72 + cq] = *(uint4*)&v[0];
    *(uint4*)&tile[r * 72 + cq + 8] = *(uint4*)&v[8];
    __syncthreads();
    int dr = t >> 2, sq = (t & 3) * 16;
    unsigned short w[16] __attribute__((aligned(16)));
#pragma unroll
    for (int j = 0; j < 16; ++j) w[j] = tile[(sq + j) * 72 + dr];
    unsigned short* dst = (mode == 0 ? Wqt : Wkt) + (size_t)(c0 + dr) * 768 + r0 + sq;
    *(uint4*)dst = *(uint4*)&w[0];
    *(uint4*)(dst + 8) = *(uint4*)&w[8];
}

// Xbf [4][4096][768], Xt [4][768][4096], csum atomics.
__global__ __launch_bounds__(256) void prep_x(const float* __restrict__ X,
                                              unsigned short* __restrict__ Xbf,
                                              unsigned short* __restrict__ Xt,
                                              float* __restrict__ csum) {
    const int b = blockIdx.z;
    const int s0 = blockIdx.x * 64;
    const int t = threadIdx.x;
    __shared__ unsigned short tile[64 * 72];
    const int d0 = blockIdx.y * 64;
    const float* Xb = X + (size_t)b * 4096 * 768;
    unsigned short* XbfB = Xbf + (size_t)b * 4096 * 768;
    unsigned short* XtB = Xt + (size_t)b * 768 * 4096;
    {
        int r = t >> 2, cq = (t & 3) * 16;
        const float* src = Xb + (size_t)(s0 + r) * 768 + d0 + cq;
        unsigned short v[16] __attribute__((aligned(16)));
#pragma unroll
        for (int j = 0; j < 16; j += 4) {
            float4 f = *(const float4*)(src + j);
            v[j] = f2bf(f.x); v[j + 1] = f2bf(f.y);
            v[j + 2] = f2bf(f.z); v[j + 3] = f2bf(f.w);
        }
        unsigned short* dst = XbfB + (size_t)(s0 + r) * 768 + d0 + cq;
        *(uint4*)dst = *(uint4*)&v[0];
        *(uint4*)(dst + 8) = *(uint4*)&v[8];
        *(uint4*)&tile[r * 72 + cq] = *(uint4*)&v[0];
        *(uint4*)&tile[r * 72 + cq + 8] = *(uint4*)&v[8];
    }
    __syncthreads();
    {
        int dr = t >> 2, sq = (t & 3) * 16;
        unsigned short v[16] __attribute__((aligned(16)));
        float part = 0.f;
#pragma unroll
        for (int j = 0; j < 16; ++j) {
            unsigned short u = tile[(sq + j) * 72 + dr];
            v[j] = u;
            part += bf2f(u);
        }
        unsigned short* dst = XtB + (size_t)(d0 + dr) * 4096 + s0 + sq;
        *(uint4*)dst = *(uint4*)&v[0];
        *(uint4*)(dst + 8) = *(uint4*)&v[8];
        part += __shfl_down(part, 1);
        part += __shfl_down(part, 2);
        if ((t & 3) == 0) atomicAdd(&csum[b * 768 + d0 + dr], part);
    }
}

// Flat grid 3488:
//   wg < 2496: triangular 64x64 Gram partial tile (tile=wg%78, zz=wg/78;
//              b=zz>>3, split=zz&7, K=512) -> packed Gp [zz*78+tile][64][64]
//   wg < 3264: aux u/d2: id=wg-2496, b=id/192, row=(id%192)*4+wave
//   wg >=3264: c2p: row=(wg-3264)*4+wave (<896): c2p[row]=Wqt+[row].bk
__global__ __launch_bounds__(256, 2) void gram2(
    const unsigned short* __restrict__ Xt, unsigned short* __restrict__ Gp,
    const float* __restrict__ Wk, const float* __restrict__ Wv,
    const unsigned short* __restrict__ Wqt,
    const float* __restrict__ bk, const float* __restrict__ bv,
    const float* __restrict__ csum,
    float* __restrict__ u, float* __restrict__ d2, float* __restrict__ c2p) {
    const long PB = 3145728;
    const unsigned wg = xcd_swizzle(blockIdx.x, gridDim.x);
    const int t = threadIdx.x;
    const int lane = t & 63;
    const int wave = t >> 6;

    if (wg >= 3264) {  // c2p
        const int row = (wg - 3264) * 4 + wave;
        float a = 0.f;
        for (int e = lane * 4; e < 768; e += 256) {
            const unsigned short* qr = Wqt + (size_t)row * 768 + e;
            float4 b4 = *(const float4*)(bk + e);
            a += bf2f(qr[0]) * b4.x + bf2f(qr[1]) * b4.y +
                 bf2f(qr[2]) * b4.z + bf2f(qr[3]) * b4.w;
        }
#pragma unroll
        for (int off = 32; off; off >>= 1) a += __shfl_down(a, off);
        if (lane == 0) c2p[row] = a;
        return;
    }
    if (wg >= 2496) {  // u + d2
        const int id = wg - 2496;
        const int b = id / 192;
        const int row = (id % 192) * 4 + wave;
        const float* s = csum + b * 768;
        float aU = 0.f, aD = 0.f;
        for (int e = lane * 4; e < 768; e += 256) {
            float4 wk4 = *(const float4*)(Wk + (size_t)row * 768 + e);
            float4 wv4 = *(const float4*)(Wv + (size_t)row * 768 + e);
            float4 s4 = *(const float4*)(s + e);
            aU += wk4.x * s4.x + wk4.y * s4.y + wk4.z * s4.z + wk4.w * s4.w;
            aD += wv4.x * s4.x + wv4.y * s4.y + wv4.z * s4.z + wv4.w * s4.w;
        }
#pragma unroll
        for (int off = 32; off; off >>= 1) {
            aU += __shfl_down(aU, off);
            aD += __shfl_down(aD, off);
        }
        if (lane == 0) {
            u[b * 768 + row] = aU;
            d2[b * 768 + row] = SCALE * (aD + 4096.f * bv[row]);
        }
        return;
    }

    __shared__ __align__(16) char ldsA[8192];
    __shared__ __align__(16) char ldsB[8192];
    const int wr = wave >> 1;
    const int wc = wave & 1;
    const int l15 = lane & 15;
    const int khi = (lane >> 4) << 4;
    f32x4 acc[2][2];
#pragma unroll
    for (int i = 0; i < 2; ++i)
#pragma unroll
        for (int j = 0; j < 2; ++j)
            acc[i][j] = (f32x4){0.f, 0.f, 0.f, 0.f};
    const int rbase = (lane >> 4) << 2;

    const int tile = wg % 78;
    const int zz = wg / 78;
    const int b = zz >> 3;
    const int koff = (zz & 7) * 512;
    int tt = tile, tby = 0;
    while (tt >= 12 - tby) { tt -= 12 - tby; ++tby; }
    const int m0 = tby * 64;
    const int n0 = (tby + tt) * 64;
    const unsigned short* Ab = Xt + (size_t)b * PB + (size_t)m0 * 4096 + koff;
    const unsigned short* Bb = Xt + (size_t)b * PB + (size_t)n0 * 4096 + koff;
    gemm_core64(Ab, Bb, 512, 4096, 4096, ldsA, ldsB, wave, lane, wr, wc, l15, khi, acc);
    unsigned short* dst = Gp + ((size_t)zz * 78 + tile) * 4096;
#pragma unroll
    for (int i = 0; i < 2; ++i)
#pragma unroll
        for (int r = 0; r < 4; ++r) {
            int rloc = wr * 32 + i * 16 + rbase + r;
#pragma unroll
            for (int j = 0; j < 2; ++j) {
                int cloc = wc * 32 + j * 16 + l15;
                dst[(size_t)rloc * 64 + cloc] = f2bf(acc[i][j][r]);
            }
        }
}

// grid (344,4):
//   x<78: reduce Gp (8 splits) -> 64x64 G tile, mirror off-diag (y=b)
//   78<=x<302: c1p[b][row] = SCALE * Wqt+[row] . u_b   (row=(x-78)*4+wave)
//   x>=302 && y==0: P+ tile id=x-302 (7x6, K=768) -> Pp
__global__ __launch_bounds__(256, 2) void redvec2(
    const unsigned short* __restrict__ Gp, unsigned short* __restrict__ G,
    const unsigned short* __restrict__ Wqt, const unsigned short* __restrict__ Wkt,
    unsigned short* __restrict__ Pp,
    const float* __restrict__ u, float* __restrict__ c1p) {
    const int b = blockIdx.y;
    const int t = threadIdx.x;
    const int lane = t & 63;
    const int wave = t >> 6;
    if (blockIdx.x >= 302) {
        if (b) return;
        __shared__ __align__(16) char ldsA[16384];
        __shared__ __align__(16) char ldsB[16384];
        const int id = blockIdx.x - 302;
        const int m0 = (id / 6) * 128;
        const int n0 = (id % 6) * 128;
        const int wm = wave >> 1;
        const int wn = wave & 1;
        const int l15 = lane & 15;
        const int khi = (lane >> 4) << 4;
        f32x4 acc[4][4];
#pragma unroll
        for (int i = 0; i < 4; ++i)
#pragma unroll
            for (int j = 0; j < 4; ++j)
                acc[i][j] = (f32x4){0.f, 0.f, 0.f, 0.f};
        gemm_core(Wqt + (size_t)m0 * 768, Wkt + (size_t)n0 * 768,
                  768, 768, 768, ldsA, ldsB, wave, lane, wm, wn, l15, khi, acc);
        const int rbase = (lane >> 4) << 2;
#pragma unroll
        for (int i = 0; i < 4; ++i)
#pragma unroll
            for (int r = 0; r < 4; ++r) {
                int row = m0 + wm * 64 + i * 16 + rbase + r;
#pragma unroll
                for (int j = 0; j < 4; ++j) {
                    int col = n0 + wn * 64 + j * 16 + l15;
                    Pp[(size_t)row * 768 + col] = f2bf(acc[i][j][r]);
                }
            }
        return;
    }
    if (blockIdx.x >= 78) {  // c1p
        const int row = (blockIdx.x - 78) * 4 + wave;
        const float* ub = u + b * 768;
        float a = 0.f;
        for (int e = lane * 4; e < 768; e += 256) {
            const unsigned short* qr = Wqt + (size_t)row * 768 + e;
            float4 u4 = *(const float4*)(ub + e);
            a += bf2f(qr[0]) * u4.x + bf2f(qr[1]) * u4.y +
                 bf2f(qr[2]) * u4.z + bf2f(qr[3]) * u4.w;
        }
#pragma unroll
        for (int off = 32; off; off >>= 1) a += __shfl_down(a, off);
        if (lane == 0) c1p[b * 896 + row] = SCALE * a;
        return;
    }
    // reduce one 64x64 tile over 8 splits; mirror off-diagonal
    __shared__ unsigned short tl[64 * 72];
    const int tile = blockIdx.x;
    int tt = tile, tby = 0;
    while (tt >= 12 - tby) { tt -= 12 - tby; ++tby; }
    const int tbx = tby + tt;
    const int r = t >> 2;
    const int c0 = (t & 3) * 16;
    float acc[16];
#pragma unroll
    for (int j = 0; j < 16; ++j) acc[j] = 0.f;
    for (int sp = 0; sp < 8; ++sp) {
        const unsigned short* base =
            Gp + ((size_t)(b * 8 + sp) * 78 + tile) * 4096 + (size_t)r * 64 + c0;
#pragma unroll
        for (int j = 0; j < 2; ++j) {
            uint4 qv = *(const uint4*)(base + j * 8);
            const unsigned short* pv = (const unsigned short*)&qv;
#pragma unroll
            for (int k = 0; k < 8; ++k) acc[j * 8 + k] += bf2f(pv[k]);
        }
    }
    unsigned short v[16] __attribute__((aligned(16)));
#pragma unroll
    for (int j = 0; j < 16; ++j) v[j] = f2bf(acc[j]);
    unsigned short* dst = G + (size_t)b * 589824 +
                          (size_t)(tby * 64 + r) * 768 + tbx * 64 + c0;
    *(uint4*)dst = *(uint4*)&v[0];
    *(uint4*)(dst + 8) = *(uint4*)&v[8];
    if (tby != tbx) {
        *(uint4*)&tl[r * 72 + c0] = *(uint4*)&v[0];
        *(uint4*)&tl[r * 72 + c0 + 8] = *(uint4*)&v[8];
        __syncthreads();
        int dr = t >> 2, sq = (t & 3) * 16;
        unsigned short w[16] __attribute__((aligned(16)));
#pragma unroll
        for (int j = 0; j < 16; ++j) w[j] = tl[(sq + j) * 72 + dr];
        unsigned short* dm = G + (size_t)b * 589824 +
                             (size_t)(tbx * 64 + dr) * 768 + tby * 64 + sq;
        *(uint4*)dm = *(uint4*)&w[0];
        *(uint4*)(dm + 8) = *(uint4*)&w[8];
    }
}

extern "C" void kernel_launch(void* const* d_in, const int* in_sizes, int n_in,
                              void* d_out, int out_size, void* d_ws, size_t ws_size,
                              hipStream_t stream) {
    const float* x  = (const float*)d_in[0];
    const float* Wq = (const float*)d_in[1];
    const float* bq = (const float*)d_in[2];
    const float* Wk = (const float*)d_in[3];
    const float* bk = (const float*)d_in[4];
    const float* Wv = (const float*)d_in[5];
    const float* bv = (const float*)d_in[6];
    float* out = (float*)d_out;

    const long PB = 3145728;   // 4096*768
    const long DD = 589824;    // 768*768
    const long DA = 688128;    // 896*768

    unsigned short* ws  = (unsigned short*)d_ws;
    unsigned short* Xbf = ws;                       // 12582912
    unsigned short* Xt  = ws + 12582912;            // 12582912
    unsigned short* Pp  = ws + 25165824;            // 688128
    unsigned short* G   = ws + 25853952;            // 2359296
    unsigned short* Wqt = ws + 28213248;            // 688128 ([896][768])
    unsigned short* Wkt = ws + 28901376;            // 589824
    unsigned short* Wvb = ws + 29491200;            // 589824
    unsigned short* Gp  = ws + 30081024;            // 10223616 used (78*32 64x64)
    unsigned short* C1p = Gp;                       // overlay after redvec2
    unsigned short* At  = Gp + 2752512;             // 2752512
    float* fbase = (float*)(ws + 41091072);
    float* csum = fbase;                            // 3072
    float* u    = fbase + 3072;                     // 3072
    float* c1p  = fbase + 6144;                     // 3584
    float* c2p  = fbase + 9728;                     // 896
    float* d2   = fbase + 10624;                    // 3072

    dim3 blk(256, 1, 1);

    prep_w<<<dim3(12, 12, 5), blk, 0, stream>>>(Wq, Wk, Wv, bq, Wqt, Wkt, Wvb, csum);
    prep_x<<<dim3(64, 12, 4), blk, 0, stream>>>(x, Xbf, Xt, csum);

    // Gram tri 64x64 split-K partials (split=8, K=512) + u/d2 + c2p aux
    gram2<<<dim3(3488, 1, 1), blk, 0, stream>>>(Xt, Gp, Wk, Wv, Wqt, bk, bv,
                                                csum, u, d2, c2p);

    // reduce G (78 tiles) + c1p + P+
    redvec2<<<dim3(344, 4), blk, 0, stream>>>(Gp, G, Wqt, Wkt, Pp, u, c1p);

    // C1+ = P+ ⊠ G   [4][896][768]   (64x64 tiles: 672 wgs)
    gemm64_bf16<BIAS_NONE><<<dim3(12, 14, 4), blk, 0, stream>>>(
        Pp, G, C1p, nullptr, nullptr, nullptr, nullptr,
        768, 768, 768, 768, 0, DD, DA, 1.0f, 0);

    // At = Wvb ⊠ C1+ (+rank2)   [4][768][896]   (64x64 tiles: 672 wgs)
    gemm64_bf16<BIAS_RANK2><<<dim3(14, 12, 4), blk, 0, stream>>>(
        Wvb, C1p, At, bv, c1p, d2, c2p,
        768, 768, 768, 896, 0, DA, DA, SCALE, 896);

    // out = Xbf ⊠ At (K=768) + r epilogue (At col 768)   fp32
    gemm_bf16<BIAS_RCOL, false><<<dim3(6, 32, 4), blk, 0, stream>>>(
        Xbf, At, out, nullptr, nullptr, nullptr, nullptr, At,
        768, 768, 896, 768, PB, DA, PB, 1.0f, 0);
}

// Round 9
// 117.810 us; speedup vs baseline: 2.2236x; 1.0137x over previous
//
#include <hip/hip_runtime.h>

// out = X A + 1 r^T,  A = scale Wq^T (K^T V).  With G = X^T X, s = X^T 1:
//   K^T V = Wk G Wv^T + (Wk s) bv^T + bk (Wv s)^T + S bk bv^T
// Augment Wq+ = [Wq^T; bq^T; 0pad] (896x768) so r = col 768 of At.
//   prep_w: Wqt+/Wkt/Wvb (bf16) + zero csum
//   prep_x: Xbf [4][4096][768], Xt [4][768][4096], csum atomics
//   gram2:  2496 tri 64x64 split-K Gram partial tiles (K=512, split=8)
//           + u/d2/c2p aux
//   redvec2: reduce Gp (8 splits, 78 64x64 tiles) -> G (mirror); c1p;
//            168 64x64 P+ tiles spread over all 4 y-slices
//   C1+ = P+ ⊠ G            [4][896][768]   (gemm64: 672 wgs)
//   At  = Wvb ⊠ C1+ (+rank2)[4][768][896]   (gemm64: 672 wgs)
//   out = Xbf ⊠ At (K=768) + At[col][768] epilogue   fp32 (gemm64: 3072 wgs)
// GEMM: serial LDS loop (m97 structure), global_load_lds(16B) pre-swizzled
// source, XOR (r&7)<<4 reads, XCD-chunked bijective blockIdx swizzle.
// All GEMMs now 64x64-tile (validated occupancy lever: R6 C1/At -7us,
// R8 gram2 -15us — serial core is latency-bound, wants >=8 blocks/CU).
// (R1: dbuf+counted-vmcnt regressed; R2: P+ move regressed; R3: fused
//  reduce 6x regression; R4/R5: split 4/16 regressed -> split=8 optimal.
//  R7: FAILED on gram2 grid arithmetic — aux budget must cover all rows.)

typedef __attribute__((ext_vector_type(8))) __bf16 bf16x8;
typedef __attribute__((ext_vector_type(4))) float f32x4;

#define SCALE 0.03608439182435161f

union FragU {
    uint4 q;
    bf16x8 f;
    unsigned short s[8];
};

__device__ __forceinline__ unsigned short f2bf(float x) {
    unsigned int u = __builtin_bit_cast(unsigned int, x);
    u = (u + 0x7fffu + ((u >> 16) & 1u)) >> 16;
    return (unsigned short)u;
}
__device__ __forceinline__ float bf2f(unsigned short u) {
    unsigned int v = ((unsigned int)u) << 16;
    return __builtin_bit_cast(float, v);
}

__device__ __forceinline__ unsigned xcd_swizzle(unsigned lin, unsigned nwg) {
    const unsigned q = nwg >> 3, rr8 = nwg & 7;
    const unsigned xcd = lin & 7, o = lin >> 3;
    return (xcd < rr8 ? xcd * (q + 1) : rr8 * (q + 1) + (xcd - rr8) * q) + o;
}

// 8KB half-size staging: half in {0,1} covers rows [half*32, half*32+32).
__device__ __forceinline__ void stage_gl64(const unsigned short* __restrict__ srcRowBase,
                                           int ldElems, char* lds, int half, int lane) {
#pragma unroll
    for (int p = 0; p < 4; ++p) {
        int slotbase = (half * 4 + p) * 1024;
        int slot = slotbase + lane * 16;
        int r = slot >> 7;
        int cb = (slot & 127) ^ ((r & 7) << 4);
        const char* g = (const char*)(srcRowBase + (size_t)r * ldElems) + cb;
        __builtin_amdgcn_global_load_lds(
            (const __attribute__((address_space(1))) unsigned int*)g,
            (__attribute__((address_space(3))) unsigned int*)(lds + slotbase),
            16, 0, 0);
    }
}

__device__ __forceinline__ bf16x8 load_frag(const char* lds, int row, int kbyte) {
    int a = row * 128 + kbyte;
    a ^= (row & 7) << 4;
    FragU u;
    u.q = *(const uint4*)(lds + a);
    return u.f;
}

// 64x64 serial core: 4 waves as 2x2 of 32x32; waves 0-1 stage A, 2-3 stage B.
__device__ __forceinline__ void gemm_core64(const unsigned short* __restrict__ Ab,
                                            const unsigned short* __restrict__ Bb,
                                            int K, int lda, int ldb,
                                            char* ldsA, char* ldsB,
                                            int wave, int lane, int wr, int wc,
                                            int l15, int khi, f32x4 (&acc)[2][2]) {
    for (int k0 = 0; k0 < K; k0 += 64) {
        if (wave < 2)
            stage_gl64(Ab + k0, lda, ldsA, wave, lane);
        else
            stage_gl64(Bb + k0, ldb, ldsB, wave - 2, lane);
        __syncthreads();
#pragma unroll
        for (int kk = 0; kk < 2; ++kk) {
            const int kbyte = kk * 64 + khi;
            bf16x8 af[2], bfr[2];
#pragma unroll
            for (int i = 0; i < 2; ++i)
                af[i] = load_frag(ldsA, wr * 32 + i * 16 + l15, kbyte);
#pragma unroll
            for (int j = 0; j < 2; ++j)
                bfr[j] = load_frag(ldsB, wc * 32 + j * 16 + l15, kbyte);
#pragma unroll
            for (int i = 0; i < 2; ++i)
#pragma unroll
                for (int j = 0; j < 2; ++j)
                    acc[i][j] = __builtin_amdgcn_mfma_f32_16x16x32_bf16(
                        af[i], bfr[j], acc[i][j], 0, 0, 0);
        }
        __syncthreads();
    }
}

enum { BIAS_NONE = 0, BIAS_RANK2 = 2, BIAS_RCOL = 3 };

// 64x64-tile GEMM (all GEMM dispatches).
template <int BIASM, bool OUT_BF16>
__global__ __launch_bounds__(256, 2) void gemm64_bf16(
    const unsigned short* __restrict__ A, const unsigned short* __restrict__ B,
    void* __restrict__ C,
    const float* __restrict__ p0, const float* __restrict__ p1,
    const float* __restrict__ p2, const float* __restrict__ p3,
    const unsigned short* __restrict__ rsrc,
    int K, int lda, int ldb, int ldc, long bsA, long bsB, long bsC,
    float scale, int vld1) {
    __shared__ __align__(16) char ldsA[8192];
    __shared__ __align__(16) char ldsB[8192];

    const unsigned gx = gridDim.x, gy = gridDim.y;
    const unsigned lin = blockIdx.x + gx * (blockIdx.y + gy * blockIdx.z);
    const unsigned wg = xcd_swizzle(lin, gx * gy * gridDim.z);
    const int bx = wg % gx;
    const int by = (wg / gx) % gy;
    const int z = wg / (gx * gy);

    const int m0 = by * 64;
    const int n0 = bx * 64;
    const unsigned short* Ab = A + (size_t)z * bsA + (size_t)m0 * lda;
    const unsigned short* Bb = B + (size_t)z * bsB + (size_t)n0 * ldb;

    const int lane = threadIdx.x & 63;
    const int wave = threadIdx.x >> 6;
    const int wr = wave >> 1;
    const int wc = wave & 1;
    const int l15 = lane & 15;
    const int khi = (lane >> 4) << 4;

    f32x4 acc[2][2];
#pragma unroll
    for (int i = 0; i < 2; ++i)
#pragma unroll
        for (int j = 0; j < 2; ++j)
            acc[i][j] = (f32x4){0.f, 0.f, 0.f, 0.f};

    gemm_core64(Ab, Bb, K, lda, ldb, ldsA, ldsB, wave, lane, wr, wc, l15, khi, acc);

    const int rbase = (lane >> 4) << 2;
#pragma unroll
    for (int i = 0; i < 2; ++i) {
#pragma unroll
        for (int r = 0; r < 4; ++r) {
            int row = m0 + wr * 32 + i * 16 + rbase + r;
            float rA = 0.f, rB = 0.f;
            if (BIASM == BIAS_RANK2) {
                rA = p0[row];
                rB = p2[z * 768 + row];
            }
#pragma unroll
            for (int j = 0; j < 2; ++j) {
                int col = n0 + wc * 32 + j * 16 + l15;
                float v = acc[i][j][r] * scale;
                if (BIASM == BIAS_RANK2) v += rA * p1[z * vld1 + col] + rB * p3[col];
                if (BIASM == BIAS_RCOL)
                    v += bf2f(rsrc[(size_t)z * 688128 + (size_t)col * 896 + 768]);
                size_t off = (size_t)z * bsC + (size_t)row * ldc + col;
                if (OUT_BF16)
                    ((unsigned short*)C)[off] = f2bf(v);
                else
                    ((float*)C)[off] = v;
            }
        }
    }
}

// z=0: Wqt+ rows 0..767 = Wq^T; z=1: Wkt = Wk^T; z=2: Wvb = bf16(Wv);
// z=3: Wqt+ row 768 = bq, rows 769..895 = 0; z=4: zero csum.
__global__ __launch_bounds__(256) void prep_w(const float* __restrict__ Wq,
                                              const float* __restrict__ Wk,
                                              const float* __restrict__ Wv,
                                              const float* __restrict__ bq,
                                              unsigned short* __restrict__ Wqt,
                                              unsigned short* __restrict__ Wkt,
                                              unsigned short* __restrict__ Wvb,
                                              float* __restrict__ csum) {
    const int mode = blockIdx.z;
    const int t = threadIdx.x;
    if (mode == 4) {
        if (blockIdx.x == 0 && blockIdx.y == 0) {
            float4 z4 = {0.f, 0.f, 0.f, 0.f};
            for (int i = t * 4; i < 3072; i += 1024) *(float4*)(csum + i) = z4;
        }
        return;
    }
    if (mode == 3) {
        if (blockIdx.y) return;
        int rr = 768 + (t >> 1);
        int c0 = blockIdx.x * 64 + (t & 1) * 32;
        unsigned short v[32] __attribute__((aligned(16)));
        if (rr == 768) {
#pragma unroll
            for (int j = 0; j < 32; ++j) v[j] = f2bf(bq[c0 + j]);
        } else {
#pragma unroll
            for (int j = 0; j < 32; ++j) v[j] = 0;
        }
        unsigned short* dst = Wqt + (size_t)rr * 768 + c0;
#pragma unroll
        for (int j = 0; j < 4; ++j) *(uint4*)(dst + j * 8) = *(uint4*)&v[j * 8];
        return;
    }
    __shared__ unsigned short tile[64 * 72];
    const float* src = mode == 0 ? Wq : (mode == 1 ? Wk : Wv);
    const int r0 = blockIdx.x * 64;
    const int c0 = blockIdx.y * 64;
    int r = t >> 2, cq = (t & 3) * 16;
    unsigned short v[16] __attribute__((aligned(16)));
    const float* s = src + (size_t)(r0 + r) * 768 + c0 + cq;
#pragma unroll
    for (int j = 0; j < 16; j += 4) {
        float4 f = *(const float4*)(s + j);
        v[j] = f2bf(f.x); v[j + 1] = f2bf(f.y);
        v[j + 2] = f2bf(f.z); v[j + 3] = f2bf(f.w);
    }
    if (mode == 2) {
        unsigned short* dst = Wvb + (size_t)(r0 + r) * 768 + c0 + cq;
        *(uint4*)dst = *(uint4*)&v[0];
        *(uint4*)(dst + 8) = *(uint4*)&v[8];
        return;
    }
    *(uint4*)&tile[r * 72 + cq] = *(uint4*)&v[0];
    *(uint4*)&tile[r * 72 + cq + 8] = *(uint4*)&v[8];
    __syncthreads();
    int dr = t >> 2, sq = (t & 3) * 16;
    unsigned short w[16] __attribute__((aligned(16)));
#pragma unroll
    for (int j = 0; j < 16; ++j) w[j] = tile[(sq + j) * 72 + dr];
    unsigned short* dst = (mode == 0 ? Wqt : Wkt) + (size_t)(c0 + dr) * 768 + r0 + sq;
    *(uint4*)dst = *(uint4*)&w[0];
    *(uint4*)(dst + 8) = *(uint4*)&w[8];
}

// Xbf [4][4096][768], Xt [4][768][4096], csum atomics.
__global__ __launch_bounds__(256) void prep_x(const float* __restrict__ X,
                                              unsigned short* __restrict__ Xbf,
                                              unsigned short* __restrict__ Xt,
                                              float* __restrict__ csum) {
    const int b = blockIdx.z;
    const int s0 = blockIdx.x * 64;
    const int t = threadIdx.x;
    __shared__ unsigned short tile[64 * 72];
    const int d0 = blockIdx.y * 64;
    const float* Xb = X + (size_t)b * 4096 * 768;
    unsigned short* XbfB = Xbf + (size_t)b * 4096 * 768;
    unsigned short* XtB = Xt + (size_t)b * 768 * 4096;
    {
        int r = t >> 2, cq = (t & 3) * 16;
        const float* src = Xb + (size_t)(s0 + r) * 768 + d0 + cq;
        unsigned short v[16] __attribute__((aligned(16)));
#pragma unroll
        for (int j = 0; j < 16; j += 4) {
            float4 f = *(const float4*)(src + j);
            v[j] = f2bf(f.x); v[j + 1] = f2bf(f.y);
            v[j + 2] = f2bf(f.z); v[j + 3] = f2bf(f.w);
        }
        unsigned short* dst = XbfB + (size_t)(s0 + r) * 768 + d0 + cq;
        *(uint4*)dst = *(uint4*)&v[0];
        *(uint4*)(dst + 8) = *(uint4*)&v[8];
        *(uint4*)&tile[r * 72 + cq] = *(uint4*)&v[0];
        *(uint4*)&tile[r * 72 + cq + 8] = *(uint4*)&v[8];
    }
    __syncthreads();
    {
        int dr = t >> 2, sq = (t & 3) * 16;
        unsigned short v[16] __attribute__((aligned(16)));
        float part = 0.f;
#pragma unroll
        for (int j = 0; j < 16; ++j) {
            unsigned short u = tile[(sq + j) * 72 + dr];
            v[j] = u;
            part += bf2f(u);
        }
        unsigned short* dst = XtB + (size_t)(d0 + dr) * 4096 + s0 + sq;
        *(uint4*)dst = *(uint4*)&v[0];
        *(uint4*)(dst + 8) = *(uint4*)&v[8];
        part += __shfl_down(part, 1);
        part += __shfl_down(part, 2);
        if ((t & 3) == 0) atomicAdd(&csum[b * 768 + d0 + dr], part);
    }
}

// Flat grid 3488:
//   wg < 2496: triangular 64x64 Gram partial tile (tile=wg%78, zz=wg/78;
//              b=zz>>3, split=zz&7, K=512) -> packed Gp [zz*78+tile][64][64]
//   wg < 3264: aux u/d2: id=wg-2496, b=id/192, row=(id%192)*4+wave
//   wg >=3264: c2p: row=(wg-3264)*4+wave (<896): c2p[row]=Wqt+[row].bk
__global__ __launch_bounds__(256, 2) void gram2(
    const unsigned short* __restrict__ Xt, unsigned short* __restrict__ Gp,
    const float* __restrict__ Wk, const float* __restrict__ Wv,
    const unsigned short* __restrict__ Wqt,
    const float* __restrict__ bk, const float* __restrict__ bv,
    const float* __restrict__ csum,
    float* __restrict__ u, float* __restrict__ d2, float* __restrict__ c2p) {
    const long PB = 3145728;
    const unsigned wg = xcd_swizzle(blockIdx.x, gridDim.x);
    const int t = threadIdx.x;
    const int lane = t & 63;
    const int wave = t >> 6;

    if (wg >= 3264) {  // c2p
        const int row = (wg - 3264) * 4 + wave;
        float a = 0.f;
        for (int e = lane * 4; e < 768; e += 256) {
            const unsigned short* qr = Wqt + (size_t)row * 768 + e;
            float4 b4 = *(const float4*)(bk + e);
            a += bf2f(qr[0]) * b4.x + bf2f(qr[1]) * b4.y +
                 bf2f(qr[2]) * b4.z + bf2f(qr[3]) * b4.w;
        }
#pragma unroll
        for (int off = 32; off; off >>= 1) a += __shfl_down(a, off);
        if (lane == 0) c2p[row] = a;
        return;
    }
    if (wg >= 2496) {  // u + d2
        const int id = wg - 2496;
        const int b = id / 192;
        const int row = (id % 192) * 4 + wave;
        const float* s = csum + b * 768;
        float aU = 0.f, aD = 0.f;
        for (int e = lane * 4; e < 768; e += 256) {
            float4 wk4 = *(const float4*)(Wk + (size_t)row * 768 + e);
            float4 wv4 = *(const float4*)(Wv + (size_t)row * 768 + e);
            float4 s4 = *(const float4*)(s + e);
            aU += wk4.x * s4.x + wk4.y * s4.y + wk4.z * s4.z + wk4.w * s4.w;
            aD += wv4.x * s4.x + wv4.y * s4.y + wv4.z * s4.z + wv4.w * s4.w;
        }
#pragma unroll
        for (int off = 32; off; off >>= 1) {
            aU += __shfl_down(aU, off);
            aD += __shfl_down(aD, off);
        }
        if (lane == 0) {
            u[b * 768 + row] = aU;
            d2[b * 768 + row] = SCALE * (aD + 4096.f * bv[row]);
        }
        return;
    }

    __shared__ __align__(16) char ldsA[8192];
    __shared__ __align__(16) char ldsB[8192];
    const int wr = wave >> 1;
    const int wc = wave & 1;
    const int l15 = lane & 15;
    const int khi = (lane >> 4) << 4;
    f32x4 acc[2][2];
#pragma unroll
    for (int i = 0; i < 2; ++i)
#pragma unroll
        for (int j = 0; j < 2; ++j)
            acc[i][j] = (f32x4){0.f, 0.f, 0.f, 0.f};
    const int rbase = (lane >> 4) << 2;

    const int tile = wg % 78;
    const int zz = wg / 78;
    const int b = zz >> 3;
    const int koff = (zz & 7) * 512;
    int tt = tile, tby = 0;
    while (tt >= 12 - tby) { tt -= 12 - tby; ++tby; }
    const int m0 = tby * 64;
    const int n0 = (tby + tt) * 64;
    const unsigned short* Ab = Xt + (size_t)b * PB + (size_t)m0 * 4096 + koff;
    const unsigned short* Bb = Xt + (size_t)b * PB + (size_t)n0 * 4096 + koff;
    gemm_core64(Ab, Bb, 512, 4096, 4096, ldsA, ldsB, wave, lane, wr, wc, l15, khi, acc);
    unsigned short* dst = Gp + ((size_t)zz * 78 + tile) * 4096;
#pragma unroll
    for (int i = 0; i < 2; ++i)
#pragma unroll
        for (int r = 0; r < 4; ++r) {
            int rloc = wr * 32 + i * 16 + rbase + r;
#pragma unroll
            for (int j = 0; j < 2; ++j) {
                int cloc = wc * 32 + j * 16 + l15;
                dst[(size_t)rloc * 64 + cloc] = f2bf(acc[i][j][r]);
            }
        }
}

// grid (344,4):
//   x<78: reduce Gp (8 splits) -> 64x64 G tile, mirror off-diag (y=b)
//   78<=x<302: c1p[b][row] = SCALE * Wqt+[row] . u_b   (row=(x-78)*4+wave)
//   x>=302: 64x64 P+ tile, id=(x-302)*4+y in [0,168): 14x12 tiles, K=768
__global__ __launch_bounds__(256, 2) void redvec2(
    const unsigned short* __restrict__ Gp, unsigned short* __restrict__ G,
    const unsigned short* __restrict__ Wqt, const unsigned short* __restrict__ Wkt,
    unsigned short* __restrict__ Pp,
    const float* __restrict__ u, float* __restrict__ c1p) {
    const int b = blockIdx.y;
    const int t = threadIdx.x;
    const int lane = t & 63;
    const int wave = t >> 6;
    if (blockIdx.x >= 302) {  // P+ 64x64, spread over all y
        __shared__ __align__(16) char ldsA[8192];
        __shared__ __align__(16) char ldsB[8192];
        const int id = (blockIdx.x - 302) * 4 + b;
        const int m0 = (id / 12) * 64;
        const int n0 = (id % 12) * 64;
        const int wr = wave >> 1;
        const int wc = wave & 1;
        const int l15 = lane & 15;
        const int khi = (lane >> 4) << 4;
        f32x4 acc[2][2];
#pragma unroll
        for (int i = 0; i < 2; ++i)
#pragma unroll
            for (int j = 0; j < 2; ++j)
                acc[i][j] = (f32x4){0.f, 0.f, 0.f, 0.f};
        gemm_core64(Wqt + (size_t)m0 * 768, Wkt + (size_t)n0 * 768,
                    768, 768, 768, ldsA, ldsB, wave, lane, wr, wc, l15, khi, acc);
        const int rbase = (lane >> 4) << 2;
#pragma unroll
        for (int i = 0; i < 2; ++i)
#pragma unroll
            for (int r = 0; r < 4; ++r) {
                int row = m0 + wr * 32 + i * 16 + rbase + r;
#pragma unroll
                for (int j = 0; j < 2; ++j) {
                    int col = n0 + wc * 32 + j * 16 + l15;
                    Pp[(size_t)row * 768 + col] = f2bf(acc[i][j][r]);
                }
            }
        return;
    }
    if (blockIdx.x >= 78) {  // c1p
        const int row = (blockIdx.x - 78) * 4 + wave;
        const float* ub = u + b * 768;
        float a = 0.f;
        for (int e = lane * 4; e < 768; e += 256) {
            const unsigned short* qr = Wqt + (size_t)row * 768 + e;
            float4 u4 = *(const float4*)(ub + e);
            a += bf2f(qr[0]) * u4.x + bf2f(qr[1]) * u4.y +
                 bf2f(qr[2]) * u4.z + bf2f(qr[3]) * u4.w;
        }
#pragma unroll
        for (int off = 32; off; off >>= 1) a += __shfl_down(a, off);
        if (lane == 0) c1p[b * 896 + row] = SCALE * a;
        return;
    }
    // reduce one 64x64 tile over 8 splits; mirror off-diagonal
    __shared__ unsigned short tl[64 * 72];
    const int tile = blockIdx.x;
    int tt = tile, tby = 0;
    while (tt >= 12 - tby) { tt -= 12 - tby; ++tby; }
    const int tbx = tby + tt;
    const int r = t >> 2;
    const int c0 = (t & 3) * 16;
    float acc[16];
#pragma unroll
    for (int j = 0; j < 16; ++j) acc[j] = 0.f;
    for (int sp = 0; sp < 8; ++sp) {
        const unsigned short* base =
            Gp + ((size_t)(b * 8 + sp) * 78 + tile) * 4096 + (size_t)r * 64 + c0;
#pragma unroll
        for (int j = 0; j < 2; ++j) {
            uint4 qv = *(const uint4*)(base + j * 8);
            const unsigned short* pv = (const unsigned short*)&qv;
#pragma unroll
            for (int k = 0; k < 8; ++k) acc[j * 8 + k] += bf2f(pv[k]);
        }
    }
    unsigned short v[16] __attribute__((aligned(16)));
#pragma unroll
    for (int j = 0; j < 16; ++j) v[j] = f2bf(acc[j]);
    unsigned short* dst = G + (size_t)b * 589824 +
                          (size_t)(tby * 64 + r) * 768 + tbx * 64 + c0;
    *(uint4*)dst = *(uint4*)&v[0];
    *(uint4*)(dst + 8) = *(uint4*)&v[8];
    if (tby != tbx) {
        *(uint4*)&tl[r * 72 + c0] = *(uint4*)&v[0];
        *(uint4*)&tl[r * 72 + c0 + 8] = *(uint4*)&v[8];
        __syncthreads();
        int dr = t >> 2, sq = (t & 3) * 16;
        unsigned short w[16] __attribute__((aligned(16)));
#pragma unroll
        for (int j = 0; j < 16; ++j) w[j] = tl[(sq + j) * 72 + dr];
        unsigned short* dm = G + (size_t)b * 589824 +
                             (size_t)(tbx * 64 + dr) * 768 + tby * 64 + sq;
        *(uint4*)dm = *(uint4*)&w[0];
        *(uint4*)(dm + 8) = *(uint4*)&w[8];
    }
}

extern "C" void kernel_launch(void* const* d_in, const int* in_sizes, int n_in,
                              void* d_out, int out_size, void* d_ws, size_t ws_size,
                              hipStream_t stream) {
    const float* x  = (const float*)d_in[0];
    const float* Wq = (const float*)d_in[1];
    const float* bq = (const float*)d_in[2];
    const float* Wk = (const float*)d_in[3];
    const float* bk = (const float*)d_in[4];
    const float* Wv = (const float*)d_in[5];
    const float* bv = (const float*)d_in[6];
    float* out = (float*)d_out;

    const long PB = 3145728;   // 4096*768
    const long DD = 589824;    // 768*768
    const long DA = 688128;    // 896*768

    unsigned short* ws  = (unsigned short*)d_ws;
    unsigned short* Xbf = ws;                       // 12582912
    unsigned short* Xt  = ws + 12582912;            // 12582912
    unsigned short* Pp  = ws + 25165824;            // 688128
    unsigned short* G   = ws + 25853952;            // 2359296
    unsigned short* Wqt = ws + 28213248;            // 688128 ([896][768])
    unsigned short* Wkt = ws + 28901376;            // 589824
    unsigned short* Wvb = ws + 29491200;            // 589824
    unsigned short* Gp  = ws + 30081024;            // 10223616 used (78*32 64x64)
    unsigned short* C1p = Gp;                       // overlay after redvec2
    unsigned short* At  = Gp + 2752512;             // 2752512
    float* fbase = (float*)(ws + 41091072);
    float* csum = fbase;                            // 3072
    float* u    = fbase + 3072;                     // 3072
    float* c1p  = fbase + 6144;                     // 3584
    float* c2p  = fbase + 9728;                     // 896
    float* d2   = fbase + 10624;                    // 3072

    dim3 blk(256, 1, 1);

    prep_w<<<dim3(12, 12, 5), blk, 0, stream>>>(Wq, Wk, Wv, bq, Wqt, Wkt, Wvb, csum);
    prep_x<<<dim3(64, 12, 4), blk, 0, stream>>>(x, Xbf, Xt, csum);

    // Gram tri 64x64 split-K partials (split=8, K=512) + u/d2 + c2p aux
    gram2<<<dim3(3488, 1, 1), blk, 0, stream>>>(Xt, Gp, Wk, Wv, Wqt, bk, bv,
                                                csum, u, d2, c2p);

    // reduce G (78 tiles) + c1p + P+ (64x64, 168 tiles over 4 y)
    redvec2<<<dim3(344, 4), blk, 0, stream>>>(Gp, G, Wqt, Wkt, Pp, u, c1p);

    // C1+ = P+ ⊠ G   [4][896][768]   (64x64 tiles: 672 wgs)
    gemm64_bf16<BIAS_NONE, true><<<dim3(12, 14, 4), blk, 0, stream>>>(
        Pp, G, C1p, nullptr, nullptr, nullptr, nullptr, nullptr,
        768, 768, 768, 768, 0, DD, DA, 1.0f, 0);

    // At = Wvb ⊠ C1+ (+rank2)   [4][768][896]   (64x64 tiles: 672 wgs)
    gemm64_bf16<BIAS_RANK2, true><<<dim3(14, 12, 4), blk, 0, stream>>>(
        Wvb, C1p, At, bv, c1p, d2, c2p, nullptr,
        768, 768, 768, 896, 0, DA, DA, SCALE, 896);

    // out = Xbf ⊠ At (K=768) + r epilogue (At col 768)  fp32 (64x64: 3072 wgs)
    gemm64_bf16<BIAS_RCOL, false><<<dim3(12, 64, 4), blk, 0, stream>>>(
        Xbf, At, out, nullptr, nullptr, nullptr, nullptr, At,
        768, 768, 896, 768, PB, DA, PB, 1.0f, 0);
}

// Round 10
// 114.927 us; speedup vs baseline: 2.2794x; 1.0251x over previous
//
#include <hip/hip_runtime.h>

// out = X A + 1 r^T,  A = scale Wq^T (K^T V).  With G = X^T X, s = X^T 1:
//   K^T V = Wk G Wv^T + (Wk s) bv^T + bk (Wv s)^T + S bk bv^T
// Augment Wq+ = [Wq^T; bq^T; 0pad] (896x768) so r = col 768 of At.
//   prep_w: Wqt+/Wkt/Wvb (bf16) + zero csum
//   prep_x: Xbf [4][4096][768], Xt [4][768][4096], csum atomics
//   gram2:  2496 tri 64x64 split-K Gram partial tiles (K=512, split=8)
//           + u/d2/c2p aux
//   redvec2: reduce Gp (8 splits, 78 64x64 tiles) -> G (mirror); c1p;
//            168 64x64 P+ tiles spread over all 4 y-slices
//   C1+ = P+ ⊠ G            [4][896][768]   (gemm64: 672 wgs)
//   At  = Wvb ⊠ C1+ (+rank2)[4][768][896]   (gemm64: 672 wgs)
//   out = Xbf ⊠ At (K=768) + At[col][768] epilogue  fp32 (gemm128: 768 wgs)
// GEMM: serial LDS loop (m97 structure), global_load_lds(16B) pre-swizzled
// source, XOR (r&7)<<4 reads, XCD-chunked bijective blockIdx swizzle.
// Tile-size model (R4..R9): serial-core dispatches are latency-bound until
// ~8 blocks/CU, then staging-BW-bound (L2/L3 ~16 TB/s). 64-tile doubles
// panel traffic vs 128 — use 64 only where starting occupancy <3 blocks/CU
// (gram2 R8 -15us, C1/At R6 -7us); gemm3 at 768 wgs keeps 128 (R9: 64-tile
// there was ~+2us net).
// (R1: dbuf+counted-vmcnt regressed; R2: P+ move regressed; R3: fused
//  reduce 6x regression; R4/R5: split 4/16 regressed -> split=8 optimal.
//  R7: FAILED on gram2 grid arithmetic — aux budget must cover all rows.)

typedef __attribute__((ext_vector_type(8))) __bf16 bf16x8;
typedef __attribute__((ext_vector_type(4))) float f32x4;

#define SCALE 0.03608439182435161f

union FragU {
    uint4 q;
    bf16x8 f;
    unsigned short s[8];
};

__device__ __forceinline__ unsigned short f2bf(float x) {
    unsigned int u = __builtin_bit_cast(unsigned int, x);
    u = (u + 0x7fffu + ((u >> 16) & 1u)) >> 16;
    return (unsigned short)u;
}
__device__ __forceinline__ float bf2f(unsigned short u) {
    unsigned int v = ((unsigned int)u) << 16;
    return __builtin_bit_cast(float, v);
}

__device__ __forceinline__ unsigned xcd_swizzle(unsigned lin, unsigned nwg) {
    const unsigned q = nwg >> 3, rr8 = nwg & 7;
    const unsigned xcd = lin & 7, o = lin >> 3;
    return (xcd < rr8 ? xcd * (q + 1) : rr8 * (q + 1) + (xcd - rr8) * q) + o;
}

// 16KB staging for 128-row panel: wave w covers rows [w*32, w*32+32).
__device__ __forceinline__ void stage_gl(const unsigned short* __restrict__ srcRowBase,
                                         int ldElems, char* lds, int wave, int lane) {
#pragma unroll
    for (int p = 0; p < 4; ++p) {
        int slotbase = (wave * 4 + p) * 1024;
        int slot = slotbase + lane * 16;
        int r = slot >> 7;
        int cb = (slot & 127) ^ ((r & 7) << 4);
        const char* g = (const char*)(srcRowBase + (size_t)r * ldElems) + cb;
        __builtin_amdgcn_global_load_lds(
            (const __attribute__((address_space(1))) unsigned int*)g,
            (__attribute__((address_space(3))) unsigned int*)(lds + slotbase),
            16, 0, 0);
    }
}

// 8KB half-size staging: half in {0,1} covers rows [half*32, half*32+32).
__device__ __forceinline__ void stage_gl64(const unsigned short* __restrict__ srcRowBase,
                                           int ldElems, char* lds, int half, int lane) {
#pragma unroll
    for (int p = 0; p < 4; ++p) {
        int slotbase = (half * 4 + p) * 1024;
        int slot = slotbase + lane * 16;
        int r = slot >> 7;
        int cb = (slot & 127) ^ ((r & 7) << 4);
        const char* g = (const char*)(srcRowBase + (size_t)r * ldElems) + cb;
        __builtin_amdgcn_global_load_lds(
            (const __attribute__((address_space(1))) unsigned int*)g,
            (__attribute__((address_space(3))) unsigned int*)(lds + slotbase),
            16, 0, 0);
    }
}

__device__ __forceinline__ bf16x8 load_frag(const char* lds, int row, int kbyte) {
    int a = row * 128 + kbyte;
    a ^= (row & 7) << 4;
    FragU u;
    u.q = *(const uint4*)(lds + a);
    return u.f;
}

// 128x128 serial core (m97 structure): 4 waves as 2x2 of 64x64.
__device__ __forceinline__ void gemm_core(const unsigned short* __restrict__ Ab,
                                          const unsigned short* __restrict__ Bb,
                                          int K, int lda, int ldb,
                                          char* ldsA, char* ldsB,
                                          int wave, int lane, int wm, int wn,
                                          int l15, int khi, f32x4 (&acc)[4][4]) {
    for (int k0 = 0; k0 < K; k0 += 64) {
        stage_gl(Ab + k0, lda, ldsA, wave, lane);
        stage_gl(Bb + k0, ldb, ldsB, wave, lane);
        __syncthreads();
#pragma unroll
        for (int kk = 0; kk < 2; ++kk) {
            const int kbyte = kk * 64 + khi;
            bf16x8 af[4], bfr[4];
#pragma unroll
            for (int i = 0; i < 4; ++i)
                af[i] = load_frag(ldsA, wm * 64 + i * 16 + l15, kbyte);
#pragma unroll
            for (int j = 0; j < 4; ++j)
                bfr[j] = load_frag(ldsB, wn * 64 + j * 16 + l15, kbyte);
#pragma unroll
            for (int i = 0; i < 4; ++i)
#pragma unroll
                for (int j = 0; j < 4; ++j)
                    acc[i][j] = __builtin_amdgcn_mfma_f32_16x16x32_bf16(
                        af[i], bfr[j], acc[i][j], 0, 0, 0);
        }
        __syncthreads();
    }
}

// 64x64 serial core: 4 waves as 2x2 of 32x32; waves 0-1 stage A, 2-3 stage B.
__device__ __forceinline__ void gemm_core64(const unsigned short* __restrict__ Ab,
                                            const unsigned short* __restrict__ Bb,
                                            int K, int lda, int ldb,
                                            char* ldsA, char* ldsB,
                                            int wave, int lane, int wr, int wc,
                                            int l15, int khi, f32x4 (&acc)[2][2]) {
    for (int k0 = 0; k0 < K; k0 += 64) {
        if (wave < 2)
            stage_gl64(Ab + k0, lda, ldsA, wave, lane);
        else
            stage_gl64(Bb + k0, ldb, ldsB, wave - 2, lane);
        __syncthreads();
#pragma unroll
        for (int kk = 0; kk < 2; ++kk) {
            const int kbyte = kk * 64 + khi;
            bf16x8 af[2], bfr[2];
#pragma unroll
            for (int i = 0; i < 2; ++i)
                af[i] = load_frag(ldsA, wr * 32 + i * 16 + l15, kbyte);
#pragma unroll
            for (int j = 0; j < 2; ++j)
                bfr[j] = load_frag(ldsB, wc * 32 + j * 16 + l15, kbyte);
#pragma unroll
            for (int i = 0; i < 2; ++i)
#pragma unroll
                for (int j = 0; j < 2; ++j)
                    acc[i][j] = __builtin_amdgcn_mfma_f32_16x16x32_bf16(
                        af[i], bfr[j], acc[i][j], 0, 0, 0);
        }
        __syncthreads();
    }
}

enum { BIAS_NONE = 0, BIAS_RANK2 = 2, BIAS_RCOL = 3 };

// 128x128-tile GEMM (high-workgroup dispatches: gemm3).
template <int BIASM, bool OUT_BF16>
__global__ __launch_bounds__(256, 2) void gemm_bf16(
    const unsigned short* __restrict__ A, const unsigned short* __restrict__ B,
    void* __restrict__ C,
    const float* __restrict__ p0, const float* __restrict__ p1,
    const float* __restrict__ p2, const float* __restrict__ p3,
    const unsigned short* __restrict__ rsrc,
    int K, int lda, int ldb, int ldc, long bsA, long bsB, long bsC,
    float scale, int vld1) {
    __shared__ __align__(16) char ldsA[16384];
    __shared__ __align__(16) char ldsB[16384];

    const unsigned gx = gridDim.x, gy = gridDim.y;
    const unsigned lin = blockIdx.x + gx * (blockIdx.y + gy * blockIdx.z);
    const unsigned wg = xcd_swizzle(lin, gx * gy * gridDim.z);
    const int bx = wg % gx;
    const int by = (wg / gx) % gy;
    const int z = wg / (gx * gy);

    const int m0 = by * 128;
    const int n0 = bx * 128;
    const unsigned short* Ab = A + (size_t)z * bsA + (size_t)m0 * lda;
    const unsigned short* Bb = B + (size_t)z * bsB + (size_t)n0 * ldb;

    const int lane = threadIdx.x & 63;
    const int wave = threadIdx.x >> 6;
    const int wm = wave >> 1;
    const int wn = wave & 1;
    const int l15 = lane & 15;
    const int khi = (lane >> 4) << 4;

    f32x4 acc[4][4];
#pragma unroll
    for (int i = 0; i < 4; ++i)
#pragma unroll
        for (int j = 0; j < 4; ++j)
            acc[i][j] = (f32x4){0.f, 0.f, 0.f, 0.f};

    gemm_core(Ab, Bb, K, lda, ldb, ldsA, ldsB, wave, lane, wm, wn, l15, khi, acc);

    const int rbase = (lane >> 4) << 2;
#pragma unroll
    for (int i = 0; i < 4; ++i) {
#pragma unroll
        for (int r = 0; r < 4; ++r) {
            int row = m0 + wm * 64 + i * 16 + rbase + r;
            float rA = 0.f, rB = 0.f;
            if (BIASM == BIAS_RANK2) {
                rA = p0[row];
                rB = p2[z * 768 + row];
            }
#pragma unroll
            for (int j = 0; j < 4; ++j) {
                int col = n0 + wn * 64 + j * 16 + l15;
                float v = acc[i][j][r] * scale;
                if (BIASM == BIAS_RANK2) v += rA * p1[z * vld1 + col] + rB * p3[col];
                if (BIASM == BIAS_RCOL)
                    v += bf2f(rsrc[(size_t)z * 688128 + (size_t)col * 896 + 768]);
                size_t off = (size_t)z * bsC + (size_t)row * ldc + col;
                if (OUT_BF16)
                    ((unsigned short*)C)[off] = f2bf(v);
                else
                    ((float*)C)[off] = v;
            }
        }
    }
}

// 64x64-tile GEMM (low-workgroup mid-chain dispatches).
template <int BIASM, bool OUT_BF16>
__global__ __launch_bounds__(256, 2) void gemm64_bf16(
    const unsigned short* __restrict__ A, const unsigned short* __restrict__ B,
    void* __restrict__ C,
    const float* __restrict__ p0, const float* __restrict__ p1,
    const float* __restrict__ p2, const float* __restrict__ p3,
    const unsigned short* __restrict__ rsrc,
    int K, int lda, int ldb, int ldc, long bsA, long bsB, long bsC,
    float scale, int vld1) {
    __shared__ __align__(16) char ldsA[8192];
    __shared__ __align__(16) char ldsB[8192];

    const unsigned gx = gridDim.x, gy = gridDim.y;
    const unsigned lin = blockIdx.x + gx * (blockIdx.y + gy * blockIdx.z);
    const unsigned wg = xcd_swizzle(lin, gx * gy * gridDim.z);
    const int bx = wg % gx;
    const int by = (wg / gx) % gy;
    const int z = wg / (gx * gy);

    const int m0 = by * 64;
    const int n0 = bx * 64;
    const unsigned short* Ab = A + (size_t)z * bsA + (size_t)m0 * lda;
    const unsigned short* Bb = B + (size_t)z * bsB + (size_t)n0 * ldb;

    const int lane = threadIdx.x & 63;
    const int wave = threadIdx.x >> 6;
    const int wr = wave >> 1;
    const int wc = wave & 1;
    const int l15 = lane & 15;
    const int khi = (lane >> 4) << 4;

    f32x4 acc[2][2];
#pragma unroll
    for (int i = 0; i < 2; ++i)
#pragma unroll
        for (int j = 0; j < 2; ++j)
            acc[i][j] = (f32x4){0.f, 0.f, 0.f, 0.f};

    gemm_core64(Ab, Bb, K, lda, ldb, ldsA, ldsB, wave, lane, wr, wc, l15, khi, acc);

    const int rbase = (lane >> 4) << 2;
#pragma unroll
    for (int i = 0; i < 2; ++i) {
#pragma unroll
        for (int r = 0; r < 4; ++r) {
            int row = m0 + wr * 32 + i * 16 + rbase + r;
            float rA = 0.f, rB = 0.f;
            if (BIASM == BIAS_RANK2) {
                rA = p0[row];
                rB = p2[z * 768 + row];
            }
#pragma unroll
            for (int j = 0; j < 2; ++j) {
                int col = n0 + wc * 32 + j * 16 + l15;
                float v = acc[i][j][r] * scale;
                if (BIASM == BIAS_RANK2) v += rA * p1[z * vld1 + col] + rB * p3[col];
                if (BIASM == BIAS_RCOL)
                    v += bf2f(rsrc[(size_t)z * 688128 + (size_t)col * 896 + 768]);
                size_t off = (size_t)z * bsC + (size_t)row * ldc + col;
                if (OUT_BF16)
                    ((unsigned short*)C)[off] = f2bf(v);
                else
                    ((float*)C)[off] = v;
            }
        }
    }
}

// z=0: Wqt+ rows 0..767 = Wq^T; z=1: Wkt = Wk^T; z=2: Wvb = bf16(Wv);
// z=3: Wqt+ row 768 = bq, rows 769..895 = 0; z=4: zero csum.
__global__ __launch_bounds__(256) void prep_w(const float* __restrict__ Wq,
                                              const float* __restrict__ Wk,
                                              const float* __restrict__ Wv,
                                              const float* __restrict__ bq,
                                              unsigned short* __restrict__ Wqt,
                                              unsigned short* __restrict__ Wkt,
                                              unsigned short* __restrict__ Wvb,
                                              float* __restrict__ csum) {
    const int mode = blockIdx.z;
    const int t = threadIdx.x;
    if (mode == 4) {
        if (blockIdx.x == 0 && blockIdx.y == 0) {
            float4 z4 = {0.f, 0.f, 0.f, 0.f};
            for (int i = t * 4; i < 3072; i += 1024) *(float4*)(csum + i) = z4;
        }
        return;
    }
    if (mode == 3) {
        if (blockIdx.y) return;
        int rr = 768 + (t >> 1);
        int c0 = blockIdx.x * 64 + (t & 1) * 32;
        unsigned short v[32] __attribute__((aligned(16)));
        if (rr == 768) {
#pragma unroll
            for (int j = 0; j < 32; ++j) v[j] = f2bf(bq[c0 + j]);
        } else {
#pragma unroll
            for (int j = 0; j < 32; ++j) v[j] = 0;
        }
        unsigned short* dst = Wqt + (size_t)rr * 768 + c0;
#pragma unroll
        for (int j = 0; j < 4; ++j) *(uint4*)(dst + j * 8) = *(uint4*)&v[j * 8];
        return;
    }
    __shared__ unsigned short tile[64 * 72];
    const float* src = mode == 0 ? Wq : (mode == 1 ? Wk : Wv);
    const int r0 = blockIdx.x * 64;
    const int c0 = blockIdx.y * 64;
    int r = t >> 2, cq = (t & 3) * 16;
    unsigned short v[16] __attribute__((aligned(16)));
    const float* s = src + (size_t)(r0 + r) * 768 + c0 + cq;
#pragma unroll
    for (int j = 0; j < 16; j += 4) {
        float4 f = *(const float4*)(s + j);
        v[j] = f2bf(f.x); v[j + 1] = f2bf(f.y);
        v[j + 2] = f2bf(f.z); v[j + 3] = f2bf(f.w);
    }
    if (mode == 2) {
        unsigned short* dst = Wvb + (size_t)(r0 + r) * 768 + c0 + cq;
        *(uint4*)dst = *(uint4*)&v[0];
        *(uint4*)(dst + 8) = *(uint4*)&v[8];
        return;
    }
    *(uint4*)&tile[r * 72 + cq] = *(uint4*)&v[0];
    *(uint4*)&tile[r * 72 + cq + 8] = *(uint4*)&v[8];
    __syncthreads();
    int dr = t >> 2, sq = (t & 3) * 16;
    unsigned short w[16] __attribute__((aligned(16)));
#pragma unroll
    for (int j = 0; j < 16; ++j) w[j] = tile[(sq + j) * 72 + dr];
    unsigned short* dst = (mode == 0 ? Wqt : Wkt) + (size_t)(c0 + dr) * 768 + r0 + sq;
    *(uint4*)dst = *(uint4*)&w[0];
    *(uint4*)(dst + 8) = *(uint4*)&w[8];
}

// Xbf [4][4096][768], Xt [4][768][4096], csum atomics.
__global__ __launch_bounds__(256) void prep_x(const float* __restrict__ X,
                                              unsigned short* __restrict__ Xbf,
                                              unsigned short* __restrict__ Xt,
                                              float* __restrict__ csum) {
    const int b = blockIdx.z;
    const int s0 = blockIdx.x * 64;
    const int t = threadIdx.x;
    __shared__ unsigned short tile[64 * 72];
    const int d0 = blockIdx.y * 64;
    const float* Xb = X + (size_t)b * 4096 * 768;
    unsigned short* XbfB = Xbf + (size_t)b * 4096 * 768;
    unsigned short* XtB = Xt + (size_t)b * 768 * 4096;
    {
        int r = t >> 2, cq = (t & 3) * 16;
        const float* src = Xb + (size_t)(s0 + r) * 768 + d0 + cq;
        unsigned short v[16] __attribute__((aligned(16)));
#pragma unroll
        for (int j = 0; j < 16; j += 4) {
            float4 f = *(const float4*)(src + j);
            v[j] = f2bf(f.x); v[j + 1] = f2bf(f.y);
            v[j + 2] = f2bf(f.z); v[j + 3] = f2bf(f.w);
        }
        unsigned short* dst = XbfB + (size_t)(s0 + r) * 768 + d0 + cq;
        *(uint4*)dst = *(uint4*)&v[0];
        *(uint4*)(dst + 8) = *(uint4*)&v[8];
        *(uint4*)&tile[r * 72 + cq] = *(uint4*)&v[0];
        *(uint4*)&tile[r * 72 + cq + 8] = *(uint4*)&v[8];
    }
    __syncthreads();
    {
        int dr = t >> 2, sq = (t & 3) * 16;
        unsigned short v[16] __attribute__((aligned(16)));
        float part = 0.f;
#pragma unroll
        for (int j = 0; j < 16; ++j) {
            unsigned short u = tile[(sq + j) * 72 + dr];
            v[j] = u;
            part += bf2f(u);
        }
        unsigned short* dst = XtB + (size_t)(d0 + dr) * 4096 + s0 + sq;
        *(uint4*)dst = *(uint4*)&v[0];
        *(uint4*)(dst + 8) = *(uint4*)&v[8];
        part += __shfl_down(part, 1);
        part += __shfl_down(part, 2);
        if ((t & 3) == 0) atomicAdd(&csum[b * 768 + d0 + dr], part);
    }
}

// Flat grid 3488:
//   wg < 2496: triangular 64x64 Gram partial tile (tile=wg%78, zz=wg/78;
//              b=zz>>3, split=zz&7, K=512) -> packed Gp [zz*78+tile][64][64]
//   wg < 3264: aux u/d2: id=wg-2496, b=id/192, row=(id%192)*4+wave
//   wg >=3264: c2p: row=(wg-3264)*4+wave (<896): c2p[row]=Wqt+[row].bk
__global__ __launch_bounds__(256, 2) void gram2(
    const unsigned short* __restrict__ Xt, unsigned short* __restrict__ Gp,
    const float* __restrict__ Wk, const float* __restrict__ Wv,
    const unsigned short* __restrict__ Wqt,
    const float* __restrict__ bk, const float* __restrict__ bv,
    const float* __restrict__ csum,
    float* __restrict__ u, float* __restrict__ d2, float* __restrict__ c2p) {
    const long PB = 3145728;
    const unsigned wg = xcd_swizzle(blockIdx.x, gridDim.x);
    const int t = threadIdx.x;
    const int lane = t & 63;
    const int wave = t >> 6;

    if (wg >= 3264) {  // c2p
        const int row = (wg - 3264) * 4 + wave;
        float a = 0.f;
        for (int e = lane * 4; e < 768; e += 256) {
            const unsigned short* qr = Wqt + (size_t)row * 768 + e;
            float4 b4 = *(const float4*)(bk + e);
            a += bf2f(qr[0]) * b4.x + bf2f(qr[1]) * b4.y +
                 bf2f(qr[2]) * b4.z + bf2f(qr[3]) * b4.w;
        }
#pragma unroll
        for (int off = 32; off; off >>= 1) a += __shfl_down(a, off);
        if (lane == 0) c2p[row] = a;
        return;
    }
    if (wg >= 2496) {  // u + d2
        const int id = wg - 2496;
        const int b = id / 192;
        const int row = (id % 192) * 4 + wave;
        const float* s = csum + b * 768;
        float aU = 0.f, aD = 0.f;
        for (int e = lane * 4; e < 768; e += 256) {
            float4 wk4 = *(const float4*)(Wk + (size_t)row * 768 + e);
            float4 wv4 = *(const float4*)(Wv + (size_t)row * 768 + e);
            float4 s4 = *(const float4*)(s + e);
            aU += wk4.x * s4.x + wk4.y * s4.y + wk4.z * s4.z + wk4.w * s4.w;
            aD += wv4.x * s4.x + wv4.y * s4.y + wv4.z * s4.z + wv4.w * s4.w;
        }
#pragma unroll
        for (int off = 32; off; off >>= 1) {
            aU += __shfl_down(aU, off);
            aD += __shfl_down(aD, off);
        }
        if (lane == 0) {
            u[b * 768 + row] = aU;
            d2[b * 768 + row] = SCALE * (aD + 4096.f * bv[row]);
        }
        return;
    }

    __shared__ __align__(16) char ldsA[8192];
    __shared__ __align__(16) char ldsB[8192];
    const int wr = wave >> 1;
    const int wc = wave & 1;
    const int l15 = lane & 15;
    const int khi = (lane >> 4) << 4;
    f32x4 acc[2][2];
#pragma unroll
    for (int i = 0; i < 2; ++i)
#pragma unroll
        for (int j = 0; j < 2; ++j)
            acc[i][j] = (f32x4){0.f, 0.f, 0.f, 0.f};
    const int rbase = (lane >> 4) << 2;

    const int tile = wg % 78;
    const int zz = wg / 78;
    const int b = zz >> 3;
    const int koff = (zz & 7) * 512;
    int tt = tile, tby = 0;
    while (tt >= 12 - tby) { tt -= 12 - tby; ++tby; }
    const int m0 = tby * 64;
    const int n0 = (tby + tt) * 64;
    const unsigned short* Ab = Xt + (size_t)b * PB + (size_t)m0 * 4096 + koff;
    const unsigned short* Bb = Xt + (size_t)b * PB + (size_t)n0 * 4096 + koff;
    gemm_core64(Ab, Bb, 512, 4096, 4096, ldsA, ldsB, wave, lane, wr, wc, l15, khi, acc);
    unsigned short* dst = Gp + ((size_t)zz * 78 + tile) * 4096;
#pragma unroll
    for (int i = 0; i < 2; ++i)
#pragma unroll
        for (int r = 0; r < 4; ++r) {
            int rloc = wr * 32 + i * 16 + rbase + r;
#pragma unroll
            for (int j = 0; j < 2; ++j) {
                int cloc = wc * 32 + j * 16 + l15;
                dst[(size_t)rloc * 64 + cloc] = f2bf(acc[i][j][r]);
            }
        }
}

// grid (344,4):
//   x<78: reduce Gp (8 splits) -> 64x64 G tile, mirror off-diag (y=b)
//   78<=x<302: c1p[b][row] = SCALE * Wqt+[row] . u_b   (row=(x-78)*4+wave)
//   x>=302: 64x64 P+ tile, id=(x-302)*4+y in [0,168): 14x12 tiles, K=768
__global__ __launch_bounds__(256, 2) void redvec2(
    const unsigned short* __restrict__ Gp, unsigned short* __restrict__ G,
    const unsigned short* __restrict__ Wqt, const unsigned short* __restrict__ Wkt,
    unsigned short* __restrict__ Pp,
    const float* __restrict__ u, float* __restrict__ c1p) {
    const int b = blockIdx.y;
    const int t = threadIdx.x;
    const int lane = t & 63;
    const int wave = t >> 6;
    if (blockIdx.x >= 302) {  // P+ 64x64, spread over all y
        __shared__ __align__(16) char ldsA[8192];
        __shared__ __align__(16) char ldsB[8192];
        const int id = (blockIdx.x - 302) * 4 + b;
        const int m0 = (id / 12) * 64;
        const int n0 = (id % 12) * 64;
        const int wr = wave >> 1;
        const int wc = wave & 1;
        const int l15 = lane & 15;
        const int khi = (lane >> 4) << 4;
        f32x4 acc[2][2];
#pragma unroll
        for (int i = 0; i < 2; ++i)
#pragma unroll
            for (int j = 0; j < 2; ++j)
                acc[i][j] = (f32x4){0.f, 0.f, 0.f, 0.f};
        gemm_core64(Wqt + (size_t)m0 * 768, Wkt + (size_t)n0 * 768,
                    768, 768, 768, ldsA, ldsB, wave, lane, wr, wc, l15, khi, acc);
        const int rbase = (lane >> 4) << 2;
#pragma unroll
        for (int i = 0; i < 2; ++i)
#pragma unroll
            for (int r = 0; r < 4; ++r) {
                int row = m0 + wr * 32 + i * 16 + rbase + r;
#pragma unroll
                for (int j = 0; j < 2; ++j) {
                    int col = n0 + wc * 32 + j * 16 + l15;
                    Pp[(size_t)row * 768 + col] = f2bf(acc[i][j][r]);
                }
            }
        return;
    }
    if (blockIdx.x >= 78) {  // c1p
        const int row = (blockIdx.x - 78) * 4 + wave;
        const float* ub = u + b * 768;
        float a = 0.f;
        for (int e = lane * 4; e < 768; e += 256) {
            const unsigned short* qr = Wqt + (size_t)row * 768 + e;
            float4 u4 = *(const float4*)(ub + e);
            a += bf2f(qr[0]) * u4.x + bf2f(qr[1]) * u4.y +
                 bf2f(qr[2]) * u4.z + bf2f(qr[3]) * u4.w;
        }
#pragma unroll
        for (int off = 32; off; off >>= 1) a += __shfl_down(a, off);
        if (lane == 0) c1p[b * 896 + row] = SCALE * a;
        return;
    }
    // reduce one 64x64 tile over 8 splits; mirror off-diagonal
    __shared__ unsigned short tl[64 * 72];
    const int tile = blockIdx.x;
    int tt = tile, tby = 0;
    while (tt >= 12 - tby) { tt -= 12 - tby; ++tby; }
    const int tbx = tby + tt;
    const int r = t >> 2;
    const int c0 = (t & 3) * 16;
    float acc[16];
#pragma unroll
    for (int j = 0; j < 16; ++j) acc[j] = 0.f;
    for (int sp = 0; sp < 8; ++sp) {
        const unsigned short* base =
            Gp + ((size_t)(b * 8 + sp) * 78 + tile) * 4096 + (size_t)r * 64 + c0;
#pragma unroll
        for (int j = 0; j < 2; ++j) {
            uint4 qv = *(const uint4*)(base + j * 8);
            const unsigned short* pv = (const unsigned short*)&qv;
#pragma unroll
            for (int k = 0; k < 8; ++k) acc[j * 8 + k] += bf2f(pv[k]);
        }
    }
    unsigned short v[16] __attribute__((aligned(16)));
#pragma unroll
    for (int j = 0; j < 16; ++j) v[j] = f2bf(acc[j]);
    unsigned short* dst = G + (size_t)b * 589824 +
                          (size_t)(tby * 64 + r) * 768 + tbx * 64 + c0;
    *(uint4*)dst = *(uint4*)&v[0];
    *(uint4*)(dst + 8) = *(uint4*)&v[8];
    if (tby != tbx) {
        *(uint4*)&tl[r * 72 + c0] = *(uint4*)&v[0];
        *(uint4*)&tl[r * 72 + c0 + 8] = *(uint4*)&v[8];
        __syncthreads();
        int dr = t >> 2, sq = (t & 3) * 16;
        unsigned short w[16] __attribute__((aligned(16)));
#pragma unroll
        for (int j = 0; j < 16; ++j) w[j] = tl[(sq + j) * 72 + dr];
        unsigned short* dm = G + (size_t)b * 589824 +
                             (size_t)(tbx * 64 + dr) * 768 + tby * 64 + sq;
        *(uint4*)dm = *(uint4*)&w[0];
        *(uint4*)(dm + 8) = *(uint4*)&w[8];
    }
}

extern "C" void kernel_launch(void* const* d_in, const int* in_sizes, int n_in,
                              void* d_out, int out_size, void* d_ws, size_t ws_size,
                              hipStream_t stream) {
    const float* x  = (const float*)d_in[0];
    const float* Wq = (const float*)d_in[1];
    const float* bq = (const float*)d_in[2];
    const float* Wk = (const float*)d_in[3];
    const float* bk = (const float*)d_in[4];
    const float* Wv = (const float*)d_in[5];
    const float* bv = (const float*)d_in[6];
    float* out = (float*)d_out;

    const long PB = 3145728;   // 4096*768
    const long DD = 589824;    // 768*768
    const long DA = 688128;    // 896*768

    unsigned short* ws  = (unsigned short*)d_ws;
    unsigned short* Xbf = ws;                       // 12582912
    unsigned short* Xt  = ws + 12582912;            // 12582912
    unsigned short* Pp  = ws + 25165824;            // 688128
    unsigned short* G   = ws + 25853952;            // 2359296
    unsigned short* Wqt = ws + 28213248;            // 688128 ([896][768])
    unsigned short* Wkt = ws + 28901376;            // 589824
    unsigned short* Wvb = ws + 29491200;            // 589824
    unsigned short* Gp  = ws + 30081024;            // 10223616 used (78*32 64x64)
    unsigned short* C1p = Gp;                       // overlay after redvec2
    unsigned short* At  = Gp + 2752512;             // 2752512
    float* fbase = (float*)(ws + 41091072);
    float* csum = fbase;                            // 3072
    float* u    = fbase + 3072;                     // 3072
    float* c1p  = fbase + 6144;                     // 3584
    float* c2p  = fbase + 9728;                     // 896
    float* d2   = fbase + 10624;                    // 3072

    dim3 blk(256, 1, 1);

    prep_w<<<dim3(12, 12, 5), blk, 0, stream>>>(Wq, Wk, Wv, bq, Wqt, Wkt, Wvb, csum);
    prep_x<<<dim3(64, 12, 4), blk, 0, stream>>>(x, Xbf, Xt, csum);

    // Gram tri 64x64 split-K partials (split=8, K=512) + u/d2 + c2p aux
    gram2<<<dim3(3488, 1, 1), blk, 0, stream>>>(Xt, Gp, Wk, Wv, Wqt, bk, bv,
                                                csum, u, d2, c2p);

    // reduce G (78 tiles) + c1p + P+ (64x64, 168 tiles over 4 y)
    redvec2<<<dim3(344, 4), blk, 0, stream>>>(Gp, G, Wqt, Wkt, Pp, u, c1p);

    // C1+ = P+ ⊠ G   [4][896][768]   (64x64 tiles: 672 wgs)
    gemm64_bf16<BIAS_NONE, true><<<dim3(12, 14, 4), blk, 0, stream>>>(
        Pp, G, C1p, nullptr, nullptr, nullptr, nullptr, nullptr,
        768, 768, 768, 768, 0, DD, DA, 1.0f, 0);

    // At = Wvb ⊠ C1+ (+rank2)   [4][768][896]   (64x64 tiles: 672 wgs)
    gemm64_bf16<BIAS_RANK2, true><<<dim3(14, 12, 4), blk, 0, stream>>>(
        Wvb, C1p, At, bv, c1p, d2, c2p, nullptr,
        768, 768, 768, 896, 0, DA, DA, SCALE, 896);

    // out = Xbf ⊠ At (K=768) + r epilogue (At col 768)  fp32 (128x128: 768 wgs)
    gemm_bf16<BIAS_RCOL, false><<<dim3(6, 32, 4), blk, 0, stream>>>(
        Xbf, At, out, nullptr, nullptr, nullptr, nullptr, At,
        768, 768, 896, 768, PB, DA, PB, 1.0f, 0);
}